// Round 9
// baseline (369.131 us; speedup 1.0000x reference)
//
#include <hip/hip_runtime.h>
#include <hip/hip_bf16.h>

// DeformableAttention3D — MI355X (gfx950)
// R16: R15's explicit register prefetch was compiler-defeated (loads sunk to
// use; VGPR 72->64, 82->93us). Revert k_mfma_projf to the R13 form (fastest).
// NEW lever: store projected v as BF16 (was f32):
//   * v shrinks 44.6MB -> 22.3MB: better L2 residency for k_fused2's random
//     corner gathers (each XCD L2 is only 4MB), gather bytes halved.
//   * projf value-proj WRITE halves (54MB -> ~24MB).
//   * precision precedent: R2/R6 (harness-passed) used bf16 v in fused path.
// k_mfma_proj / k_mfma_projf templated on output type; k_fused2 on v type.
#define EMBED    256
#define HEADS    8
#define LEVELS   4
#define POINTS   4
#define BATCH    2
#define M_TOT    21760   // 128*128 + 64*64 + 32*32 + 16*16
#define LDP      (EMBED + 4)   // padded LDS leading dim

typedef __hip_bfloat16 bf16;
typedef __attribute__((ext_vector_type(8))) short short8;
typedef __attribute__((ext_vector_type(8))) short bf16x8s;  // 8 bf16 (4 VGPRs)
typedef __attribute__((ext_vector_type(4))) float f32x4;

__device__ __constant__ int c_H[LEVELS]  = {128, 64, 32, 16};
__device__ __constant__ int c_St[LEVELS] = {0, 16384, 20480, 21504};

template<bool BF>
__device__ __forceinline__ float ldf(const void* p, size_t i) {
  if (BF) return __bfloat162float(((const bf16*)p)[i]);
  else    return ((const float*)p)[i];
}
__device__ __forceinline__ float vt2f(float x) { return x; }
__device__ __forceinline__ float vt2f(bf16 x)  { return __bfloat162float(x); }

__device__ __forceinline__ void stout(float* p, float v) { *p = v; }
__device__ __forceinline__ void stout(bf16* p, float v)  { *p = __float2bfloat16(v); }

template<bool BF>
__device__ __forceinline__ float4 ld4(const void* p, size_t i) {
  if (BF) {
    ushort4 u = *(const ushort4*)((const bf16*)p + i);
    float4 f;
    f.x = __bfloat162float(*reinterpret_cast<bf16*>(&u.x));
    f.y = __bfloat162float(*reinterpret_cast<bf16*>(&u.y));
    f.z = __bfloat162float(*reinterpret_cast<bf16*>(&u.z));
    f.w = __bfloat162float(*reinterpret_cast<bf16*>(&u.w));
    return f;
  } else {
    return *(const float4*)((const float*)p + i);
  }
}

__device__ __forceinline__ void fma4(float4& ac, float s, const float4& wv) {
  ac.x = fmaf(s, wv.x, ac.x);
  ac.y = fmaf(s, wv.y, ac.y);
  ac.z = fmaf(s, wv.z, ac.z);
  ac.w = fmaf(s, wv.w, ac.w);
}

// split 8 f32 -> hi/lo bf16x8 (in registers)
__device__ __forceinline__ void split8(const float4 x, const float4 y,
                                       bf16x8s& h, bf16x8s& l) {
  float f[8] = {x.x, x.y, x.z, x.w, y.x, y.y, y.z, y.w};
#pragma unroll
  for (int j = 0; j < 8; ++j) {
    bf16 hb = __float2bfloat16(f[j]);
    float r = f[j] - __bfloat162float(hb);
    bf16 lb = __float2bfloat16(r);
    h[j] = *reinterpret_cast<short*>(&hb);
    l[j] = *reinterpret_cast<short*>(&lb);
  }
}

// ---------------------------------------------------------------------------
// Dtype detector (flag=1 -> buffers bf16, flag=0 -> f32). Verbatim.
// ---------------------------------------------------------------------------
__global__ __launch_bounds__(256)
void k_detect(const unsigned short* __restrict__ q16, int* __restrict__ flag) {
  __shared__ int cnt;
  if (threadIdx.x == 0) cnt = 0;
  __syncthreads();
  int c = 0;
  for (int i = threadIdx.x; i < 8192; i += 256) {
    unsigned short v = q16[i];
    if ((v & 0x7F80u) == 0x7F80u) ++c;   // bf16 Inf/NaN pattern
  }
  if (c) atomicAdd(&cnt, c);
  __syncthreads();
  if (threadIdx.x == 0) flag[0] = (cnt == 0) ? 1 : 0;
}

// ---------------------------------------------------------------------------
// bf16 path (flag==1): transpose  WT[N][K] = W[K][N].  Verbatim R12.
// ---------------------------------------------------------------------------
__global__ __launch_bounds__(256)
void k_transpose_bf16(const unsigned short* __restrict__ W,
                      unsigned short* __restrict__ WT,
                      int K, int N, const int* __restrict__ flag) {
  if (*flag != 1) return;
  __shared__ unsigned short tile[64][65];
  const int ntn = N >> 6;
  const int tk = (int)blockIdx.x / ntn;
  const int tn = (int)blockIdx.x % ntn;
  const int k0 = tk << 6, n0 = tn << 6;
  const int t   = threadIdx.x;
  const int row = t >> 2;            // 0..63
  const int cq  = (t & 3) << 4;      // 0,16,32,48
  const unsigned short* src = W + (size_t)(k0 + row) * N + n0 + cq;
#pragma unroll
  for (int j = 0; j < 16; ++j) tile[row][cq + j] = src[j];
  __syncthreads();
  unsigned short* dst = WT + (size_t)(n0 + row) * K + k0 + cq;
#pragma unroll
  for (int j = 0; j < 16; ++j) dst[j] = tile[cq + j][row];
}

// ---------------------------------------------------------------------------
// f32 path (flag==0): all three W's -> transposed hi/lo bf16 in one launch.
// ---------------------------------------------------------------------------
__global__ __launch_bounds__(256)
void k_wsplit_all(const float* __restrict__ Wv, const float* __restrict__ Woff,
                  const float* __restrict__ Wattn,
                  bf16* __restrict__ Tvh, bf16* __restrict__ Tvl,
                  bf16* __restrict__ Toh, bf16* __restrict__ Tol,
                  bf16* __restrict__ Tah, bf16* __restrict__ Tal,
                  const int* __restrict__ flag) {
  if (*flag != 0) return;
  int bid = (int)blockIdx.x;
  const float* W; bf16 *H, *L; int N;
  if (bid < 16)      { W = Wv;    H = Tvh; L = Tvl; N = 256; }
  else if (bid < 32) { W = Woff;  H = Toh; L = Tol; N = 256; bid -= 16; }
  else               { W = Wattn; H = Tah; L = Tal; N = 128; bid -= 32; }
  const int K = 256;
  __shared__ float tile[64][65];
  const int ntn = N >> 6;
  const int tk = bid / ntn, tn = bid % ntn;
  const int k0 = tk << 6, n0 = tn << 6;
  const int t   = threadIdx.x;
  const int row = t >> 2;            // 0..63
  const int cq  = (t & 3) << 4;      // 0,16,32,48
  const float* src = W + (size_t)(k0 + row) * N + n0 + cq;
#pragma unroll
  for (int j = 0; j < 16; ++j) tile[row][cq + j] = src[j];
  __syncthreads();
  const size_t d0 = (size_t)(n0 + row) * K + k0 + cq;
#pragma unroll
  for (int j = 0; j < 16; ++j) {
    float v = tile[cq + j][row];
    bf16 hb = __float2bfloat16(v);
    float r = v - __bfloat162float(hb);
    H[d0 + j] = hb;
    L[d0 + j] = __float2bfloat16(r);
  }
}

// ---------------------------------------------------------------------------
// bf16-input MFMA projection (flag==1). R12 body, output type templated.
// ---------------------------------------------------------------------------
template<class OT>
__global__ __launch_bounds__(256)
void k_mfma_proj(const bf16* __restrict__ A, const bf16* __restrict__ WT,
                 const void* __restrict__ bias, OT* __restrict__ C,
                 int M, int N, const int* __restrict__ flag) {
  if (*flag != 1) return;
  const int colBlocks = N >> 7;
  const int rb = (int)blockIdx.x / colBlocks;
  const int cb = (int)blockIdx.x % colBlocks;
  const int t   = threadIdx.x;
  const int wid = t >> 6;
  const int l   = t & 63;
  const int lrow = l & 15;
  const int lk8  = (l >> 4) << 3;
  const int r0 = rb * 64 + (wid & 1) * 32;
  const int c0 = cb * 128 + (wid >> 1) * 64;

  f32x4 acc[2][4];
#pragma unroll
  for (int rf = 0; rf < 2; ++rf)
#pragma unroll
    for (int cf = 0; cf < 4; ++cf) acc[rf][cf] = (f32x4){0.f, 0.f, 0.f, 0.f};

  const bf16* Ap0 = A + (size_t)min(r0 + lrow,      M - 1) * EMBED + lk8;
  const bf16* Ap1 = A + (size_t)min(r0 + 16 + lrow, M - 1) * EMBED + lk8;
  const bf16* Bp  = WT + (size_t)(c0 + lrow) * EMBED + lk8;

#pragma unroll
  for (int k = 0; k < EMBED; k += 32) {
    bf16x8s a0 = *(const bf16x8s*)(Ap0 + k);
    bf16x8s a1 = *(const bf16x8s*)(Ap1 + k);
    bf16x8s b0 = *(const bf16x8s*)(Bp + 0 * 16 * EMBED + k);
    bf16x8s b1 = *(const bf16x8s*)(Bp + 1 * 16 * EMBED + k);
    bf16x8s b2 = *(const bf16x8s*)(Bp + 2 * 16 * EMBED + k);
    bf16x8s b3 = *(const bf16x8s*)(Bp + 3 * 16 * EMBED + k);
    acc[0][0] = __builtin_amdgcn_mfma_f32_16x16x32_bf16(a0, b0, acc[0][0], 0, 0, 0);
    acc[0][1] = __builtin_amdgcn_mfma_f32_16x16x32_bf16(a0, b1, acc[0][1], 0, 0, 0);
    acc[0][2] = __builtin_amdgcn_mfma_f32_16x16x32_bf16(a0, b2, acc[0][2], 0, 0, 0);
    acc[0][3] = __builtin_amdgcn_mfma_f32_16x16x32_bf16(a0, b3, acc[0][3], 0, 0, 0);
    acc[1][0] = __builtin_amdgcn_mfma_f32_16x16x32_bf16(a1, b0, acc[1][0], 0, 0, 0);
    acc[1][1] = __builtin_amdgcn_mfma_f32_16x16x32_bf16(a1, b1, acc[1][1], 0, 0, 0);
    acc[1][2] = __builtin_amdgcn_mfma_f32_16x16x32_bf16(a1, b2, acc[1][2], 0, 0, 0);
    acc[1][3] = __builtin_amdgcn_mfma_f32_16x16x32_bf16(a1, b3, acc[1][3], 0, 0, 0);
  }

  const int rbase = (l >> 4) << 2;
#pragma unroll
  for (int cf = 0; cf < 4; ++cf) {
    const int col = c0 + cf * 16 + lrow;
    const float bv = ldf<true>(bias, col);
#pragma unroll
    for (int rf = 0; rf < 2; ++rf) {
#pragma unroll
      for (int r = 0; r < 4; ++r) {
        const int row = r0 + rf * 16 + rbase + r;
        if (row < M) stout(&C[(size_t)row * N + col], acc[rf][cf][r] + bv);
      }
    }
  }
}

// ---------------------------------------------------------------------------
// f32-input split-bf16 MFMA projection (flag==0). R13 body (fastest measured),
// output type templated (bf16 for v, f32 for off/attn).
// ---------------------------------------------------------------------------
template<class OT>
__global__ __launch_bounds__(256)
void k_mfma_projf(const float* __restrict__ A, const bf16* __restrict__ WThi,
                  const bf16* __restrict__ WTlo, const float* __restrict__ bias,
                  OT* __restrict__ C, int M, int N,
                  const int* __restrict__ flag) {
  if (*flag != 0) return;
  const int colBlocks = N >> 7;
  const int rb = (int)blockIdx.x / colBlocks;
  const int cb = (int)blockIdx.x % colBlocks;
  const int t   = threadIdx.x;
  const int wid = t >> 6;
  const int l   = t & 63;
  const int lrow = l & 15;
  const int lk8  = (l >> 4) << 3;
  const int r0 = rb * 64 + (wid & 1) * 32;
  const int c0 = cb * 128 + (wid >> 1) * 64;

  f32x4 acc[2][4];
#pragma unroll
  for (int rf = 0; rf < 2; ++rf)
#pragma unroll
    for (int cf = 0; cf < 4; ++cf) acc[rf][cf] = (f32x4){0.f, 0.f, 0.f, 0.f};

  const float* Ap0 = A + (size_t)min(r0 + lrow,      M - 1) * EMBED + lk8;
  const float* Ap1 = A + (size_t)min(r0 + 16 + lrow, M - 1) * EMBED + lk8;
  const bf16* Bh = WThi + (size_t)(c0 + lrow) * EMBED + lk8;
  const bf16* Bl = WTlo + (size_t)(c0 + lrow) * EMBED + lk8;

#pragma unroll 2
  for (int k = 0; k < EMBED; k += 32) {
    bf16x8s a0h, a0l, a1h, a1l;
    split8(*(const float4*)(Ap0 + k), *(const float4*)(Ap0 + k + 4), a0h, a0l);
    split8(*(const float4*)(Ap1 + k), *(const float4*)(Ap1 + k + 4), a1h, a1l);
    bf16x8s bh0 = *(const bf16x8s*)(Bh + 0 * 16 * EMBED + k);
    bf16x8s bh1 = *(const bf16x8s*)(Bh + 1 * 16 * EMBED + k);
    bf16x8s bh2 = *(const bf16x8s*)(Bh + 2 * 16 * EMBED + k);
    bf16x8s bh3 = *(const bf16x8s*)(Bh + 3 * 16 * EMBED + k);
    bf16x8s bl0 = *(const bf16x8s*)(Bl + 0 * 16 * EMBED + k);
    bf16x8s bl1 = *(const bf16x8s*)(Bl + 1 * 16 * EMBED + k);
    bf16x8s bl2 = *(const bf16x8s*)(Bl + 2 * 16 * EMBED + k);
    bf16x8s bl3 = *(const bf16x8s*)(Bl + 3 * 16 * EMBED + k);
    // hi*hi
    acc[0][0] = __builtin_amdgcn_mfma_f32_16x16x32_bf16(a0h, bh0, acc[0][0], 0, 0, 0);
    acc[0][1] = __builtin_amdgcn_mfma_f32_16x16x32_bf16(a0h, bh1, acc[0][1], 0, 0, 0);
    acc[0][2] = __builtin_amdgcn_mfma_f32_16x16x32_bf16(a0h, bh2, acc[0][2], 0, 0, 0);
    acc[0][3] = __builtin_amdgcn_mfma_f32_16x16x32_bf16(a0h, bh3, acc[0][3], 0, 0, 0);
    acc[1][0] = __builtin_amdgcn_mfma_f32_16x16x32_bf16(a1h, bh0, acc[1][0], 0, 0, 0);
    acc[1][1] = __builtin_amdgcn_mfma_f32_16x16x32_bf16(a1h, bh1, acc[1][1], 0, 0, 0);
    acc[1][2] = __builtin_amdgcn_mfma_f32_16x16x32_bf16(a1h, bh2, acc[1][2], 0, 0, 0);
    acc[1][3] = __builtin_amdgcn_mfma_f32_16x16x32_bf16(a1h, bh3, acc[1][3], 0, 0, 0);
    // hi*lo
    acc[0][0] = __builtin_amdgcn_mfma_f32_16x16x32_bf16(a0h, bl0, acc[0][0], 0, 0, 0);
    acc[0][1] = __builtin_amdgcn_mfma_f32_16x16x32_bf16(a0h, bl1, acc[0][1], 0, 0, 0);
    acc[0][2] = __builtin_amdgcn_mfma_f32_16x16x32_bf16(a0h, bl2, acc[0][2], 0, 0, 0);
    acc[0][3] = __builtin_amdgcn_mfma_f32_16x16x32_bf16(a0h, bl3, acc[0][3], 0, 0, 0);
    acc[1][0] = __builtin_amdgcn_mfma_f32_16x16x32_bf16(a1h, bl0, acc[1][0], 0, 0, 0);
    acc[1][1] = __builtin_amdgcn_mfma_f32_16x16x32_bf16(a1h, bl1, acc[1][1], 0, 0, 0);
    acc[1][2] = __builtin_amdgcn_mfma_f32_16x16x32_bf16(a1h, bl2, acc[1][2], 0, 0, 0);
    acc[1][3] = __builtin_amdgcn_mfma_f32_16x16x32_bf16(a1h, bl3, acc[1][3], 0, 0, 0);
    // lo*hi
    acc[0][0] = __builtin_amdgcn_mfma_f32_16x16x32_bf16(a0l, bh0, acc[0][0], 0, 0, 0);
    acc[0][1] = __builtin_amdgcn_mfma_f32_16x16x32_bf16(a0l, bh1, acc[0][1], 0, 0, 0);
    acc[0][2] = __builtin_amdgcn_mfma_f32_16x16x32_bf16(a0l, bh2, acc[0][2], 0, 0, 0);
    acc[0][3] = __builtin_amdgcn_mfma_f32_16x16x32_bf16(a0l, bh3, acc[0][3], 0, 0, 0);
    acc[1][0] = __builtin_amdgcn_mfma_f32_16x16x32_bf16(a1l, bh0, acc[1][0], 0, 0, 0);
    acc[1][1] = __builtin_amdgcn_mfma_f32_16x16x32_bf16(a1l, bh1, acc[1][1], 0, 0, 0);
    acc[1][2] = __builtin_amdgcn_mfma_f32_16x16x32_bf16(a1l, bh2, acc[1][2], 0, 0, 0);
    acc[1][3] = __builtin_amdgcn_mfma_f32_16x16x32_bf16(a1l, bh3, acc[1][3], 0, 0, 0);
  }

  const int rbase = (l >> 4) << 2;
#pragma unroll
  for (int cf = 0; cf < 4; ++cf) {
    const int col = c0 + cf * 16 + lrow;
    const float bv = bias[col];
#pragma unroll
    for (int rf = 0; rf < 2; ++rf) {
#pragma unroll
      for (int r = 0; r < 4; ++r) {
        const int row = r0 + rf * 16 + rbase + r;
        if (row < M) stout(&C[(size_t)row * N + col], acc[rf][cf][r] + bv);
      }
    }
  }
}

// ---------------------------------------------------------------------------
// shared staging: 16 rows of A (EMBED cols) into padded LDS tile (R11)
// ---------------------------------------------------------------------------
template<bool BF>
__device__ __forceinline__ void stage16(const void* __restrict__ A,
                                        float (*rowA)[LDP],
                                        int r0, int M, int t) {
  int r  = t >> 4;
  int rr = min(r0 + r, M - 1);
  int c0 = (t & 15) * 16;
  if (BF) {
    const bf16* ap = (const bf16*)A + (size_t)rr * EMBED + c0;
    short8 a0 = *(const short8*)ap;
    short8 a1 = *(const short8*)(ap + 8);
#pragma unroll
    for (int j = 0; j < 8; ++j) {
      short s0 = a0[j], s1 = a1[j];
      rowA[r][c0 + j]     = __bfloat162float(*reinterpret_cast<bf16*>(&s0));
      rowA[r][c0 + 8 + j] = __bfloat162float(*reinterpret_cast<bf16*>(&s1));
    }
  } else {
    const float* ap = (const float*)A + (size_t)rr * EMBED + c0;
#pragma unroll
    for (int j = 0; j < 4; ++j) {
      float4 f = *(const float4*)(ap + j * 4);
      rowA[r][c0 + j * 4 + 0] = f.x;
      rowA[r][c0 + j * 4 + 1] = f.y;
      rowA[r][c0 + j * 4 + 2] = f.z;
      rowA[r][c0 + j * 4 + 3] = f.w;
    }
  }
}

// ---------------------------------------------------------------------------
// R11 tier kernels (need_full fallback): 4x4 / 2x4 register-blocked GEMVs.
// ---------------------------------------------------------------------------
template<bool BF>
__device__ void vgemv4x4_body(const void* __restrict__ A, const void* __restrict__ W,
                              const void* __restrict__ bias, float* __restrict__ C,
                              int M) {
  const int t  = threadIdx.x;
  const int r0 = blockIdx.x * 16;
  if (r0 >= M) return;

  __shared__ float rowA[16][LDP];
  stage16<BF>(A, rowA, r0, M, t);
  __syncthreads();

  const int g  = t >> 6;
  const int c0 = (t & 63) * 4;

  float4 bv;
  bv.x = ldf<BF>(bias, c0 + 0);
  bv.y = ldf<BF>(bias, c0 + 1);
  bv.z = ldf<BF>(bias, c0 + 2);
  bv.w = ldf<BF>(bias, c0 + 3);

  float4 acc[4];
#pragma unroll
  for (int r = 0; r < 4; ++r) acc[r] = bv;

#pragma unroll 2
  for (int k = 0; k < EMBED; k += 4) {
    float4 av[4];
#pragma unroll
    for (int r = 0; r < 4; ++r)
      av[r] = *(const float4*)&rowA[g * 4 + r][k];
    float4 w0 = ld4<BF>(W, (size_t)(k + 0) * EMBED + c0);
    float4 w1 = ld4<BF>(W, (size_t)(k + 1) * EMBED + c0);
    float4 w2 = ld4<BF>(W, (size_t)(k + 2) * EMBED + c0);
    float4 w3 = ld4<BF>(W, (size_t)(k + 3) * EMBED + c0);
#pragma unroll
    for (int r = 0; r < 4; ++r) {
      fma4(acc[r], av[r].x, w0);
      fma4(acc[r], av[r].y, w1);
      fma4(acc[r], av[r].z, w2);
      fma4(acc[r], av[r].w, w3);
    }
  }
#pragma unroll
  for (int r = 0; r < 4; ++r) {
    int row = r0 + g * 4 + r;
    if (row < M) *(float4*)&C[(size_t)row * EMBED + c0] = acc[r];
  }
}

__global__ __launch_bounds__(256)
void k_vgemv4x4(const void* A, const void* W, const void* bias, float* C,
                int M, const int* flag) {
  if (*flag) vgemv4x4_body<true >(A, W, bias, C, M);
  else       vgemv4x4_body<false>(A, W, bias, C, M);
}

template<bool BF>
__device__ void agemv4_body(const void* __restrict__ A, const void* __restrict__ W,
                            const void* __restrict__ bias, float* __restrict__ C,
                            int M) {
  const int t  = threadIdx.x;
  const int r0 = blockIdx.x * 16;
  if (r0 >= M) return;

  __shared__ float rowA[16][LDP];
  stage16<BF>(A, rowA, r0, M, t);
  __syncthreads();

  const int g  = t >> 5;
  const int c0 = (t & 31) * 4;

  float4 bv;
  bv.x = ldf<BF>(bias, c0 + 0);
  bv.y = ldf<BF>(bias, c0 + 1);
  bv.z = ldf<BF>(bias, c0 + 2);
  bv.w = ldf<BF>(bias, c0 + 3);

  float4 acc[2];
  acc[0] = bv; acc[1] = bv;

#pragma unroll 2
  for (int k = 0; k < EMBED; k += 4) {
    float4 a0 = *(const float4*)&rowA[g * 2 + 0][k];
    float4 a1 = *(const float4*)&rowA[g * 2 + 1][k];
    float4 w0 = ld4<BF>(W, (size_t)(k + 0) * 128 + c0);
    float4 w1 = ld4<BF>(W, (size_t)(k + 1) * 128 + c0);
    float4 w2 = ld4<BF>(W, (size_t)(k + 2) * 128 + c0);
    float4 w3 = ld4<BF>(W, (size_t)(k + 3) * 128 + c0);
    fma4(acc[0], a0.x, w0); fma4(acc[0], a0.y, w1);
    fma4(acc[0], a0.z, w2); fma4(acc[0], a0.w, w3);
    fma4(acc[1], a1.x, w0); fma4(acc[1], a1.y, w1);
    fma4(acc[1], a1.z, w2); fma4(acc[1], a1.w, w3);
  }
#pragma unroll
  for (int r = 0; r < 2; ++r) {
    int row = r0 + g * 2 + r;
    if (row < M) *(float4*)&C[(size_t)row * 128 + c0] = acc[r];
  }
}

__global__ __launch_bounds__(256)
void k_agemv4(const void* A, const void* W, const void* bias, float* C,
              int M, const int* flag) {
  if (*flag) agemv4_body<true >(A, W, bias, C, M);
  else       agemv4_body<false>(A, W, bias, C, M);
}

// ---------------------------------------------------------------------------
// k_fused2: softmax + pack (t<128) + ILP-batched gather. v type templated.
// ---------------------------------------------------------------------------
template<bool BF, class VT>
__device__ void fused2_body(const void* __restrict__ ref_points,
                            const float* __restrict__ off_pre,
                            const float* __restrict__ scores,
                            const VT* __restrict__ v,
                            void* __restrict__ out, int N, int BN) {
  int q = blockIdx.x;
  if (q >= BN) return;
  int b = q / N;
  int t = threadIdx.x;

  __shared__ float  s_aw[128];
  __shared__ float  s_rp[2];
  __shared__ int4   s_pi[128];   // corner element index (cell<<8)
  __shared__ float4 s_pw[128];   // wa * bilinear * valid

  if (t < 2)   s_rp[t] = ldf<BF>(ref_points, (size_t)q * 2 + t);
  if (t < 128) s_aw[t] = scores[(size_t)q * 128 + t];
  __syncthreads();

  if (t < 128) {
    int base = t & ~15;
    float mx = -1e30f;
#pragma unroll
    for (int i = 0; i < 16; ++i) mx = fmaxf(mx, s_aw[base + i]);
    float sum = 0.f;
#pragma unroll
    for (int i = 0; i < 16; ++i) sum += expf(s_aw[base + i] - mx);
    float wa = expf(s_aw[t] - mx) / sum;

    int   l  = (t >> 2) & 3;
    int   Wl = 128 >> l;                       // levels are square
    float fW = (float)Wl;
    int   st = (int)((65536u - (65536u >> (2 * l))) / 3u);  // level start
    float ox = off_pre[(size_t)q * EMBED + 2 * t]     - 0.5f;
    float oy = off_pre[(size_t)q * EMBED + 2 * t + 1] - 0.5f;
    float x = fmaf(s_rp[0], fW, ox);
    float y = fmaf(s_rp[1], fW, oy);
    float x0f = floorf(x), y0f = floorf(y);
    float lx = x - x0f, ly = y - y0f;
    int x0 = (int)x0f, y0 = (int)y0f;
    int x1 = x0 + 1,   y1 = y0 + 1;
    float w00 = wa * (1.f - lx) * (1.f - ly);
    float w01 = wa * lx * (1.f - ly);
    float w10 = wa * (1.f - lx) * ly;
    float w11 = wa * lx * ly;
    bool vx0 = (unsigned)x0 < (unsigned)Wl;
    bool vx1 = (unsigned)x1 < (unsigned)Wl;
    bool vy0 = (unsigned)y0 < (unsigned)Wl;
    bool vy1 = (unsigned)y1 < (unsigned)Wl;
    int xc0 = min(max(x0, 0), Wl - 1), xc1 = min(max(x1, 0), Wl - 1);
    int yc0 = min(max(y0, 0), Wl - 1), yc1 = min(max(y1, 0), Wl - 1);
    int r0i = st + yc0 * Wl;
    int r1i = st + yc1 * Wl;
    int4 pi; float4 pw;
    pi.x = (r0i + xc0) << 8;  pw.x = (vx0 && vy0) ? w00 : 0.f;
    pi.y = (r0i + xc1) << 8;  pw.y = (vx1 && vy0) ? w01 : 0.f;
    pi.z = (r1i + xc0) << 8;  pw.z = (vx0 && vy1) ? w10 : 0.f;
    pi.w = (r1i + xc1) << 8;  pw.w = (vx1 && vy1) ? w11 : 0.f;
    s_pi[t] = pi;
    s_pw[t] = pw;
  }
  __syncthreads();

  const VT* vb = v + (size_t)b * (M_TOT * EMBED);
  const int cb = (t >> 5) << 4;            // h*16
  float o0 = 0.f, o1 = 0.f;
#pragma unroll
  for (int g = 0; g < 4; ++g) {
    const int c0 = cb + (g << 2);
    int4   iA = s_pi[c0 + 0], iB = s_pi[c0 + 1], iC = s_pi[c0 + 2], iD = s_pi[c0 + 3];
    float4 wA = s_pw[c0 + 0], wB = s_pw[c0 + 1], wC = s_pw[c0 + 2], wD = s_pw[c0 + 3];
    float gA0 = vt2f(vb[iA.x + t]), gA1 = vt2f(vb[iA.y + t]);
    float gA2 = vt2f(vb[iA.z + t]), gA3 = vt2f(vb[iA.w + t]);
    float gB0 = vt2f(vb[iB.x + t]), gB1 = vt2f(vb[iB.y + t]);
    float gB2 = vt2f(vb[iB.z + t]), gB3 = vt2f(vb[iB.w + t]);
    float gC0 = vt2f(vb[iC.x + t]), gC1 = vt2f(vb[iC.y + t]);
    float gC2 = vt2f(vb[iC.z + t]), gC3 = vt2f(vb[iC.w + t]);
    float gD0 = vt2f(vb[iD.x + t]), gD1 = vt2f(vb[iD.y + t]);
    float gD2 = vt2f(vb[iD.z + t]), gD3 = vt2f(vb[iD.w + t]);
    o0 = fmaf(wA.x, gA0, o0); o1 = fmaf(wA.y, gA1, o1);
    o0 = fmaf(wA.z, gA2, o0); o1 = fmaf(wA.w, gA3, o1);
    o0 = fmaf(wB.x, gB0, o0); o1 = fmaf(wB.y, gB1, o1);
    o0 = fmaf(wB.z, gB2, o0); o1 = fmaf(wB.w, gB3, o1);
    o0 = fmaf(wC.x, gC0, o0); o1 = fmaf(wC.y, gC1, o1);
    o0 = fmaf(wC.z, gC2, o0); o1 = fmaf(wC.w, gC3, o1);
    o0 = fmaf(wD.x, gD0, o0); o1 = fmaf(wD.y, gD1, o1);
    o0 = fmaf(wD.z, gD2, o0); o1 = fmaf(wD.w, gD3, o1);
  }
  float o = o0 + o1;
  if (BF) ((bf16*)out)[(size_t)q * EMBED + t] = __float2bfloat16(o);
  else    ((float*)out)[(size_t)q * EMBED + t] = o;
}

template<class VT>
__global__ __launch_bounds__(256)
void k_fused2(const void* ref_points, const float* off_pre, const float* scores,
              const VT* v, void* out, int N, int BN, const int* flag) {
  if (*flag) fused2_body<true,  VT>(ref_points, off_pre, scores, v, out, N, BN);
  else       fused2_body<false, VT>(ref_points, off_pre, scores, v, out, N, BN);
}

// ---------------------------------------------------------------------------
// MID TIER (R8, proven): 8-row GEMV + fused with in-kernel attn GEMV.
// ---------------------------------------------------------------------------
template<bool BF>
__device__ void vgemv8_body(const void* __restrict__ A, const void* __restrict__ W,
                            const void* __restrict__ bias, float* __restrict__ C,
                            int M) {
  const int t  = threadIdx.x;
  const int r0 = blockIdx.x * 8;
  if (r0 >= M) return;

  __shared__ float rowA[8][EMBED];
  {
    int r  = t >> 5;
    int rr = min(r0 + r, M - 1);
    int c0 = (t & 31) * 8;
    if (BF) {
      const bf16* ap = (const bf16*)A + (size_t)rr * EMBED + c0;
      short8 a = *(const short8*)ap;
#pragma unroll
      for (int j = 0; j < 8; ++j) {
        short s = a[j];
        bf16 hb = *reinterpret_cast<bf16*>(&s);
        rowA[r][c0 + j] = __bfloat162float(hb);
      }
    } else {
      const float* ap = (const float*)A + (size_t)rr * EMBED + c0;
#pragma unroll
      for (int j = 0; j < 8; ++j) rowA[r][c0 + j] = ap[j];
    }
  }
  __syncthreads();

  const int n = t;
  const float b = ldf<BF>(bias, n);
  float acc[8];
#pragma unroll
  for (int r = 0; r < 8; ++r) acc[r] = b;
#pragma unroll 4
  for (int k = 0; k < EMBED; ++k) {
    float w = ldf<BF>(W, (size_t)k * EMBED + n);
#pragma unroll
    for (int r = 0; r < 8; ++r) acc[r] = fmaf(rowA[r][k], w, acc[r]);
  }
#pragma unroll
  for (int r = 0; r < 8; ++r)
    if (r0 + r < M) C[(size_t)(r0 + r) * EMBED + n] = acc[r];
}

__global__ __launch_bounds__(256)
void k_vgemv8(const void* A, const void* W, const void* bias, float* C,
              int M, const int* flag) {
  if (*flag) vgemv8_body<true >(A, W, bias, C, M);
  else       vgemv8_body<false>(A, W, bias, C, M);
}

template<bool BF, class VT>
__device__ void fused_body(const void* __restrict__ query,
                           const void* __restrict__ ref_points,
                           const float* __restrict__ off_pre,
                           const void* __restrict__ W_attn,
                           const void* __restrict__ b_attn,
                           const VT* __restrict__ v,
                           void* __restrict__ out, int N, int BN) {
  int q = blockIdx.x;
  if (q >= BN) return;
  int b = q / N;
  int t = threadIdx.x;

  __shared__ float  row[EMBED];
  __shared__ float  s_part[256];
  __shared__ float  s_aw[HEADS * LEVELS * POINTS];
  __shared__ float  s_rp[2];
  __shared__ int4   s_pi[HEADS * LEVELS * POINTS];
  __shared__ float4 s_pw[HEADS * LEVELS * POINTS];

  row[t] = ldf<BF>(query, (size_t)q * EMBED + t);
  if (t < 2) s_rp[t] = ldf<BF>(ref_points, (size_t)q * 2 + t);
  __syncthreads();

  {
    const int col = t & 127;
    const int e0  = (t >> 7) * 128;
    float acc = 0.f;
#pragma unroll 8
    for (int e = 0; e < 128; ++e)
      acc = fmaf(row[e0 + e], ldf<BF>(W_attn, (size_t)(e0 + e) * 128 + col), acc);
    s_part[t] = acc;
  }
  __syncthreads();
  if (t < 128)
    s_aw[t] = ldf<BF>(b_attn, t) + s_part[t] + s_part[t + 128];
  __syncthreads();

  if (t < 128) {
    int base = t & ~15;
    float mx = -1e30f;
#pragma unroll
    for (int i = 0; i < 16; ++i) mx = fmaxf(mx, s_aw[base + i]);
    float sum = 0.f;
#pragma unroll
    for (int i = 0; i < 16; ++i) sum += expf(s_aw[base + i] - mx);
    float wa = expf(s_aw[t] - mx) / sum;

    int   l  = (t >> 2) & 3;
    int   Wl = 128 >> l;
    float fW = (float)Wl;
    int   st = (int)((65536u - (65536u >> (2 * l))) / 3u);
    float ox = off_pre[(size_t)q * EMBED + 2 * t]     - 0.5f;
    float oy = off_pre[(size_t)q * EMBED + 2 * t + 1] - 0.5f;
    float x = fmaf(s_rp[0], fW, ox);
    float y = fmaf(s_rp[1], fW, oy);
    float x0f = floorf(x), y0f = floorf(y);
    float lx = x - x0f, ly = y - y0f;
    int x0 = (int)x0f, y0 = (int)y0f;
    int x1 = x0 + 1,   y1 = y0 + 1;
    float w00 = wa * (1.f - lx) * (1.f - ly);
    float w01 = wa * lx * (1.f - ly);
    float w10 = wa * (1.f - lx) * ly;
    float w11 = wa * lx * ly;
    bool vx0 = (unsigned)x0 < (unsigned)Wl;
    bool vx1 = (unsigned)x1 < (unsigned)Wl;
    bool vy0 = (unsigned)y0 < (unsigned)Wl;
    bool vy1 = (unsigned)y1 < (unsigned)Wl;
    int xc0 = min(max(x0, 0), Wl - 1), xc1 = min(max(x1, 0), Wl - 1);
    int yc0 = min(max(y0, 0), Wl - 1), yc1 = min(max(y1, 0), Wl - 1);
    int r0i = st + yc0 * Wl;
    int r1i = st + yc1 * Wl;
    int4 pi; float4 pw;
    pi.x = (r0i + xc0) << 8;  pw.x = (vx0 && vy0) ? w00 : 0.f;
    pi.y = (r0i + xc1) << 8;  pw.y = (vx1 && vy0) ? w01 : 0.f;
    pi.z = (r1i + xc0) << 8;  pw.z = (vx0 && vy1) ? w10 : 0.f;
    pi.w = (r1i + xc1) << 8;  pw.w = (vx1 && vy1) ? w11 : 0.f;
    s_pi[t] = pi;
    s_pw[t] = pw;
  }
  __syncthreads();

  const int h = t >> 5;
  const VT* vbt = v + (size_t)b * M_TOT * EMBED + t;
  float o = 0.f;
#pragma unroll
  for (int lp = 0; lp < 16; ++lp) {
    int c = (h << 4) + lp;
    int4   i4 = s_pi[c];
    float4 w4 = s_pw[c];
    o = fmaf(w4.x, vt2f(vbt[i4.x]), o);
    o = fmaf(w4.y, vt2f(vbt[i4.y]), o);
    o = fmaf(w4.z, vt2f(vbt[i4.z]), o);
    o = fmaf(w4.w, vt2f(vbt[i4.w]), o);
  }
  if (BF) ((bf16*)out)[(size_t)q * EMBED + t] = __float2bfloat16(o);
  else    ((float*)out)[(size_t)q * EMBED + t] = o;
}

template<class VT>
__global__ __launch_bounds__(256)
void k_fused(const void* query, const void* ref_points, const float* off_pre,
             const void* W_attn, const void* b_attn,
             const VT* v, void* out, int N, int BN, const int* flag) {
  if (*flag) fused_body<true,  VT>(query, ref_points, off_pre, W_attn, b_attn, v, out, N, BN);
  else       fused_body<false, VT>(query, ref_points, off_pre, W_attn, b_attn, v, out, N, BN);
}

// ---------------------------------------------------------------------------
// Fallback path (ws too small): R2/R6's bf16 fused path, fully self-contained.
// ---------------------------------------------------------------------------
template<bool BF, class VT>
__device__ void vproj_body(const void* __restrict__ value,
                           const void* __restrict__ W_v,
                           const void* __restrict__ b_v,
                           VT* __restrict__ v, int BM) {
  int m = blockIdx.x;
  if (m >= BM) return;
  int t = threadIdx.x;
  __shared__ float row[EMBED];
  row[t] = ldf<BF>(value, (size_t)m * EMBED + t);
  __syncthreads();
  float acc = ldf<BF>(b_v, t);
#pragma unroll 8
  for (int e = 0; e < EMBED; ++e)
    acc = fmaf(row[e], ldf<BF>(W_v, (size_t)e * EMBED + t), acc);
  if (sizeof(VT) == 2) ((bf16*)v)[(size_t)m * EMBED + t] = __float2bfloat16(acc);
  else                 ((float*)v)[(size_t)m * EMBED + t] = acc;
}

template<class VT>
__global__ __launch_bounds__(256)
void k_value_proj(const void* value, const void* W_v, const void* b_v,
                  VT* v, int BM, const int* flag) {
  if (*flag) vproj_body<true,  VT>(value, W_v, b_v, v, BM);
  else       vproj_body<false, VT>(value, W_v, b_v, v, BM);
}

template<bool BF, class VT>
__device__ void fusedfb_body(const void* __restrict__ query,
                             const void* __restrict__ ref_points,
                             const void* __restrict__ W_off,
                             const void* __restrict__ b_off,
                             const void* __restrict__ W_attn,
                             const void* __restrict__ b_attn,
                             const VT* __restrict__ v,
                             void* __restrict__ out, int N, int BN) {
  int q = blockIdx.x;
  if (q >= BN) return;
  int b = q / N;
  int t = threadIdx.x;

  __shared__ float row[EMBED];
  __shared__ float s_off[EMBED];
  __shared__ float s_aw[HEADS * LEVELS * POINTS];
  __shared__ float s_rp[2];

  row[t] = ldf<BF>(query, (size_t)q * EMBED + t);
  if (t < 2) s_rp[t] = ldf<BF>(ref_points, (size_t)q * 2 + t);
  __syncthreads();

  {
    float acc = ldf<BF>(b_off, t);
#pragma unroll 8
    for (int e = 0; e < EMBED; ++e)
      acc = fmaf(row[e], ldf<BF>(W_off, (size_t)e * EMBED + t), acc);
    s_off[t] = acc;
  }
  if (t < 128) {
    float acc = ldf<BF>(b_attn, t);
#pragma unroll 8
    for (int e = 0; e < EMBED; ++e)
      acc = fmaf(row[e], ldf<BF>(W_attn, (size_t)e * 128 + t), acc);
    s_aw[t] = acc;
  }
  __syncthreads();

  float aval = 0.f;
  if (t < 128) {
    int base = t & ~15;
    float mx = -1e30f;
#pragma unroll
    for (int i = 0; i < 16; ++i) mx = fmaxf(mx, s_aw[base + i]);
    float sum = 0.f;
#pragma unroll
    for (int i = 0; i < 16; ++i) sum += expf(s_aw[base + i] - mx);
    aval = expf(s_aw[t] - mx) / sum;
  }
  __syncthreads();
  if (t < 128) s_aw[t] = aval;
  __syncthreads();

  int h = t >> 5;
  const VT* vb = v + (size_t)b * M_TOT * EMBED;
  float o = 0.f;
#pragma unroll
  for (int l = 0; l < LEVELS; ++l) {
    const int Hl = c_H[l], Wl = c_H[l];
    const VT* vl = vb + (size_t)c_St[l] * EMBED;
    const float fW = (float)Wl, fH = (float)Hl;
#pragma unroll
    for (int p = 0; p < POINTS; ++p) {
      int oi = ((h * LEVELS + l) * POINTS + p) << 1;
      float x = (s_rp[0] + s_off[oi]     / fW) * fW - 0.5f;
      float y = (s_rp[1] + s_off[oi + 1] / fH) * fH - 0.5f;
      float x0f = floorf(x), y0f = floorf(y);
      float lx = x - x0f, ly = y - y0f;
      int x0 = (int)x0f, y0 = (int)y0f;
      float wa = s_aw[(h * LEVELS + l) * POINTS + p];
      float cw[4] = {(1.f - lx) * (1.f - ly), lx * (1.f - ly),
                     (1.f - lx) * ly,         lx * ly};
      const int dxs[4] = {0, 1, 0, 1};
      const int dys[4] = {0, 0, 1, 1};
#pragma unroll
      for (int cidx = 0; cidx < 4; ++cidx) {
        int xi = x0 + dxs[cidx];
        int yi = y0 + dys[cidx];
        bool valid = (xi >= 0) & (xi < Wl) & (yi >= 0) & (yi < Hl);
        int xc = min(max(xi, 0), Wl - 1);
        int yc = min(max(yi, 0), Hl - 1);
        float g = vt2f(vl[(size_t)(yc * Wl + xc) * EMBED + t]);
        o += (valid ? wa * cw[cidx] : 0.f) * g;
      }
    }
  }
  if (BF) ((bf16*)out)[(size_t)q * EMBED + t] = __float2bfloat16(o);
  else    ((float*)out)[(size_t)q * EMBED + t] = o;
}

template<class VT>
__global__ __launch_bounds__(256)
void k_fused_fb(const void* query, const void* ref_points,
                const void* W_off, const void* b_off,
                const void* W_attn, const void* b_attn,
                const VT* v, void* out, int N, int BN, const int* flag) {
  if (*flag) fusedfb_body<true,  VT>(query, ref_points, W_off, b_off, W_attn, b_attn, v, out, N, BN);
  else       fusedfb_body<false, VT>(query, ref_points, W_off, b_off, W_attn, b_attn, v, out, N, BN);
}

// ---------------------------------------------------------------------------
extern "C" void kernel_launch(void* const* d_in, const int* in_sizes, int n_in,
                              void* d_out, int out_size, void* d_ws, size_t ws_size,
                              hipStream_t stream) {
  const void* query      = d_in[0];
  const void* value      = d_in[2];
  const void* ref_points = d_in[3];
  const void* W_off  = d_in[6];
  const void* b_off  = d_in[7];
  const void* W_attn = d_in[8];
  const void* b_attn = d_in[9];
  const void* W_v    = d_in[10];
  const void* b_v    = d_in[11];

  const int BN = in_sizes[0] / EMBED;   // 20000
  const int BM = in_sizes[2] / EMBED;   // 43520
  const int N  = BN / BATCH;

  int*  flag    = (int*)d_ws;
  char* ws_base = (char*)d_ws + 256;

  k_detect<<<1, 256, 0, stream>>>((const unsigned short*)query, flag);

  const size_t sz_v    = (size_t)BM * EMBED * sizeof(float);  // layout slot (v used as bf16)
  const size_t sz_off  = (size_t)BN * EMBED * sizeof(float);
  const size_t sz_attn = (size_t)BN * 128 * sizeof(float);
  // weight-transform area (union of bf16 path 320KB and f32 hi/lo path 640KB)
  const size_t sz_T    = (size_t)(256 * 256 * 2 + 256 * 128) * 2 /*hi+lo*/ * 2;
  const size_t need_mfma = 256 + sz_v + sz_off + sz_attn + sz_T;
  const size_t need_full = 256 + sz_v + sz_off + sz_attn;
  const size_t need_mid  = 256 + sz_v + sz_off;

  if (ws_size >= need_mfma) {
    bf16*  ws_v    = (bf16*)ws_base;                    // v stored as bf16 (22.3MB)
    float* ws_off  = (float*)(ws_base + sz_v);
    float* ws_attn = (float*)(ws_base + sz_v + sz_off);
    unsigned short* wsT = (unsigned short*)(ws_base + sz_v + sz_off + sz_attn);
    // bf16 path layout
    unsigned short* wsT_v    = wsT;
    unsigned short* wsT_off  = wsT + 256 * 256;
    unsigned short* wsT_attn = wsT + 2 * 256 * 256;
    // f32 path layout (same area; only one path runs)
    bf16* Tvh = (bf16*)wsT;
    bf16* Tvl = Tvh + 256 * 256;
    bf16* Toh = Tvl + 256 * 256;
    bf16* Tol = Toh + 256 * 256;
    bf16* Tah = Tol + 256 * 256;
    bf16* Tal = Tah + 256 * 128;

    const int rbV64 = (BM + 63) / 64;
    const int rbQ64 = (BN + 63) / 64;

    // bf16 path (flag==1)
    k_transpose_bf16<<<16, 256, 0, stream>>>((const unsigned short*)W_v,    wsT_v,    256, 256, flag);
    k_transpose_bf16<<<16, 256, 0, stream>>>((const unsigned short*)W_off,  wsT_off,  256, 256, flag);
    k_transpose_bf16<<< 8, 256, 0, stream>>>((const unsigned short*)W_attn, wsT_attn, 256, 128, flag);
    k_mfma_proj<bf16 ><<<rbV64 * 2, 256, 0, stream>>>((const bf16*)value, (const bf16*)wsT_v,
                                                      b_v, ws_v, BM, 256, flag);
    k_mfma_proj<float><<<rbQ64 * 2, 256, 0, stream>>>((const bf16*)query, (const bf16*)wsT_off,
                                                      b_off, ws_off, BN, 256, flag);
    k_mfma_proj<float><<<rbQ64,     256, 0, stream>>>((const bf16*)query, (const bf16*)wsT_attn,
                                                      b_attn, ws_attn, BN, 128, flag);

    // f32 path (flag==0): split-bf16 MFMA (R13 geometry)
    k_wsplit_all<<<40, 256, 0, stream>>>((const float*)W_v, (const float*)W_off,
                                         (const float*)W_attn,
                                         Tvh, Tvl, Toh, Tol, Tah, Tal, flag);
    k_mfma_projf<bf16 ><<<rbV64 * 2, 256, 0, stream>>>((const float*)value, Tvh, Tvl,
                                                       (const float*)b_v, ws_v, BM, 256, flag);
    k_mfma_projf<float><<<rbQ64 * 2, 256, 0, stream>>>((const float*)query, Toh, Tol,
                                                       (const float*)b_off, ws_off, BN, 256, flag);
    k_mfma_projf<float><<<rbQ64,     256, 0, stream>>>((const float*)query, Tah, Tal,
                                                       (const float*)b_attn, ws_attn, BN, 128, flag);

    k_fused2<bf16><<<BN, 256, 0, stream>>>(ref_points, ws_off, ws_attn, ws_v,
                                           d_out, N, BN, flag);
  } else if (ws_size >= need_full) {
    float* ws_v    = (float*)ws_base;
    float* ws_off  = (float*)(ws_base + sz_v);
    float* ws_attn = (float*)(ws_base + sz_v + sz_off);
    k_vgemv4x4<<<(BM + 15) / 16, 256, 0, stream>>>(value, W_v, b_v, ws_v, BM, flag);
    k_vgemv4x4<<<(BN + 15) / 16, 256, 0, stream>>>(query, W_off, b_off, ws_off, BN, flag);
    k_agemv4<<<(BN + 15) / 16, 256, 0, stream>>>(query, W_attn, b_attn, ws_attn, BN, flag);
    k_fused2<float><<<BN, 256, 0, stream>>>(ref_points, ws_off, ws_attn, ws_v,
                                            d_out, N, BN, flag);
  } else if (ws_size >= need_mid) {
    float* ws_v   = (float*)ws_base;
    float* ws_off = (float*)(ws_base + sz_v);
    k_vgemv8<<<(BM + 7) / 8, 256, 0, stream>>>(value, W_v, b_v, ws_v, BM, flag);
    k_vgemv8<<<(BN + 7) / 8, 256, 0, stream>>>(query, W_off, b_off, ws_off, BN, flag);
    k_fused<float><<<BN, 256, 0, stream>>>(query, ref_points, ws_off,
                                           W_attn, b_attn, ws_v, d_out, N, BN, flag);
  } else {
    bf16* ws_v = (bf16*)ws_base;
    k_value_proj<bf16><<<BM, 256, 0, stream>>>(value, W_v, b_v, ws_v, BM, flag);
    k_fused_fb<bf16><<<BN, 256, 0, stream>>>(query, ref_points, W_off, b_off,
                                             W_attn, b_attn, ws_v, d_out, N, BN, flag);
  }
}

// Round 10
// 325.039 us; speedup vs baseline: 1.1356x; 1.1356x over previous
//
#include <hip/hip_runtime.h>
#include <hip/hip_bf16.h>

// DeformableAttention3D — MI355X (gfx950)
// R17: two independent restructures (per-dispatch attributable):
//  1) k_fused2 gather: 2 channels/lane (ushort2), 32 loads not 64, bit-op
//     bf16 unpack, combo-split across thread halves + LDS combine.
//  2) k_mfma_projf2: LDS-staged A (whole K=256, 32 rows, 33KB padded tile,
//     reg-staged float4 bulk loads, one barrier) + R13 split-bf16 MFMA loop.
//     Fixes the ~900cy HBM latency that pinned MfmaUtil at 7% (R13-R15).
// Everything else verbatim from R16.
#define EMBED    256
#define HEADS    8
#define LEVELS   4
#define POINTS   4
#define BATCH    2
#define M_TOT    21760   // 128*128 + 64*64 + 32*32 + 16*16
#define LDP      (EMBED + 4)   // padded LDS leading dim

typedef __hip_bfloat16 bf16;
typedef __attribute__((ext_vector_type(8))) short short8;
typedef __attribute__((ext_vector_type(8))) short bf16x8s;  // 8 bf16 (4 VGPRs)
typedef __attribute__((ext_vector_type(4))) float f32x4;

__device__ __constant__ int c_H[LEVELS]  = {128, 64, 32, 16};
__device__ __constant__ int c_St[LEVELS] = {0, 16384, 20480, 21504};

template<bool BF>
__device__ __forceinline__ float ldf(const void* p, size_t i) {
  if (BF) return __bfloat162float(((const bf16*)p)[i]);
  else    return ((const float*)p)[i];
}
__device__ __forceinline__ float vt2f(float x) { return x; }
__device__ __forceinline__ float vt2f(bf16 x)  { return __bfloat162float(x); }

__device__ __forceinline__ void stout(float* p, float v) { *p = v; }
__device__ __forceinline__ void stout(bf16* p, float v)  { *p = __float2bfloat16(v); }

// load 2 consecutive channels -> 2 f32
__device__ __forceinline__ void ld2c(const bf16* p, float& lo, float& hi) {
  unsigned u = *(const unsigned*)p;
  lo = __uint_as_float(u << 16);
  hi = __uint_as_float(u & 0xFFFF0000u);
}
__device__ __forceinline__ void ld2c(const float* p, float& lo, float& hi) {
  float2 f = *(const float2*)p;
  lo = f.x; hi = f.y;
}

template<bool BF>
__device__ __forceinline__ float4 ld4(const void* p, size_t i) {
  if (BF) {
    ushort4 u = *(const ushort4*)((const bf16*)p + i);
    float4 f;
    f.x = __bfloat162float(*reinterpret_cast<bf16*>(&u.x));
    f.y = __bfloat162float(*reinterpret_cast<bf16*>(&u.y));
    f.z = __bfloat162float(*reinterpret_cast<bf16*>(&u.z));
    f.w = __bfloat162float(*reinterpret_cast<bf16*>(&u.w));
    return f;
  } else {
    return *(const float4*)((const float*)p + i);
  }
}

__device__ __forceinline__ void fma4(float4& ac, float s, const float4& wv) {
  ac.x = fmaf(s, wv.x, ac.x);
  ac.y = fmaf(s, wv.y, ac.y);
  ac.z = fmaf(s, wv.z, ac.z);
  ac.w = fmaf(s, wv.w, ac.w);
}

// split 8 f32 -> hi/lo bf16x8 (in registers)
__device__ __forceinline__ void split8(const float4 x, const float4 y,
                                       bf16x8s& h, bf16x8s& l) {
  float f[8] = {x.x, x.y, x.z, x.w, y.x, y.y, y.z, y.w};
#pragma unroll
  for (int j = 0; j < 8; ++j) {
    bf16 hb = __float2bfloat16(f[j]);
    float r = f[j] - __bfloat162float(hb);
    bf16 lb = __float2bfloat16(r);
    h[j] = *reinterpret_cast<short*>(&hb);
    l[j] = *reinterpret_cast<short*>(&lb);
  }
}

// ---------------------------------------------------------------------------
// Dtype detector (flag=1 -> buffers bf16, flag=0 -> f32). Verbatim.
// ---------------------------------------------------------------------------
__global__ __launch_bounds__(256)
void k_detect(const unsigned short* __restrict__ q16, int* __restrict__ flag) {
  __shared__ int cnt;
  if (threadIdx.x == 0) cnt = 0;
  __syncthreads();
  int c = 0;
  for (int i = threadIdx.x; i < 8192; i += 256) {
    unsigned short v = q16[i];
    if ((v & 0x7F80u) == 0x7F80u) ++c;   // bf16 Inf/NaN pattern
  }
  if (c) atomicAdd(&cnt, c);
  __syncthreads();
  if (threadIdx.x == 0) flag[0] = (cnt == 0) ? 1 : 0;
}

// ---------------------------------------------------------------------------
// bf16 path (flag==1): transpose  WT[N][K] = W[K][N].  Verbatim R12.
// ---------------------------------------------------------------------------
__global__ __launch_bounds__(256)
void k_transpose_bf16(const unsigned short* __restrict__ W,
                      unsigned short* __restrict__ WT,
                      int K, int N, const int* __restrict__ flag) {
  if (*flag != 1) return;
  __shared__ unsigned short tile[64][65];
  const int ntn = N >> 6;
  const int tk = (int)blockIdx.x / ntn;
  const int tn = (int)blockIdx.x % ntn;
  const int k0 = tk << 6, n0 = tn << 6;
  const int t   = threadIdx.x;
  const int row = t >> 2;            // 0..63
  const int cq  = (t & 3) << 4;      // 0,16,32,48
  const unsigned short* src = W + (size_t)(k0 + row) * N + n0 + cq;
#pragma unroll
  for (int j = 0; j < 16; ++j) tile[row][cq + j] = src[j];
  __syncthreads();
  unsigned short* dst = WT + (size_t)(n0 + row) * K + k0 + cq;
#pragma unroll
  for (int j = 0; j < 16; ++j) dst[j] = tile[cq + j][row];
}

// ---------------------------------------------------------------------------
// f32 path (flag==0): all three W's -> transposed hi/lo bf16 in one launch.
// ---------------------------------------------------------------------------
__global__ __launch_bounds__(256)
void k_wsplit_all(const float* __restrict__ Wv, const float* __restrict__ Woff,
                  const float* __restrict__ Wattn,
                  bf16* __restrict__ Tvh, bf16* __restrict__ Tvl,
                  bf16* __restrict__ Toh, bf16* __restrict__ Tol,
                  bf16* __restrict__ Tah, bf16* __restrict__ Tal,
                  const int* __restrict__ flag) {
  if (*flag != 0) return;
  int bid = (int)blockIdx.x;
  const float* W; bf16 *H, *L; int N;
  if (bid < 16)      { W = Wv;    H = Tvh; L = Tvl; N = 256; }
  else if (bid < 32) { W = Woff;  H = Toh; L = Tol; N = 256; bid -= 16; }
  else               { W = Wattn; H = Tah; L = Tal; N = 128; bid -= 32; }
  const int K = 256;
  __shared__ float tile[64][65];
  const int ntn = N >> 6;
  const int tk = bid / ntn, tn = bid % ntn;
  const int k0 = tk << 6, n0 = tn << 6;
  const int t   = threadIdx.x;
  const int row = t >> 2;            // 0..63
  const int cq  = (t & 3) << 4;      // 0,16,32,48
  const float* src = W + (size_t)(k0 + row) * N + n0 + cq;
#pragma unroll
  for (int j = 0; j < 16; ++j) tile[row][cq + j] = src[j];
  __syncthreads();
  const size_t d0 = (size_t)(n0 + row) * K + k0 + cq;
#pragma unroll
  for (int j = 0; j < 16; ++j) {
    float v = tile[cq + j][row];
    bf16 hb = __float2bfloat16(v);
    float r = v - __bfloat162float(hb);
    H[d0 + j] = hb;
    L[d0 + j] = __float2bfloat16(r);
  }
}

// ---------------------------------------------------------------------------
// bf16-input MFMA projection (flag==1). Verbatim R16.
// ---------------------------------------------------------------------------
template<class OT>
__global__ __launch_bounds__(256)
void k_mfma_proj(const bf16* __restrict__ A, const bf16* __restrict__ WT,
                 const void* __restrict__ bias, OT* __restrict__ C,
                 int M, int N, const int* __restrict__ flag) {
  if (*flag != 1) return;
  const int colBlocks = N >> 7;
  const int rb = (int)blockIdx.x / colBlocks;
  const int cb = (int)blockIdx.x % colBlocks;
  const int t   = threadIdx.x;
  const int wid = t >> 6;
  const int l   = t & 63;
  const int lrow = l & 15;
  const int lk8  = (l >> 4) << 3;
  const int r0 = rb * 64 + (wid & 1) * 32;
  const int c0 = cb * 128 + (wid >> 1) * 64;

  f32x4 acc[2][4];
#pragma unroll
  for (int rf = 0; rf < 2; ++rf)
#pragma unroll
    for (int cf = 0; cf < 4; ++cf) acc[rf][cf] = (f32x4){0.f, 0.f, 0.f, 0.f};

  const bf16* Ap0 = A + (size_t)min(r0 + lrow,      M - 1) * EMBED + lk8;
  const bf16* Ap1 = A + (size_t)min(r0 + 16 + lrow, M - 1) * EMBED + lk8;
  const bf16* Bp  = WT + (size_t)(c0 + lrow) * EMBED + lk8;

#pragma unroll
  for (int k = 0; k < EMBED; k += 32) {
    bf16x8s a0 = *(const bf16x8s*)(Ap0 + k);
    bf16x8s a1 = *(const bf16x8s*)(Ap1 + k);
    bf16x8s b0 = *(const bf16x8s*)(Bp + 0 * 16 * EMBED + k);
    bf16x8s b1 = *(const bf16x8s*)(Bp + 1 * 16 * EMBED + k);
    bf16x8s b2 = *(const bf16x8s*)(Bp + 2 * 16 * EMBED + k);
    bf16x8s b3 = *(const bf16x8s*)(Bp + 3 * 16 * EMBED + k);
    acc[0][0] = __builtin_amdgcn_mfma_f32_16x16x32_bf16(a0, b0, acc[0][0], 0, 0, 0);
    acc[0][1] = __builtin_amdgcn_mfma_f32_16x16x32_bf16(a0, b1, acc[0][1], 0, 0, 0);
    acc[0][2] = __builtin_amdgcn_mfma_f32_16x16x32_bf16(a0, b2, acc[0][2], 0, 0, 0);
    acc[0][3] = __builtin_amdgcn_mfma_f32_16x16x32_bf16(a0, b3, acc[0][3], 0, 0, 0);
    acc[1][0] = __builtin_amdgcn_mfma_f32_16x16x32_bf16(a1, b0, acc[1][0], 0, 0, 0);
    acc[1][1] = __builtin_amdgcn_mfma_f32_16x16x32_bf16(a1, b1, acc[1][1], 0, 0, 0);
    acc[1][2] = __builtin_amdgcn_mfma_f32_16x16x32_bf16(a1, b2, acc[1][2], 0, 0, 0);
    acc[1][3] = __builtin_amdgcn_mfma_f32_16x16x32_bf16(a1, b3, acc[1][3], 0, 0, 0);
  }

  const int rbase = (l >> 4) << 2;
#pragma unroll
  for (int cf = 0; cf < 4; ++cf) {
    const int col = c0 + cf * 16 + lrow;
    const float bv = ldf<true>(bias, col);
#pragma unroll
    for (int rf = 0; rf < 2; ++rf) {
#pragma unroll
      for (int r = 0; r < 4; ++r) {
        const int row = r0 + rf * 16 + rbase + r;
        if (row < M) stout(&C[(size_t)row * N + col], acc[rf][cf][r] + bv);
      }
    }
  }
}

// ---------------------------------------------------------------------------
// R17: f32-input split-bf16 MFMA projection, LDS-staged A (flag==0).
// Block = NW waves (NW = N/64); tile = 32 rows x N cols; WHOLE K staged once
// into As[32][260] (33KB, padded stride = 2-way max bank conflict).
// Reg-staged float4 bulk loads -> one barrier -> R13 MFMA loop from LDS.
// ---------------------------------------------------------------------------
template<int NW, class OT>
__global__ __launch_bounds__(256)
void k_mfma_projf2(const float* __restrict__ A, const bf16* __restrict__ WThi,
                   const bf16* __restrict__ WTlo, const float* __restrict__ bias,
                   OT* __restrict__ C, int M, const int* __restrict__ flag) {
  if (*flag != 0) return;
  constexpr int N = NW * 64;
  const int t   = threadIdx.x;
  const int wid = t >> 6;
  const int l   = t & 63;
  const int lrow = l & 15;
  const int lk8  = (l >> 4) << 3;
  const int r0 = (int)blockIdx.x * 32;
  const int c0 = wid * 64;

  __shared__ float As[32][260];   // 33280 B; stride 1040B = 65*16 (aligned)

  // ---- stage 32 rows x 256 f32 (each wave: rows wid, wid+NW, ...) ----
  constexpr int RPW = 32 / NW;
#pragma unroll
  for (int base = 0; base < RPW; base += 8) {
    float4 tmp[8];
#pragma unroll
    for (int i = 0; i < 8; ++i) {
      int r   = wid + (base + i) * NW;
      int row = min(r0 + r, M - 1);
      tmp[i] = *(const float4*)(A + (size_t)row * EMBED + (l << 2));
    }
#pragma unroll
    for (int i = 0; i < 8; ++i) {
      int r = wid + (base + i) * NW;
      *(float4*)&As[r][l << 2] = tmp[i];
    }
  }
  __syncthreads();

  f32x4 acc[2][4];
#pragma unroll
  for (int rf = 0; rf < 2; ++rf)
#pragma unroll
    for (int cf = 0; cf < 4; ++cf) acc[rf][cf] = (f32x4){0.f, 0.f, 0.f, 0.f};

  const bf16* Bh = WThi + (size_t)(c0 + lrow) * EMBED + lk8;
  const bf16* Bl = WTlo + (size_t)(c0 + lrow) * EMBED + lk8;

#pragma unroll
  for (int ks = 0; ks < 8; ++ks) {
    const int k = ks * 32;
    bf16x8s a0h, a0l, a1h, a1l;
    split8(*(const float4*)&As[lrow     ][k + lk8],
           *(const float4*)&As[lrow     ][k + lk8 + 4], a0h, a0l);
    split8(*(const float4*)&As[lrow + 16][k + lk8],
           *(const float4*)&As[lrow + 16][k + lk8 + 4], a1h, a1l);
    bf16x8s bh0 = *(const bf16x8s*)(Bh + 0 * 16 * EMBED + k);
    bf16x8s bh1 = *(const bf16x8s*)(Bh + 1 * 16 * EMBED + k);
    bf16x8s bh2 = *(const bf16x8s*)(Bh + 2 * 16 * EMBED + k);
    bf16x8s bh3 = *(const bf16x8s*)(Bh + 3 * 16 * EMBED + k);
    bf16x8s bl0 = *(const bf16x8s*)(Bl + 0 * 16 * EMBED + k);
    bf16x8s bl1 = *(const bf16x8s*)(Bl + 1 * 16 * EMBED + k);
    bf16x8s bl2 = *(const bf16x8s*)(Bl + 2 * 16 * EMBED + k);
    bf16x8s bl3 = *(const bf16x8s*)(Bl + 3 * 16 * EMBED + k);
    // hi*hi
    acc[0][0] = __builtin_amdgcn_mfma_f32_16x16x32_bf16(a0h, bh0, acc[0][0], 0, 0, 0);
    acc[0][1] = __builtin_amdgcn_mfma_f32_16x16x32_bf16(a0h, bh1, acc[0][1], 0, 0, 0);
    acc[0][2] = __builtin_amdgcn_mfma_f32_16x16x32_bf16(a0h, bh2, acc[0][2], 0, 0, 0);
    acc[0][3] = __builtin_amdgcn_mfma_f32_16x16x32_bf16(a0h, bh3, acc[0][3], 0, 0, 0);
    acc[1][0] = __builtin_amdgcn_mfma_f32_16x16x32_bf16(a1h, bh0, acc[1][0], 0, 0, 0);
    acc[1][1] = __builtin_amdgcn_mfma_f32_16x16x32_bf16(a1h, bh1, acc[1][1], 0, 0, 0);
    acc[1][2] = __builtin_amdgcn_mfma_f32_16x16x32_bf16(a1h, bh2, acc[1][2], 0, 0, 0);
    acc[1][3] = __builtin_amdgcn_mfma_f32_16x16x32_bf16(a1h, bh3, acc[1][3], 0, 0, 0);
    // hi*lo
    acc[0][0] = __builtin_amdgcn_mfma_f32_16x16x32_bf16(a0h, bl0, acc[0][0], 0, 0, 0);
    acc[0][1] = __builtin_amdgcn_mfma_f32_16x16x32_bf16(a0h, bl1, acc[0][1], 0, 0, 0);
    acc[0][2] = __builtin_amdgcn_mfma_f32_16x16x32_bf16(a0h, bl2, acc[0][2], 0, 0, 0);
    acc[0][3] = __builtin_amdgcn_mfma_f32_16x16x32_bf16(a0h, bl3, acc[0][3], 0, 0, 0);
    acc[1][0] = __builtin_amdgcn_mfma_f32_16x16x32_bf16(a1h, bl0, acc[1][0], 0, 0, 0);
    acc[1][1] = __builtin_amdgcn_mfma_f32_16x16x32_bf16(a1h, bl1, acc[1][1], 0, 0, 0);
    acc[1][2] = __builtin_amdgcn_mfma_f32_16x16x32_bf16(a1h, bl2, acc[1][2], 0, 0, 0);
    acc[1][3] = __builtin_amdgcn_mfma_f32_16x16x32_bf16(a1h, bl3, acc[1][3], 0, 0, 0);
    // lo*hi
    acc[0][0] = __builtin_amdgcn_mfma_f32_16x16x32_bf16(a0l, bh0, acc[0][0], 0, 0, 0);
    acc[0][1] = __builtin_amdgcn_mfma_f32_16x16x32_bf16(a0l, bh1, acc[0][1], 0, 0, 0);
    acc[0][2] = __builtin_amdgcn_mfma_f32_16x16x32_bf16(a0l, bh2, acc[0][2], 0, 0, 0);
    acc[0][3] = __builtin_amdgcn_mfma_f32_16x16x32_bf16(a0l, bh3, acc[0][3], 0, 0, 0);
    acc[1][0] = __builtin_amdgcn_mfma_f32_16x16x32_bf16(a1l, bh0, acc[1][0], 0, 0, 0);
    acc[1][1] = __builtin_amdgcn_mfma_f32_16x16x32_bf16(a1l, bh1, acc[1][1], 0, 0, 0);
    acc[1][2] = __builtin_amdgcn_mfma_f32_16x16x32_bf16(a1l, bh2, acc[1][2], 0, 0, 0);
    acc[1][3] = __builtin_amdgcn_mfma_f32_16x16x32_bf16(a1l, bh3, acc[1][3], 0, 0, 0);
  }

  const int rbase = (l >> 4) << 2;
#pragma unroll
  for (int cf = 0; cf < 4; ++cf) {
    const int col = c0 + cf * 16 + lrow;
    const float bv = bias[col];
#pragma unroll
    for (int rf = 0; rf < 2; ++rf) {
#pragma unroll
      for (int r = 0; r < 4; ++r) {
        const int row = r0 + rf * 16 + rbase + r;
        if (row < M) stout(&C[(size_t)row * N + col], acc[rf][cf][r] + bv);
      }
    }
  }
}

// ---------------------------------------------------------------------------
// shared staging: 16 rows of A (EMBED cols) into padded LDS tile (R11)
// ---------------------------------------------------------------------------
template<bool BF>
__device__ __forceinline__ void stage16(const void* __restrict__ A,
                                        float (*rowA)[LDP],
                                        int r0, int M, int t) {
  int r  = t >> 4;
  int rr = min(r0 + r, M - 1);
  int c0 = (t & 15) * 16;
  if (BF) {
    const bf16* ap = (const bf16*)A + (size_t)rr * EMBED + c0;
    short8 a0 = *(const short8*)ap;
    short8 a1 = *(const short8*)(ap + 8);
#pragma unroll
    for (int j = 0; j < 8; ++j) {
      short s0 = a0[j], s1 = a1[j];
      rowA[r][c0 + j]     = __bfloat162float(*reinterpret_cast<bf16*>(&s0));
      rowA[r][c0 + 8 + j] = __bfloat162float(*reinterpret_cast<bf16*>(&s1));
    }
  } else {
    const float* ap = (const float*)A + (size_t)rr * EMBED + c0;
#pragma unroll
    for (int j = 0; j < 4; ++j) {
      float4 f = *(const float4*)(ap + j * 4);
      rowA[r][c0 + j * 4 + 0] = f.x;
      rowA[r][c0 + j * 4 + 1] = f.y;
      rowA[r][c0 + j * 4 + 2] = f.z;
      rowA[r][c0 + j * 4 + 3] = f.w;
    }
  }
}

// ---------------------------------------------------------------------------
// R11 tier kernels (need_full fallback): 4x4 / 2x4 register-blocked GEMVs.
// ---------------------------------------------------------------------------
template<bool BF>
__device__ void vgemv4x4_body(const void* __restrict__ A, const void* __restrict__ W,
                              const void* __restrict__ bias, float* __restrict__ C,
                              int M) {
  const int t  = threadIdx.x;
  const int r0 = blockIdx.x * 16;
  if (r0 >= M) return;

  __shared__ float rowA[16][LDP];
  stage16<BF>(A, rowA, r0, M, t);
  __syncthreads();

  const int g  = t >> 6;
  const int c0 = (t & 63) * 4;

  float4 bv;
  bv.x = ldf<BF>(bias, c0 + 0);
  bv.y = ldf<BF>(bias, c0 + 1);
  bv.z = ldf<BF>(bias, c0 + 2);
  bv.w = ldf<BF>(bias, c0 + 3);

  float4 acc[4];
#pragma unroll
  for (int r = 0; r < 4; ++r) acc[r] = bv;

#pragma unroll 2
  for (int k = 0; k < EMBED; k += 4) {
    float4 av[4];
#pragma unroll
    for (int r = 0; r < 4; ++r)
      av[r] = *(const float4*)&rowA[g * 4 + r][k];
    float4 w0 = ld4<BF>(W, (size_t)(k + 0) * EMBED + c0);
    float4 w1 = ld4<BF>(W, (size_t)(k + 1) * EMBED + c0);
    float4 w2 = ld4<BF>(W, (size_t)(k + 2) * EMBED + c0);
    float4 w3 = ld4<BF>(W, (size_t)(k + 3) * EMBED + c0);
#pragma unroll
    for (int r = 0; r < 4; ++r) {
      fma4(acc[r], av[r].x, w0);
      fma4(acc[r], av[r].y, w1);
      fma4(acc[r], av[r].z, w2);
      fma4(acc[r], av[r].w, w3);
    }
  }
#pragma unroll
  for (int r = 0; r < 4; ++r) {
    int row = r0 + g * 4 + r;
    if (row < M) *(float4*)&C[(size_t)row * EMBED + c0] = acc[r];
  }
}

__global__ __launch_bounds__(256)
void k_vgemv4x4(const void* A, const void* W, const void* bias, float* C,
                int M, const int* flag) {
  if (*flag) vgemv4x4_body<true >(A, W, bias, C, M);
  else       vgemv4x4_body<false>(A, W, bias, C, M);
}

template<bool BF>
__device__ void agemv4_body(const void* __restrict__ A, const void* __restrict__ W,
                            const void* __restrict__ bias, float* __restrict__ C,
                            int M) {
  const int t  = threadIdx.x;
  const int r0 = blockIdx.x * 16;
  if (r0 >= M) return;

  __shared__ float rowA[16][LDP];
  stage16<BF>(A, rowA, r0, M, t);
  __syncthreads();

  const int g  = t >> 5;
  const int c0 = (t & 31) * 4;

  float4 bv;
  bv.x = ldf<BF>(bias, c0 + 0);
  bv.y = ldf<BF>(bias, c0 + 1);
  bv.z = ldf<BF>(bias, c0 + 2);
  bv.w = ldf<BF>(bias, c0 + 3);

  float4 acc[2];
  acc[0] = bv; acc[1] = bv;

#pragma unroll 2
  for (int k = 0; k < EMBED; k += 4) {
    float4 a0 = *(const float4*)&rowA[g * 2 + 0][k];
    float4 a1 = *(const float4*)&rowA[g * 2 + 1][k];
    float4 w0 = ld4<BF>(W, (size_t)(k + 0) * 128 + c0);
    float4 w1 = ld4<BF>(W, (size_t)(k + 1) * 128 + c0);
    float4 w2 = ld4<BF>(W, (size_t)(k + 2) * 128 + c0);
    float4 w3 = ld4<BF>(W, (size_t)(k + 3) * 128 + c0);
    fma4(acc[0], a0.x, w0); fma4(acc[0], a0.y, w1);
    fma4(acc[0], a0.z, w2); fma4(acc[0], a0.w, w3);
    fma4(acc[1], a1.x, w0); fma4(acc[1], a1.y, w1);
    fma4(acc[1], a1.z, w2); fma4(acc[1], a1.w, w3);
  }
#pragma unroll
  for (int r = 0; r < 2; ++r) {
    int row = r0 + g * 2 + r;
    if (row < M) *(float4*)&C[(size_t)row * 128 + c0] = acc[r];
  }
}

__global__ __launch_bounds__(256)
void k_agemv4(const void* A, const void* W, const void* bias, float* C,
              int M, const int* flag) {
  if (*flag) agemv4_body<true >(A, W, bias, C, M);
  else       agemv4_body<false>(A, W, bias, C, M);
}

// ---------------------------------------------------------------------------
// R17 k_fused2: softmax+pack (t<128) + 2-channels-per-lane gather.
// 256 thr = (combo-half s) x (128 channel-pairs). 32 x 4B loads/thread.
// ---------------------------------------------------------------------------
template<bool BF, class VT>
__device__ void fused2_body(const void* __restrict__ ref_points,
                            const float* __restrict__ off_pre,
                            const float* __restrict__ scores,
                            const VT* __restrict__ v,
                            void* __restrict__ out, int N, int BN) {
  int q = blockIdx.x;
  if (q >= BN) return;
  int b = q / N;
  int t = threadIdx.x;

  __shared__ float  s_aw[128];
  __shared__ float  s_rp[2];
  __shared__ int4   s_pi[128];    // corner element index (cell<<8)
  __shared__ float4 s_pw[128];    // wa * bilinear * valid
  __shared__ float  s_part[2][256];

  if (t < 2)   s_rp[t] = ldf<BF>(ref_points, (size_t)q * 2 + t);
  if (t < 128) s_aw[t] = scores[(size_t)q * 128 + t];
  __syncthreads();

  if (t < 128) {
    int base = t & ~15;
    float mx = -1e30f;
#pragma unroll
    for (int i = 0; i < 16; ++i) mx = fmaxf(mx, s_aw[base + i]);
    float sum = 0.f;
#pragma unroll
    for (int i = 0; i < 16; ++i) sum += expf(s_aw[base + i] - mx);
    float wa = expf(s_aw[t] - mx) / sum;

    int   l  = (t >> 2) & 3;
    int   Wl = 128 >> l;                       // levels are square
    float fW = (float)Wl;
    int   st = (int)((65536u - (65536u >> (2 * l))) / 3u);  // level start
    float ox = off_pre[(size_t)q * EMBED + 2 * t]     - 0.5f;
    float oy = off_pre[(size_t)q * EMBED + 2 * t + 1] - 0.5f;
    float x = fmaf(s_rp[0], fW, ox);
    float y = fmaf(s_rp[1], fW, oy);
    float x0f = floorf(x), y0f = floorf(y);
    float lx = x - x0f, ly = y - y0f;
    int x0 = (int)x0f, y0 = (int)y0f;
    int x1 = x0 + 1,   y1 = y0 + 1;
    float w00 = wa * (1.f - lx) * (1.f - ly);
    float w01 = wa * lx * (1.f - ly);
    float w10 = wa * (1.f - lx) * ly;
    float w11 = wa * lx * ly;
    bool vx0 = (unsigned)x0 < (unsigned)Wl;
    bool vx1 = (unsigned)x1 < (unsigned)Wl;
    bool vy0 = (unsigned)y0 < (unsigned)Wl;
    bool vy1 = (unsigned)y1 < (unsigned)Wl;
    int xc0 = min(max(x0, 0), Wl - 1), xc1 = min(max(x1, 0), Wl - 1);
    int yc0 = min(max(y0, 0), Wl - 1), yc1 = min(max(y1, 0), Wl - 1);
    int r0i = st + yc0 * Wl;
    int r1i = st + yc1 * Wl;
    int4 pi; float4 pw;
    pi.x = (r0i + xc0) << 8;  pw.x = (vx0 && vy0) ? w00 : 0.f;
    pi.y = (r0i + xc1) << 8;  pw.y = (vx1 && vy0) ? w01 : 0.f;
    pi.z = (r1i + xc0) << 8;  pw.z = (vx0 && vy1) ? w10 : 0.f;
    pi.w = (r1i + xc1) << 8;  pw.w = (vx1 && vy1) ? w11 : 0.f;
    s_pi[t] = pi;
    s_pw[t] = pw;
  }
  __syncthreads();

  // gather: lane owns channels (2c, 2c+1); half s owns 8 of the 16 combos
  const int c  = t & 127;
  const int s  = t >> 7;
  const int h  = c >> 4;
  const int ch = c << 1;
  const VT* vb = v + (size_t)b * (M_TOT * EMBED) + ch;
  const int cbase = (h << 4) + (s << 3);

  float oL0 = 0.f, oH0 = 0.f, oL1 = 0.f, oH1 = 0.f;
#pragma unroll
  for (int g = 0; g < 2; ++g) {
    const int c0 = cbase + (g << 2);
    int4   iA = s_pi[c0 + 0], iB = s_pi[c0 + 1], iC = s_pi[c0 + 2], iD = s_pi[c0 + 3];
    float4 wA = s_pw[c0 + 0], wB = s_pw[c0 + 1], wC = s_pw[c0 + 2], wD = s_pw[c0 + 3];
    float lA0,hA0,lA1,hA1,lA2,hA2,lA3,hA3;
    float lB0,hB0,lB1,hB1,lB2,hB2,lB3,hB3;
    float lC0,hC0,lC1,hC1,lC2,hC2,lC3,hC3;
    float lD0,hD0,lD1,hD1,lD2,hD2,lD3,hD3;
    ld2c(vb + iA.x, lA0, hA0); ld2c(vb + iA.y, lA1, hA1);
    ld2c(vb + iA.z, lA2, hA2); ld2c(vb + iA.w, lA3, hA3);
    ld2c(vb + iB.x, lB0, hB0); ld2c(vb + iB.y, lB1, hB1);
    ld2c(vb + iB.z, lB2, hB2); ld2c(vb + iB.w, lB3, hB3);
    ld2c(vb + iC.x, lC0, hC0); ld2c(vb + iC.y, lC1, hC1);
    ld2c(vb + iC.z, lC2, hC2); ld2c(vb + iC.w, lC3, hC3);
    ld2c(vb + iD.x, lD0, hD0); ld2c(vb + iD.y, lD1, hD1);
    ld2c(vb + iD.z, lD2, hD2); ld2c(vb + iD.w, lD3, hD3);
    oL0 = fmaf(wA.x, lA0, oL0); oH0 = fmaf(wA.x, hA0, oH0);
    oL1 = fmaf(wA.y, lA1, oL1); oH1 = fmaf(wA.y, hA1, oH1);
    oL0 = fmaf(wA.z, lA2, oL0); oH0 = fmaf(wA.z, hA2, oH0);
    oL1 = fmaf(wA.w, lA3, oL1); oH1 = fmaf(wA.w, hA3, oH1);
    oL0 = fmaf(wB.x, lB0, oL0); oH0 = fmaf(wB.x, hB0, oH0);
    oL1 = fmaf(wB.y, lB1, oL1); oH1 = fmaf(wB.y, hB1, oH1);
    oL0 = fmaf(wB.z, lB2, oL0); oH0 = fmaf(wB.z, hB2, oH0);
    oL1 = fmaf(wB.w, lB3, oL1); oH1 = fmaf(wB.w, hB3, oH1);
    oL0 = fmaf(wC.x, lC0, oL0); oH0 = fmaf(wC.x, hC0, oH0);
    oL1 = fmaf(wC.y, lC1, oL1); oH1 = fmaf(wC.y, hC1, oH1);
    oL0 = fmaf(wC.z, lC2, oL0); oH0 = fmaf(wC.z, hC2, oH0);
    oL1 = fmaf(wC.w, lC3, oL1); oH1 = fmaf(wC.w, hC3, oH1);
    oL0 = fmaf(wD.x, lD0, oL0); oH0 = fmaf(wD.x, hD0, oH0);
    oL1 = fmaf(wD.y, lD1, oL1); oH1 = fmaf(wD.y, hD1, oH1);
    oL0 = fmaf(wD.z, lD2, oL0); oH0 = fmaf(wD.z, hD2, oH0);
    oL1 = fmaf(wD.w, lD3, oL1); oH1 = fmaf(wD.w, hD3, oH1);
  }
  s_part[s][ch]     = oL0 + oL1;
  s_part[s][ch + 1] = oH0 + oH1;
  __syncthreads();

  float o = s_part[0][t] + s_part[1][t];
  if (BF) ((bf16*)out)[(size_t)q * EMBED + t] = __float2bfloat16(o);
  else    ((float*)out)[(size_t)q * EMBED + t] = o;
}

template<class VT>
__global__ __launch_bounds__(256)
void k_fused2(const void* ref_points, const float* off_pre, const float* scores,
              const VT* v, void* out, int N, int BN, const int* flag) {
  if (*flag) fused2_body<true,  VT>(ref_points, off_pre, scores, v, out, N, BN);
  else       fused2_body<false, VT>(ref_points, off_pre, scores, v, out, N, BN);
}

// ---------------------------------------------------------------------------
// MID TIER (R8, proven): 8-row GEMV + fused with in-kernel attn GEMV.
// ---------------------------------------------------------------------------
template<bool BF>
__device__ void vgemv8_body(const void* __restrict__ A, const void* __restrict__ W,
                            const void* __restrict__ bias, float* __restrict__ C,
                            int M) {
  const int t  = threadIdx.x;
  const int r0 = blockIdx.x * 8;
  if (r0 >= M) return;

  __shared__ float rowA[8][EMBED];
  {
    int r  = t >> 5;
    int rr = min(r0 + r, M - 1);
    int c0 = (t & 31) * 8;
    if (BF) {
      const bf16* ap = (const bf16*)A + (size_t)rr * EMBED + c0;
      short8 a = *(const short8*)ap;
#pragma unroll
      for (int j = 0; j < 8; ++j) {
        short s = a[j];
        bf16 hb = *reinterpret_cast<bf16*>(&s);
        rowA[r][c0 + j] = __bfloat162float(hb);
      }
    } else {
      const float* ap = (const float*)A + (size_t)rr * EMBED + c0;
#pragma unroll
      for (int j = 0; j < 8; ++j) rowA[r][c0 + j] = ap[j];
    }
  }
  __syncthreads();

  const int n = t;
  const float b = ldf<BF>(bias, n);
  float acc[8];
#pragma unroll
  for (int r = 0; r < 8; ++r) acc[r] = b;
#pragma unroll 4
  for (int k = 0; k < EMBED; ++k) {
    float w = ldf<BF>(W, (size_t)k * EMBED + n);
#pragma unroll
    for (int r = 0; r < 8; ++r) acc[r] = fmaf(rowA[r][k], w, acc[r]);
  }
#pragma unroll
  for (int r = 0; r < 8; ++r)
    if (r0 + r < M) C[(size_t)(r0 + r) * EMBED + n] = acc[r];
}

__global__ __launch_bounds__(256)
void k_vgemv8(const void* A, const void* W, const void* bias, float* C,
              int M, const int* flag) {
  if (*flag) vgemv8_body<true >(A, W, bias, C, M);
  else       vgemv8_body<false>(A, W, bias, C, M);
}

template<bool BF, class VT>
__device__ void fused_body(const void* __restrict__ query,
                           const void* __restrict__ ref_points,
                           const float* __restrict__ off_pre,
                           const void* __restrict__ W_attn,
                           const void* __restrict__ b_attn,
                           const VT* __restrict__ v,
                           void* __restrict__ out, int N, int BN) {
  int q = blockIdx.x;
  if (q >= BN) return;
  int b = q / N;
  int t = threadIdx.x;

  __shared__ float  row[EMBED];
  __shared__ float  s_part[256];
  __shared__ float  s_aw[HEADS * LEVELS * POINTS];
  __shared__ float  s_rp[2];
  __shared__ int4   s_pi[HEADS * LEVELS * POINTS];
  __shared__ float4 s_pw[HEADS * LEVELS * POINTS];

  row[t] = ldf<BF>(query, (size_t)q * EMBED + t);
  if (t < 2) s_rp[t] = ldf<BF>(ref_points, (size_t)q * 2 + t);
  __syncthreads();

  {
    const int col = t & 127;
    const int e0  = (t >> 7) * 128;
    float acc = 0.f;
#pragma unroll 8
    for (int e = 0; e < 128; ++e)
      acc = fmaf(row[e0 + e], ldf<BF>(W_attn, (size_t)(e0 + e) * 128 + col), acc);
    s_part[t] = acc;
  }
  __syncthreads();
  if (t < 128)
    s_aw[t] = ldf<BF>(b_attn, t) + s_part[t] + s_part[t + 128];
  __syncthreads();

  if (t < 128) {
    int base = t & ~15;
    float mx = -1e30f;
#pragma unroll
    for (int i = 0; i < 16; ++i) mx = fmaxf(mx, s_aw[base + i]);
    float sum = 0.f;
#pragma unroll
    for (int i = 0; i < 16; ++i) sum += expf(s_aw[base + i] - mx);
    float wa = expf(s_aw[t] - mx) / sum;

    int   l  = (t >> 2) & 3;
    int   Wl = 128 >> l;
    float fW = (float)Wl;
    int   st = (int)((65536u - (65536u >> (2 * l))) / 3u);
    float ox = off_pre[(size_t)q * EMBED + 2 * t]     - 0.5f;
    float oy = off_pre[(size_t)q * EMBED + 2 * t + 1] - 0.5f;
    float x = fmaf(s_rp[0], fW, ox);
    float y = fmaf(s_rp[1], fW, oy);
    float x0f = floorf(x), y0f = floorf(y);
    float lx = x - x0f, ly = y - y0f;
    int x0 = (int)x0f, y0 = (int)y0f;
    int x1 = x0 + 1,   y1 = y0 + 1;
    float w00 = wa * (1.f - lx) * (1.f - ly);
    float w01 = wa * lx * (1.f - ly);
    float w10 = wa * (1.f - lx) * ly;
    float w11 = wa * lx * ly;
    bool vx0 = (unsigned)x0 < (unsigned)Wl;
    bool vx1 = (unsigned)x1 < (unsigned)Wl;
    bool vy0 = (unsigned)y0 < (unsigned)Wl;
    bool vy1 = (unsigned)y1 < (unsigned)Wl;
    int xc0 = min(max(x0, 0), Wl - 1), xc1 = min(max(x1, 0), Wl - 1);
    int yc0 = min(max(y0, 0), Wl - 1), yc1 = min(max(y1, 0), Wl - 1);
    int r0i = st + yc0 * Wl;
    int r1i = st + yc1 * Wl;
    int4 pi; float4 pw;
    pi.x = (r0i + xc0) << 8;  pw.x = (vx0 && vy0) ? w00 : 0.f;
    pi.y = (r0i + xc1) << 8;  pw.y = (vx1 && vy0) ? w01 : 0.f;
    pi.z = (r1i + xc0) << 8;  pw.z = (vx0 && vy1) ? w10 : 0.f;
    pi.w = (r1i + xc1) << 8;  pw.w = (vx1 && vy1) ? w11 : 0.f;
    s_pi[t] = pi;
    s_pw[t] = pw;
  }
  __syncthreads();

  const int h = t >> 5;
  const VT* vbt = v + (size_t)b * M_TOT * EMBED + t;
  float o = 0.f;
#pragma unroll
  for (int lp = 0; lp < 16; ++lp) {
    int c = (h << 4) + lp;
    int4   i4 = s_pi[c];
    float4 w4 = s_pw[c];
    o = fmaf(w4.x, vt2f(vbt[i4.x]), o);
    o = fmaf(w4.y, vt2f(vbt[i4.y]), o);
    o = fmaf(w4.z, vt2f(vbt[i4.z]), o);
    o = fmaf(w4.w, vt2f(vbt[i4.w]), o);
  }
  if (BF) ((bf16*)out)[(size_t)q * EMBED + t] = __float2bfloat16(o);
  else    ((float*)out)[(size_t)q * EMBED + t] = o;
}

template<class VT>
__global__ __launch_bounds__(256)
void k_fused(const void* query, const void* ref_points, const float* off_pre,
             const void* W_attn, const void* b_attn,
             const VT* v, void* out, int N, int BN, const int* flag) {
  if (*flag) fused_body<true,  VT>(query, ref_points, off_pre, W_attn, b_attn, v, out, N, BN);
  else       fused_body<false, VT>(query, ref_points, off_pre, W_attn, b_attn, v, out, N, BN);
}

// ---------------------------------------------------------------------------
// Fallback path (ws too small): R2/R6's bf16 fused path, fully self-contained.
// ---------------------------------------------------------------------------
template<bool BF, class VT>
__device__ void vproj_body(const void* __restrict__ value,
                           const void* __restrict__ W_v,
                           const void* __restrict__ b_v,
                           VT* __restrict__ v, int BM) {
  int m = blockIdx.x;
  if (m >= BM) return;
  int t = threadIdx.x;
  __shared__ float row[EMBED];
  row[t] = ldf<BF>(value, (size_t)m * EMBED + t);
  __syncthreads();
  float acc = ldf<BF>(b_v, t);
#pragma unroll 8
  for (int e = 0; e < EMBED; ++e)
    acc = fmaf(row[e], ldf<BF>(W_v, (size_t)e * EMBED + t), acc);
  if (sizeof(VT) == 2) ((bf16*)v)[(size_t)m * EMBED + t] = __float2bfloat16(acc);
  else                 ((float*)v)[(size_t)m * EMBED + t] = acc;
}

template<class VT>
__global__ __launch_bounds__(256)
void k_value_proj(const void* value, const void* W_v, const void* b_v,
                  VT* v, int BM, const int* flag) {
  if (*flag) vproj_body<true,  VT>(value, W_v, b_v, v, BM);
  else       vproj_body<false, VT>(value, W_v, b_v, v, BM);
}

template<bool BF, class VT>
__device__ void fusedfb_body(const void* __restrict__ query,
                             const void* __restrict__ ref_points,
                             const void* __restrict__ W_off,
                             const void* __restrict__ b_off,
                             const void* __restrict__ W_attn,
                             const void* __restrict__ b_attn,
                             const VT* __restrict__ v,
                             void* __restrict__ out, int N, int BN) {
  int q = blockIdx.x;
  if (q >= BN) return;
  int b = q / N;
  int t = threadIdx.x;

  __shared__ float row[EMBED];
  __shared__ float s_off[EMBED];
  __shared__ float s_aw[HEADS * LEVELS * POINTS];
  __shared__ float s_rp[2];

  row[t] = ldf<BF>(query, (size_t)q * EMBED + t);
  if (t < 2) s_rp[t] = ldf<BF>(ref_points, (size_t)q * 2 + t);
  __syncthreads();

  {
    float acc = ldf<BF>(b_off, t);
#pragma unroll 8
    for (int e = 0; e < EMBED; ++e)
      acc = fmaf(row[e], ldf<BF>(W_off, (size_t)e * EMBED + t), acc);
    s_off[t] = acc;
  }
  if (t < 128) {
    float acc = ldf<BF>(b_attn, t);
#pragma unroll 8
    for (int e = 0; e < EMBED; ++e)
      acc = fmaf(row[e], ldf<BF>(W_attn, (size_t)e * 128 + t), acc);
    s_aw[t] = acc;
  }
  __syncthreads();

  float aval = 0.f;
  if (t < 128) {
    int base = t & ~15;
    float mx = -1e30f;
#pragma unroll
    for (int i = 0; i < 16; ++i) mx = fmaxf(mx, s_aw[base + i]);
    float sum = 0.f;
#pragma unroll
    for (int i = 0; i < 16; ++i) sum += expf(s_aw[base + i] - mx);
    aval = expf(s_aw[t] - mx) / sum;
  }
  __syncthreads();
  if (t < 128) s_aw[t] = aval;
  __syncthreads();

  int h = t >> 5;
  const VT* vb = v + (size_t)b * M_TOT * EMBED;
  float o = 0.f;
#pragma unroll
  for (int l = 0; l < LEVELS; ++l) {
    const int Hl = c_H[l], Wl = c_H[l];
    const VT* vl = vb + (size_t)c_St[l] * EMBED;
    const float fW = (float)Wl, fH = (float)Hl;
#pragma unroll
    for (int p = 0; p < POINTS; ++p) {
      int oi = ((h * LEVELS + l) * POINTS + p) << 1;
      float x = (s_rp[0] + s_off[oi]     / fW) * fW - 0.5f;
      float y = (s_rp[1] + s_off[oi + 1] / fH) * fH - 0.5f;
      float x0f = floorf(x), y0f = floorf(y);
      float lx = x - x0f, ly = y - y0f;
      int x0 = (int)x0f, y0 = (int)y0f;
      float wa = s_aw[(h * LEVELS + l) * POINTS + p];
      float cw[4] = {(1.f - lx) * (1.f - ly), lx * (1.f - ly),
                     (1.f - lx) * ly,         lx * ly};
      const int dxs[4] = {0, 1, 0, 1};
      const int dys[4] = {0, 0, 1, 1};
#pragma unroll
      for (int cidx = 0; cidx < 4; ++cidx) {
        int xi = x0 + dxs[cidx];
        int yi = y0 + dys[cidx];
        bool valid = (xi >= 0) & (xi < Wl) & (yi >= 0) & (yi < Hl);
        int xc = min(max(xi, 0), Wl - 1);
        int yc = min(max(yi, 0), Hl - 1);
        float g = vt2f(vl[(size_t)(yc * Wl + xc) * EMBED + t]);
        o += (valid ? wa * cw[cidx] : 0.f) * g;
      }
    }
  }
  if (BF) ((bf16*)out)[(size_t)q * EMBED + t] = __float2bfloat16(o);
  else    ((float*)out)[(size_t)q * EMBED + t] = o;
}

template<class VT>
__global__ __launch_bounds__(256)
void k_fused_fb(const void* query, const void* ref_points,
                const void* W_off, const void* b_off,
                const void* W_attn, const void* b_attn,
                const VT* v, void* out, int N, int BN, const int* flag) {
  if (*flag) fusedfb_body<true,  VT>(query, ref_points, W_off, b_off, W_attn, b_attn, v, out, N, BN);
  else       fusedfb_body<false, VT>(query, ref_points, W_off, b_off, W_attn, b_attn, v, out, N, BN);
}

// ---------------------------------------------------------------------------
extern "C" void kernel_launch(void* const* d_in, const int* in_sizes, int n_in,
                              void* d_out, int out_size, void* d_ws, size_t ws_size,
                              hipStream_t stream) {
  const void* query      = d_in[0];
  const void* value      = d_in[2];
  const void* ref_points = d_in[3];
  const void* W_off  = d_in[6];
  const void* b_off  = d_in[7];
  const void* W_attn = d_in[8];
  const void* b_attn = d_in[9];
  const void* W_v    = d_in[10];
  const void* b_v    = d_in[11];

  const int BN = in_sizes[0] / EMBED;   // 20000
  const int BM = in_sizes[2] / EMBED;   // 43520
  const int N  = BN / BATCH;

  int*  flag    = (int*)d_ws;
  char* ws_base = (char*)d_ws + 256;

  k_detect<<<1, 256, 0, stream>>>((const unsigned short*)query, flag);

  const size_t sz_v    = (size_t)BM * EMBED * sizeof(float);  // layout slot (v used as bf16)
  const size_t sz_off  = (size_t)BN * EMBED * sizeof(float);
  const size_t sz_attn = (size_t)BN * 128 * sizeof(float);
  // weight-transform area (union of bf16 path 320KB and f32 hi/lo path 640KB)
  const size_t sz_T    = (size_t)(256 * 256 * 2 + 256 * 128) * 2 /*hi+lo*/ * 2;
  const size_t need_mfma = 256 + sz_v + sz_off + sz_attn + sz_T;
  const size_t need_full = 256 + sz_v + sz_off + sz_attn;
  const size_t need_mid  = 256 + sz_v + sz_off;

  if (ws_size >= need_mfma) {
    bf16*  ws_v    = (bf16*)ws_base;                    // v stored as bf16 (22.3MB)
    float* ws_off  = (float*)(ws_base + sz_v);
    float* ws_attn = (float*)(ws_base + sz_v + sz_off);
    unsigned short* wsT = (unsigned short*)(ws_base + sz_v + sz_off + sz_attn);
    // bf16 path layout
    unsigned short* wsT_v    = wsT;
    unsigned short* wsT_off  = wsT + 256 * 256;
    unsigned short* wsT_attn = wsT + 2 * 256 * 256;
    // f32 path layout (same area; only one path runs)
    bf16* Tvh = (bf16*)wsT;
    bf16* Tvl = Tvh + 256 * 256;
    bf16* Toh = Tvl + 256 * 256;
    bf16* Tol = Toh + 256 * 256;
    bf16* Tah = Tol + 256 * 256;
    bf16* Tal = Tah + 256 * 128;

    // bf16 path (flag==1): 64-row blocks, direct-global (R12 proven form)
    const int rbV64 = (BM + 63) / 64;
    const int rbQ64 = (BN + 63) / 64;
    k_transpose_bf16<<<16, 256, 0, stream>>>((const unsigned short*)W_v,    wsT_v,    256, 256, flag);
    k_transpose_bf16<<<16, 256, 0, stream>>>((const unsigned short*)W_off,  wsT_off,  256, 256, flag);
    k_transpose_bf16<<< 8, 256, 0, stream>>>((const unsigned short*)W_attn, wsT_attn, 256, 128, flag);
    k_mfma_proj<bf16 ><<<rbV64 * 2, 256, 0, stream>>>((const bf16*)value, (const bf16*)wsT_v,
                                                      b_v, ws_v, BM, 256, flag);
    k_mfma_proj<float><<<rbQ64 * 2, 256, 0, stream>>>((const bf16*)query, (const bf16*)wsT_off,
                                                      b_off, ws_off, BN, 256, flag);
    k_mfma_proj<float><<<rbQ64,     256, 0, stream>>>((const bf16*)query, (const bf16*)wsT_attn,
                                                      b_attn, ws_attn, BN, 128, flag);

    // f32 path (flag==0): LDS-staged split-bf16 MFMA, 32-row blocks
    const int gV32 = (BM + 31) / 32;   // 1360
    const int gQ32 = (BN + 31) / 32;   // 625
    k_wsplit_all<<<40, 256, 0, stream>>>((const float*)W_v, (const float*)W_off,
                                         (const float*)W_attn,
                                         Tvh, Tvl, Toh, Tol, Tah, Tal, flag);
    k_mfma_projf2<4, bf16 ><<<gV32, 256, 0, stream>>>((const float*)value, Tvh, Tvl,
                                                      (const float*)b_v, ws_v, BM, flag);
    k_mfma_projf2<4, float><<<gQ32, 256, 0, stream>>>((const float*)query, Toh, Tol,
                                                      (const float*)b_off, ws_off, BN, flag);
    k_mfma_projf2<2, float><<<gQ32, 128, 0, stream>>>((const float*)query, Tah, Tal,
                                                      (const float*)b_attn, ws_attn, BN, flag);

    k_fused2<bf16><<<BN, 256, 0, stream>>>(ref_points, ws_off, ws_attn, ws_v,
                                           d_out, N, BN, flag);
  } else if (ws_size >= need_full) {
    float* ws_v    = (float*)ws_base;
    float* ws_off  = (float*)(ws_base + sz_v);
    float* ws_attn = (float*)(ws_base + sz_v + sz_off);
    k_vgemv4x4<<<(BM + 15) / 16, 256, 0, stream>>>(value, W_v, b_v, ws_v, BM, flag);
    k_vgemv4x4<<<(BN + 15) / 16, 256, 0, stream>>>(query, W_off, b_off, ws_off, BN, flag);
    k_agemv4<<<(BN + 15) / 16, 256, 0, stream>>>(query, W_attn, b_attn, ws_attn, BN, flag);
    k_fused2<float><<<BN, 256, 0, stream>>>(ref_points, ws_off, ws_attn, ws_v,
                                            d_out, N, BN, flag);
  } else if (ws_size >= need_mid) {
    float* ws_v   = (float*)ws_base;
    float* ws_off = (float*)(ws_base + sz_v);
    k_vgemv8<<<(BM + 7) / 8, 256, 0, stream>>>(value, W_v, b_v, ws_v, BM, flag);
    k_vgemv8<<<(BN + 7) / 8, 256, 0, stream>>>(query, W_off, b_off, ws_off, BN, flag);
    k_fused<float><<<BN, 256, 0, stream>>>(query, ref_points, ws_off,
                                           W_attn, b_attn, ws_v, d_out, N, BN, flag);
  } else {
    bf16* ws_v = (bf16*)ws_base;
    k_value_proj<bf16><<<BM, 256, 0, stream>>>(value, W_v, b_v, ws_v, BM, flag);
    k_fused_fb<bf16><<<BN, 256, 0, stream>>>(query, ref_points, W_off, b_off,
                                             W_attn, b_attn, ws_v, d_out, N, BN, flag);
  }
}

// Round 11
// 317.483 us; speedup vs baseline: 1.1627x; 1.0238x over previous
//
#include <hip/hip_runtime.h>
#include <hip/hip_bf16.h>

// DeformableAttention3D — MI355X (gfx950)
// R18 = R17 + non-temporal hints on zero-reuse streams.
// Diagnosis: projf2 pinned at MfmaUtil 8% across 4 structures; arithmetic
// says B(split-W) loads must be missing L2 (~450-900cy) — A/C streams evict
// the 512KB W working set from the 4MB XCD L2. Fix: A-stage loads and
// off/attn C stores made nontemporal (W stays L2-hot); in k_fused2 the
// scores/off_pre/out streams made nontemporal (bf16 v stays L2-resident).
// Everything else verbatim from R17 (passed, 325us).
#define EMBED    256
#define HEADS    8
#define LEVELS   4
#define POINTS   4
#define BATCH    2
#define M_TOT    21760   // 128*128 + 64*64 + 32*32 + 16*16
#define LDP      (EMBED + 4)   // padded LDS leading dim

typedef __hip_bfloat16 bf16;
typedef __attribute__((ext_vector_type(8))) short short8;
typedef __attribute__((ext_vector_type(8))) short bf16x8s;  // 8 bf16 (4 VGPRs)
typedef __attribute__((ext_vector_type(4))) float f32x4;

__device__ __constant__ int c_H[LEVELS]  = {128, 64, 32, 16};
__device__ __constant__ int c_St[LEVELS] = {0, 16384, 20480, 21504};

template<bool BF>
__device__ __forceinline__ float ldf(const void* p, size_t i) {
  if (BF) return __bfloat162float(((const bf16*)p)[i]);
  else    return ((const float*)p)[i];
}
__device__ __forceinline__ float vt2f(float x) { return x; }
__device__ __forceinline__ float vt2f(bf16 x)  { return __bfloat162float(x); }

__device__ __forceinline__ void stout(float* p, float v) { *p = v; }
__device__ __forceinline__ void stout(bf16* p, float v)  { *p = __float2bfloat16(v); }
// nontemporal variants (float = streamed off/attn; bf16 = v, keep cached)
__device__ __forceinline__ void stout_nt(float* p, float v) {
  __builtin_nontemporal_store(v, p);
}
__device__ __forceinline__ void stout_nt(bf16* p, float v)  { *p = __float2bfloat16(v); }

// load 2 consecutive channels -> 2 f32
__device__ __forceinline__ void ld2c(const bf16* p, float& lo, float& hi) {
  unsigned u = *(const unsigned*)p;
  lo = __uint_as_float(u << 16);
  hi = __uint_as_float(u & 0xFFFF0000u);
}
__device__ __forceinline__ void ld2c(const float* p, float& lo, float& hi) {
  float2 f = *(const float2*)p;
  lo = f.x; hi = f.y;
}

template<bool BF>
__device__ __forceinline__ float4 ld4(const void* p, size_t i) {
  if (BF) {
    ushort4 u = *(const ushort4*)((const bf16*)p + i);
    float4 f;
    f.x = __bfloat162float(*reinterpret_cast<bf16*>(&u.x));
    f.y = __bfloat162float(*reinterpret_cast<bf16*>(&u.y));
    f.z = __bfloat162float(*reinterpret_cast<bf16*>(&u.z));
    f.w = __bfloat162float(*reinterpret_cast<bf16*>(&u.w));
    return f;
  } else {
    return *(const float4*)((const float*)p + i);
  }
}

__device__ __forceinline__ void fma4(float4& ac, float s, const float4& wv) {
  ac.x = fmaf(s, wv.x, ac.x);
  ac.y = fmaf(s, wv.y, ac.y);
  ac.z = fmaf(s, wv.z, ac.z);
  ac.w = fmaf(s, wv.w, ac.w);
}

// split 8 f32 -> hi/lo bf16x8 (in registers)
__device__ __forceinline__ void split8(const f32x4 x, const f32x4 y,
                                       bf16x8s& h, bf16x8s& l) {
  float f[8] = {x[0], x[1], x[2], x[3], y[0], y[1], y[2], y[3]};
#pragma unroll
  for (int j = 0; j < 8; ++j) {
    bf16 hb = __float2bfloat16(f[j]);
    float r = f[j] - __bfloat162float(hb);
    bf16 lb = __float2bfloat16(r);
    h[j] = *reinterpret_cast<short*>(&hb);
    l[j] = *reinterpret_cast<short*>(&lb);
  }
}

// ---------------------------------------------------------------------------
// Dtype detector (flag=1 -> buffers bf16, flag=0 -> f32). Verbatim.
// ---------------------------------------------------------------------------
__global__ __launch_bounds__(256)
void k_detect(const unsigned short* __restrict__ q16, int* __restrict__ flag) {
  __shared__ int cnt;
  if (threadIdx.x == 0) cnt = 0;
  __syncthreads();
  int c = 0;
  for (int i = threadIdx.x; i < 8192; i += 256) {
    unsigned short v = q16[i];
    if ((v & 0x7F80u) == 0x7F80u) ++c;   // bf16 Inf/NaN pattern
  }
  if (c) atomicAdd(&cnt, c);
  __syncthreads();
  if (threadIdx.x == 0) flag[0] = (cnt == 0) ? 1 : 0;
}

// ---------------------------------------------------------------------------
// bf16 path (flag==1): transpose  WT[N][K] = W[K][N].  Verbatim R12.
// ---------------------------------------------------------------------------
__global__ __launch_bounds__(256)
void k_transpose_bf16(const unsigned short* __restrict__ W,
                      unsigned short* __restrict__ WT,
                      int K, int N, const int* __restrict__ flag) {
  if (*flag != 1) return;
  __shared__ unsigned short tile[64][65];
  const int ntn = N >> 6;
  const int tk = (int)blockIdx.x / ntn;
  const int tn = (int)blockIdx.x % ntn;
  const int k0 = tk << 6, n0 = tn << 6;
  const int t   = threadIdx.x;
  const int row = t >> 2;            // 0..63
  const int cq  = (t & 3) << 4;      // 0,16,32,48
  const unsigned short* src = W + (size_t)(k0 + row) * N + n0 + cq;
#pragma unroll
  for (int j = 0; j < 16; ++j) tile[row][cq + j] = src[j];
  __syncthreads();
  unsigned short* dst = WT + (size_t)(n0 + row) * K + k0 + cq;
#pragma unroll
  for (int j = 0; j < 16; ++j) dst[j] = tile[cq + j][row];
}

// ---------------------------------------------------------------------------
// f32 path (flag==0): all three W's -> transposed hi/lo bf16 in one launch.
// ---------------------------------------------------------------------------
__global__ __launch_bounds__(256)
void k_wsplit_all(const float* __restrict__ Wv, const float* __restrict__ Woff,
                  const float* __restrict__ Wattn,
                  bf16* __restrict__ Tvh, bf16* __restrict__ Tvl,
                  bf16* __restrict__ Toh, bf16* __restrict__ Tol,
                  bf16* __restrict__ Tah, bf16* __restrict__ Tal,
                  const int* __restrict__ flag) {
  if (*flag != 0) return;
  int bid = (int)blockIdx.x;
  const float* W; bf16 *H, *L; int N;
  if (bid < 16)      { W = Wv;    H = Tvh; L = Tvl; N = 256; }
  else if (bid < 32) { W = Woff;  H = Toh; L = Tol; N = 256; bid -= 16; }
  else               { W = Wattn; H = Tah; L = Tal; N = 128; bid -= 32; }
  const int K = 256;
  __shared__ float tile[64][65];
  const int ntn = N >> 6;
  const int tk = bid / ntn, tn = bid % ntn;
  const int k0 = tk << 6, n0 = tn << 6;
  const int t   = threadIdx.x;
  const int row = t >> 2;            // 0..63
  const int cq  = (t & 3) << 4;      // 0,16,32,48
  const float* src = W + (size_t)(k0 + row) * N + n0 + cq;
#pragma unroll
  for (int j = 0; j < 16; ++j) tile[row][cq + j] = src[j];
  __syncthreads();
  const size_t d0 = (size_t)(n0 + row) * K + k0 + cq;
#pragma unroll
  for (int j = 0; j < 16; ++j) {
    float v = tile[cq + j][row];
    bf16 hb = __float2bfloat16(v);
    float r = v - __bfloat162float(hb);
    H[d0 + j] = hb;
    L[d0 + j] = __float2bfloat16(r);
  }
}

// ---------------------------------------------------------------------------
// bf16-input MFMA projection (flag==1). Verbatim R16.
// ---------------------------------------------------------------------------
template<class OT>
__global__ __launch_bounds__(256)
void k_mfma_proj(const bf16* __restrict__ A, const bf16* __restrict__ WT,
                 const void* __restrict__ bias, OT* __restrict__ C,
                 int M, int N, const int* __restrict__ flag) {
  if (*flag != 1) return;
  const int colBlocks = N >> 7;
  const int rb = (int)blockIdx.x / colBlocks;
  const int cb = (int)blockIdx.x % colBlocks;
  const int t   = threadIdx.x;
  const int wid = t >> 6;
  const int l   = t & 63;
  const int lrow = l & 15;
  const int lk8  = (l >> 4) << 3;
  const int r0 = rb * 64 + (wid & 1) * 32;
  const int c0 = cb * 128 + (wid >> 1) * 64;

  f32x4 acc[2][4];
#pragma unroll
  for (int rf = 0; rf < 2; ++rf)
#pragma unroll
    for (int cf = 0; cf < 4; ++cf) acc[rf][cf] = (f32x4){0.f, 0.f, 0.f, 0.f};

  const bf16* Ap0 = A + (size_t)min(r0 + lrow,      M - 1) * EMBED + lk8;
  const bf16* Ap1 = A + (size_t)min(r0 + 16 + lrow, M - 1) * EMBED + lk8;
  const bf16* Bp  = WT + (size_t)(c0 + lrow) * EMBED + lk8;

#pragma unroll
  for (int k = 0; k < EMBED; k += 32) {
    bf16x8s a0 = *(const bf16x8s*)(Ap0 + k);
    bf16x8s a1 = *(const bf16x8s*)(Ap1 + k);
    bf16x8s b0 = *(const bf16x8s*)(Bp + 0 * 16 * EMBED + k);
    bf16x8s b1 = *(const bf16x8s*)(Bp + 1 * 16 * EMBED + k);
    bf16x8s b2 = *(const bf16x8s*)(Bp + 2 * 16 * EMBED + k);
    bf16x8s b3 = *(const bf16x8s*)(Bp + 3 * 16 * EMBED + k);
    acc[0][0] = __builtin_amdgcn_mfma_f32_16x16x32_bf16(a0, b0, acc[0][0], 0, 0, 0);
    acc[0][1] = __builtin_amdgcn_mfma_f32_16x16x32_bf16(a0, b1, acc[0][1], 0, 0, 0);
    acc[0][2] = __builtin_amdgcn_mfma_f32_16x16x32_bf16(a0, b2, acc[0][2], 0, 0, 0);
    acc[0][3] = __builtin_amdgcn_mfma_f32_16x16x32_bf16(a0, b3, acc[0][3], 0, 0, 0);
    acc[1][0] = __builtin_amdgcn_mfma_f32_16x16x32_bf16(a1, b0, acc[1][0], 0, 0, 0);
    acc[1][1] = __builtin_amdgcn_mfma_f32_16x16x32_bf16(a1, b1, acc[1][1], 0, 0, 0);
    acc[1][2] = __builtin_amdgcn_mfma_f32_16x16x32_bf16(a1, b2, acc[1][2], 0, 0, 0);
    acc[1][3] = __builtin_amdgcn_mfma_f32_16x16x32_bf16(a1, b3, acc[1][3], 0, 0, 0);
  }

  const int rbase = (l >> 4) << 2;
#pragma unroll
  for (int cf = 0; cf < 4; ++cf) {
    const int col = c0 + cf * 16 + lrow;
    const float bv = ldf<true>(bias, col);
#pragma unroll
    for (int rf = 0; rf < 2; ++rf) {
#pragma unroll
      for (int r = 0; r < 4; ++r) {
        const int row = r0 + rf * 16 + rbase + r;
        if (row < M) stout(&C[(size_t)row * N + col], acc[rf][cf][r] + bv);
      }
    }
  }
}

// ---------------------------------------------------------------------------
// R18: f32-input split-bf16 MFMA projection, LDS-staged A (flag==0).
// A-stage loads NONTEMPORAL (don't evict W from L2); C stores nontemporal
// for float outputs (off/attn streams), normal for bf16 (v, re-read randomly).
// ---------------------------------------------------------------------------
template<int NW, class OT>
__global__ __launch_bounds__(256)
void k_mfma_projf2(const float* __restrict__ A, const bf16* __restrict__ WThi,
                   const bf16* __restrict__ WTlo, const float* __restrict__ bias,
                   OT* __restrict__ C, int M, const int* __restrict__ flag) {
  if (*flag != 0) return;
  constexpr int N = NW * 64;
  const int t   = threadIdx.x;
  const int wid = t >> 6;
  const int l   = t & 63;
  const int lrow = l & 15;
  const int lk8  = (l >> 4) << 3;
  const int r0 = (int)blockIdx.x * 32;
  const int c0 = wid * 64;

  __shared__ float As[32][260];   // 33280 B

  // ---- stage 32 rows x 256 f32, NONTEMPORAL (A has zero reuse) ----
  constexpr int RPW = 32 / NW;
#pragma unroll
  for (int base = 0; base < RPW; base += 8) {
    f32x4 tmp[8];
#pragma unroll
    for (int i = 0; i < 8; ++i) {
      int r   = wid + (base + i) * NW;
      int row = min(r0 + r, M - 1);
      tmp[i] = __builtin_nontemporal_load(
                 (const f32x4*)(A + (size_t)row * EMBED + (l << 2)));
    }
#pragma unroll
    for (int i = 0; i < 8; ++i) {
      int r = wid + (base + i) * NW;
      *(f32x4*)&As[r][l << 2] = tmp[i];
    }
  }
  __syncthreads();

  f32x4 acc[2][4];
#pragma unroll
  for (int rf = 0; rf < 2; ++rf)
#pragma unroll
    for (int cf = 0; cf < 4; ++cf) acc[rf][cf] = (f32x4){0.f, 0.f, 0.f, 0.f};

  const bf16* Bh = WThi + (size_t)(c0 + lrow) * EMBED + lk8;
  const bf16* Bl = WTlo + (size_t)(c0 + lrow) * EMBED + lk8;

#pragma unroll
  for (int ks = 0; ks < 8; ++ks) {
    const int k = ks * 32;
    bf16x8s a0h, a0l, a1h, a1l;
    split8(*(const f32x4*)&As[lrow     ][k + lk8],
           *(const f32x4*)&As[lrow     ][k + lk8 + 4], a0h, a0l);
    split8(*(const f32x4*)&As[lrow + 16][k + lk8],
           *(const f32x4*)&As[lrow + 16][k + lk8 + 4], a1h, a1l);
    bf16x8s bh0 = *(const bf16x8s*)(Bh + 0 * 16 * EMBED + k);
    bf16x8s bh1 = *(const bf16x8s*)(Bh + 1 * 16 * EMBED + k);
    bf16x8s bh2 = *(const bf16x8s*)(Bh + 2 * 16 * EMBED + k);
    bf16x8s bh3 = *(const bf16x8s*)(Bh + 3 * 16 * EMBED + k);
    bf16x8s bl0 = *(const bf16x8s*)(Bl + 0 * 16 * EMBED + k);
    bf16x8s bl1 = *(const bf16x8s*)(Bl + 1 * 16 * EMBED + k);
    bf16x8s bl2 = *(const bf16x8s*)(Bl + 2 * 16 * EMBED + k);
    bf16x8s bl3 = *(const bf16x8s*)(Bl + 3 * 16 * EMBED + k);
    // hi*hi
    acc[0][0] = __builtin_amdgcn_mfma_f32_16x16x32_bf16(a0h, bh0, acc[0][0], 0, 0, 0);
    acc[0][1] = __builtin_amdgcn_mfma_f32_16x16x32_bf16(a0h, bh1, acc[0][1], 0, 0, 0);
    acc[0][2] = __builtin_amdgcn_mfma_f32_16x16x32_bf16(a0h, bh2, acc[0][2], 0, 0, 0);
    acc[0][3] = __builtin_amdgcn_mfma_f32_16x16x32_bf16(a0h, bh3, acc[0][3], 0, 0, 0);
    acc[1][0] = __builtin_amdgcn_mfma_f32_16x16x32_bf16(a1h, bh0, acc[1][0], 0, 0, 0);
    acc[1][1] = __builtin_amdgcn_mfma_f32_16x16x32_bf16(a1h, bh1, acc[1][1], 0, 0, 0);
    acc[1][2] = __builtin_amdgcn_mfma_f32_16x16x32_bf16(a1h, bh2, acc[1][2], 0, 0, 0);
    acc[1][3] = __builtin_amdgcn_mfma_f32_16x16x32_bf16(a1h, bh3, acc[1][3], 0, 0, 0);
    // hi*lo
    acc[0][0] = __builtin_amdgcn_mfma_f32_16x16x32_bf16(a0h, bl0, acc[0][0], 0, 0, 0);
    acc[0][1] = __builtin_amdgcn_mfma_f32_16x16x32_bf16(a0h, bl1, acc[0][1], 0, 0, 0);
    acc[0][2] = __builtin_amdgcn_mfma_f32_16x16x32_bf16(a0h, bl2, acc[0][2], 0, 0, 0);
    acc[0][3] = __builtin_amdgcn_mfma_f32_16x16x32_bf16(a0h, bl3, acc[0][3], 0, 0, 0);
    acc[1][0] = __builtin_amdgcn_mfma_f32_16x16x32_bf16(a1h, bl0, acc[1][0], 0, 0, 0);
    acc[1][1] = __builtin_amdgcn_mfma_f32_16x16x32_bf16(a1h, bl1, acc[1][1], 0, 0, 0);
    acc[1][2] = __builtin_amdgcn_mfma_f32_16x16x32_bf16(a1h, bl2, acc[1][2], 0, 0, 0);
    acc[1][3] = __builtin_amdgcn_mfma_f32_16x16x32_bf16(a1h, bl3, acc[1][3], 0, 0, 0);
    // lo*hi
    acc[0][0] = __builtin_amdgcn_mfma_f32_16x16x32_bf16(a0l, bh0, acc[0][0], 0, 0, 0);
    acc[0][1] = __builtin_amdgcn_mfma_f32_16x16x32_bf16(a0l, bh1, acc[0][1], 0, 0, 0);
    acc[0][2] = __builtin_amdgcn_mfma_f32_16x16x32_bf16(a0l, bh2, acc[0][2], 0, 0, 0);
    acc[0][3] = __builtin_amdgcn_mfma_f32_16x16x32_bf16(a0l, bh3, acc[0][3], 0, 0, 0);
    acc[1][0] = __builtin_amdgcn_mfma_f32_16x16x32_bf16(a1l, bh0, acc[1][0], 0, 0, 0);
    acc[1][1] = __builtin_amdgcn_mfma_f32_16x16x32_bf16(a1l, bh1, acc[1][1], 0, 0, 0);
    acc[1][2] = __builtin_amdgcn_mfma_f32_16x16x32_bf16(a1l, bh2, acc[1][2], 0, 0, 0);
    acc[1][3] = __builtin_amdgcn_mfma_f32_16x16x32_bf16(a1l, bh3, acc[1][3], 0, 0, 0);
  }

  const int rbase = (l >> 4) << 2;
#pragma unroll
  for (int cf = 0; cf < 4; ++cf) {
    const int col = c0 + cf * 16 + lrow;
    const float bv = bias[col];
#pragma unroll
    for (int rf = 0; rf < 2; ++rf) {
#pragma unroll
      for (int r = 0; r < 4; ++r) {
        const int row = r0 + rf * 16 + rbase + r;
        if (row < M) stout_nt(&C[(size_t)row * N + col], acc[rf][cf][r] + bv);
      }
    }
  }
}

// ---------------------------------------------------------------------------
// shared staging: 16 rows of A (EMBED cols) into padded LDS tile (R11)
// ---------------------------------------------------------------------------
template<bool BF>
__device__ __forceinline__ void stage16(const void* __restrict__ A,
                                        float (*rowA)[LDP],
                                        int r0, int M, int t) {
  int r  = t >> 4;
  int rr = min(r0 + r, M - 1);
  int c0 = (t & 15) * 16;
  if (BF) {
    const bf16* ap = (const bf16*)A + (size_t)rr * EMBED + c0;
    short8 a0 = *(const short8*)ap;
    short8 a1 = *(const short8*)(ap + 8);
#pragma unroll
    for (int j = 0; j < 8; ++j) {
      short s0 = a0[j], s1 = a1[j];
      rowA[r][c0 + j]     = __bfloat162float(*reinterpret_cast<bf16*>(&s0));
      rowA[r][c0 + 8 + j] = __bfloat162float(*reinterpret_cast<bf16*>(&s1));
    }
  } else {
    const float* ap = (const float*)A + (size_t)rr * EMBED + c0;
#pragma unroll
    for (int j = 0; j < 4; ++j) {
      float4 f = *(const float4*)(ap + j * 4);
      rowA[r][c0 + j * 4 + 0] = f.x;
      rowA[r][c0 + j * 4 + 1] = f.y;
      rowA[r][c0 + j * 4 + 2] = f.z;
      rowA[r][c0 + j * 4 + 3] = f.w;
    }
  }
}

// ---------------------------------------------------------------------------
// R11 tier kernels (need_full fallback): 4x4 / 2x4 register-blocked GEMVs.
// ---------------------------------------------------------------------------
template<bool BF>
__device__ void vgemv4x4_body(const void* __restrict__ A, const void* __restrict__ W,
                              const void* __restrict__ bias, float* __restrict__ C,
                              int M) {
  const int t  = threadIdx.x;
  const int r0 = blockIdx.x * 16;
  if (r0 >= M) return;

  __shared__ float rowA[16][LDP];
  stage16<BF>(A, rowA, r0, M, t);
  __syncthreads();

  const int g  = t >> 6;
  const int c0 = (t & 63) * 4;

  float4 bv;
  bv.x = ldf<BF>(bias, c0 + 0);
  bv.y = ldf<BF>(bias, c0 + 1);
  bv.z = ldf<BF>(bias, c0 + 2);
  bv.w = ldf<BF>(bias, c0 + 3);

  float4 acc[4];
#pragma unroll
  for (int r = 0; r < 4; ++r) acc[r] = bv;

#pragma unroll 2
  for (int k = 0; k < EMBED; k += 4) {
    float4 av[4];
#pragma unroll
    for (int r = 0; r < 4; ++r)
      av[r] = *(const float4*)&rowA[g * 4 + r][k];
    float4 w0 = ld4<BF>(W, (size_t)(k + 0) * EMBED + c0);
    float4 w1 = ld4<BF>(W, (size_t)(k + 1) * EMBED + c0);
    float4 w2 = ld4<BF>(W, (size_t)(k + 2) * EMBED + c0);
    float4 w3 = ld4<BF>(W, (size_t)(k + 3) * EMBED + c0);
#pragma unroll
    for (int r = 0; r < 4; ++r) {
      fma4(acc[r], av[r].x, w0);
      fma4(acc[r], av[r].y, w1);
      fma4(acc[r], av[r].z, w2);
      fma4(acc[r], av[r].w, w3);
    }
  }
#pragma unroll
  for (int r = 0; r < 4; ++r) {
    int row = r0 + g * 4 + r;
    if (row < M) *(float4*)&C[(size_t)row * EMBED + c0] = acc[r];
  }
}

__global__ __launch_bounds__(256)
void k_vgemv4x4(const void* A, const void* W, const void* bias, float* C,
                int M, const int* flag) {
  if (*flag) vgemv4x4_body<true >(A, W, bias, C, M);
  else       vgemv4x4_body<false>(A, W, bias, C, M);
}

template<bool BF>
__device__ void agemv4_body(const void* __restrict__ A, const void* __restrict__ W,
                            const void* __restrict__ bias, float* __restrict__ C,
                            int M) {
  const int t  = threadIdx.x;
  const int r0 = blockIdx.x * 16;
  if (r0 >= M) return;

  __shared__ float rowA[16][LDP];
  stage16<BF>(A, rowA, r0, M, t);
  __syncthreads();

  const int g  = t >> 5;
  const int c0 = (t & 31) * 4;

  float4 bv;
  bv.x = ldf<BF>(bias, c0 + 0);
  bv.y = ldf<BF>(bias, c0 + 1);
  bv.z = ldf<BF>(bias, c0 + 2);
  bv.w = ldf<BF>(bias, c0 + 3);

  float4 acc[2];
  acc[0] = bv; acc[1] = bv;

#pragma unroll 2
  for (int k = 0; k < EMBED; k += 4) {
    float4 a0 = *(const float4*)&rowA[g * 2 + 0][k];
    float4 a1 = *(const float4*)&rowA[g * 2 + 1][k];
    float4 w0 = ld4<BF>(W, (size_t)(k + 0) * 128 + c0);
    float4 w1 = ld4<BF>(W, (size_t)(k + 1) * 128 + c0);
    float4 w2 = ld4<BF>(W, (size_t)(k + 2) * 128 + c0);
    float4 w3 = ld4<BF>(W, (size_t)(k + 3) * 128 + c0);
    fma4(acc[0], a0.x, w0); fma4(acc[0], a0.y, w1);
    fma4(acc[0], a0.z, w2); fma4(acc[0], a0.w, w3);
    fma4(acc[1], a1.x, w0); fma4(acc[1], a1.y, w1);
    fma4(acc[1], a1.z, w2); fma4(acc[1], a1.w, w3);
  }
#pragma unroll
  for (int r = 0; r < 2; ++r) {
    int row = r0 + g * 2 + r;
    if (row < M) *(float4*)&C[(size_t)row * 128 + c0] = acc[r];
  }
}

__global__ __launch_bounds__(256)
void k_agemv4(const void* A, const void* W, const void* bias, float* C,
              int M, const int* flag) {
  if (*flag) agemv4_body<true >(A, W, bias, C, M);
  else       agemv4_body<false>(A, W, bias, C, M);
}

// ---------------------------------------------------------------------------
// R18 k_fused2: softmax+pack (t<128) + 2-channels-per-lane gather.
// scores/off_pre loads + out store NONTEMPORAL (keep v L2-resident).
// ---------------------------------------------------------------------------
template<bool BF, class VT>
__device__ void fused2_body(const void* __restrict__ ref_points,
                            const float* __restrict__ off_pre,
                            const float* __restrict__ scores,
                            const VT* __restrict__ v,
                            void* __restrict__ out, int N, int BN) {
  int q = blockIdx.x;
  if (q >= BN) return;
  int b = q / N;
  int t = threadIdx.x;

  __shared__ float  s_aw[128];
  __shared__ float  s_rp[2];
  __shared__ int4   s_pi[128];    // corner element index (cell<<8)
  __shared__ float4 s_pw[128];    // wa * bilinear * valid
  __shared__ float  s_part[2][256];

  if (t < 2)   s_rp[t] = ldf<BF>(ref_points, (size_t)q * 2 + t);
  if (t < 128) s_aw[t] = __builtin_nontemporal_load(&scores[(size_t)q * 128 + t]);
  __syncthreads();

  if (t < 128) {
    int base = t & ~15;
    float mx = -1e30f;
#pragma unroll
    for (int i = 0; i < 16; ++i) mx = fmaxf(mx, s_aw[base + i]);
    float sum = 0.f;
#pragma unroll
    for (int i = 0; i < 16; ++i) sum += expf(s_aw[base + i] - mx);
    float wa = expf(s_aw[t] - mx) / sum;

    int   l  = (t >> 2) & 3;
    int   Wl = 128 >> l;                       // levels are square
    float fW = (float)Wl;
    int   st = (int)((65536u - (65536u >> (2 * l))) / 3u);  // level start
    float ox = __builtin_nontemporal_load(&off_pre[(size_t)q * EMBED + 2 * t])     - 0.5f;
    float oy = __builtin_nontemporal_load(&off_pre[(size_t)q * EMBED + 2 * t + 1]) - 0.5f;
    float x = fmaf(s_rp[0], fW, ox);
    float y = fmaf(s_rp[1], fW, oy);
    float x0f = floorf(x), y0f = floorf(y);
    float lx = x - x0f, ly = y - y0f;
    int x0 = (int)x0f, y0 = (int)y0f;
    int x1 = x0 + 1,   y1 = y0 + 1;
    float w00 = wa * (1.f - lx) * (1.f - ly);
    float w01 = wa * lx * (1.f - ly);
    float w10 = wa * (1.f - lx) * ly;
    float w11 = wa * lx * ly;
    bool vx0 = (unsigned)x0 < (unsigned)Wl;
    bool vx1 = (unsigned)x1 < (unsigned)Wl;
    bool vy0 = (unsigned)y0 < (unsigned)Wl;
    bool vy1 = (unsigned)y1 < (unsigned)Wl;
    int xc0 = min(max(x0, 0), Wl - 1), xc1 = min(max(x1, 0), Wl - 1);
    int yc0 = min(max(y0, 0), Wl - 1), yc1 = min(max(y1, 0), Wl - 1);
    int r0i = st + yc0 * Wl;
    int r1i = st + yc1 * Wl;
    int4 pi; float4 pw;
    pi.x = (r0i + xc0) << 8;  pw.x = (vx0 && vy0) ? w00 : 0.f;
    pi.y = (r0i + xc1) << 8;  pw.y = (vx1 && vy0) ? w01 : 0.f;
    pi.z = (r1i + xc0) << 8;  pw.z = (vx0 && vy1) ? w10 : 0.f;
    pi.w = (r1i + xc1) << 8;  pw.w = (vx1 && vy1) ? w11 : 0.f;
    s_pi[t] = pi;
    s_pw[t] = pw;
  }
  __syncthreads();

  // gather: lane owns channels (2c, 2c+1); half s owns 8 of the 16 combos
  const int c  = t & 127;
  const int s  = t >> 7;
  const int h  = c >> 4;
  const int ch = c << 1;
  const VT* vb = v + (size_t)b * (M_TOT * EMBED) + ch;
  const int cbase = (h << 4) + (s << 3);

  float oL0 = 0.f, oH0 = 0.f, oL1 = 0.f, oH1 = 0.f;
#pragma unroll
  for (int g = 0; g < 2; ++g) {
    const int c0 = cbase + (g << 2);
    int4   iA = s_pi[c0 + 0], iB = s_pi[c0 + 1], iC = s_pi[c0 + 2], iD = s_pi[c0 + 3];
    float4 wA = s_pw[c0 + 0], wB = s_pw[c0 + 1], wC = s_pw[c0 + 2], wD = s_pw[c0 + 3];
    float lA0,hA0,lA1,hA1,lA2,hA2,lA3,hA3;
    float lB0,hB0,lB1,hB1,lB2,hB2,lB3,hB3;
    float lC0,hC0,lC1,hC1,lC2,hC2,lC3,hC3;
    float lD0,hD0,lD1,hD1,lD2,hD2,lD3,hD3;
    ld2c(vb + iA.x, lA0, hA0); ld2c(vb + iA.y, lA1, hA1);
    ld2c(vb + iA.z, lA2, hA2); ld2c(vb + iA.w, lA3, hA3);
    ld2c(vb + iB.x, lB0, hB0); ld2c(vb + iB.y, lB1, hB1);
    ld2c(vb + iB.z, lB2, hB2); ld2c(vb + iB.w, lB3, hB3);
    ld2c(vb + iC.x, lC0, hC0); ld2c(vb + iC.y, lC1, hC1);
    ld2c(vb + iC.z, lC2, hC2); ld2c(vb + iC.w, lC3, hC3);
    ld2c(vb + iD.x, lD0, hD0); ld2c(vb + iD.y, lD1, hD1);
    ld2c(vb + iD.z, lD2, hD2); ld2c(vb + iD.w, lD3, hD3);
    oL0 = fmaf(wA.x, lA0, oL0); oH0 = fmaf(wA.x, hA0, oH0);
    oL1 = fmaf(wA.y, lA1, oL1); oH1 = fmaf(wA.y, hA1, oH1);
    oL0 = fmaf(wA.z, lA2, oL0); oH0 = fmaf(wA.z, hA2, oH0);
    oL1 = fmaf(wA.w, lA3, oL1); oH1 = fmaf(wA.w, hA3, oH1);
    oL0 = fmaf(wB.x, lB0, oL0); oH0 = fmaf(wB.x, hB0, oH0);
    oL1 = fmaf(wB.y, lB1, oL1); oH1 = fmaf(wB.y, hB1, oH1);
    oL0 = fmaf(wB.z, lB2, oL0); oH0 = fmaf(wB.z, hB2, oH0);
    oL1 = fmaf(wB.w, lB3, oL1); oH1 = fmaf(wB.w, hB3, oH1);
    oL0 = fmaf(wC.x, lC0, oL0); oH0 = fmaf(wC.x, hC0, oH0);
    oL1 = fmaf(wC.y, lC1, oL1); oH1 = fmaf(wC.y, hC1, oH1);
    oL0 = fmaf(wC.z, lC2, oL0); oH0 = fmaf(wC.z, hC2, oH0);
    oL1 = fmaf(wC.w, lC3, oL1); oH1 = fmaf(wC.w, hC3, oH1);
    oL0 = fmaf(wD.x, lD0, oL0); oH0 = fmaf(wD.x, hD0, oH0);
    oL1 = fmaf(wD.y, lD1, oL1); oH1 = fmaf(wD.y, hD1, oH1);
    oL0 = fmaf(wD.z, lD2, oL0); oH0 = fmaf(wD.z, hD2, oH0);
    oL1 = fmaf(wD.w, lD3, oL1); oH1 = fmaf(wD.w, hD3, oH1);
  }
  s_part[s][ch]     = oL0 + oL1;
  s_part[s][ch + 1] = oH0 + oH1;
  __syncthreads();

  float o = s_part[0][t] + s_part[1][t];
  if (BF) {
    bf16 ob = __float2bfloat16(o);
    __builtin_nontemporal_store(*reinterpret_cast<unsigned short*>(&ob),
                                (unsigned short*)out + (size_t)q * EMBED + t);
  } else {
    __builtin_nontemporal_store(o, (float*)out + (size_t)q * EMBED + t);
  }
}

template<class VT>
__global__ __launch_bounds__(256)
void k_fused2(const void* ref_points, const float* off_pre, const float* scores,
              const VT* v, void* out, int N, int BN, const int* flag) {
  if (*flag) fused2_body<true,  VT>(ref_points, off_pre, scores, v, out, N, BN);
  else       fused2_body<false, VT>(ref_points, off_pre, scores, v, out, N, BN);
}

// ---------------------------------------------------------------------------
// MID TIER (R8, proven): 8-row GEMV + fused with in-kernel attn GEMV.
// ---------------------------------------------------------------------------
template<bool BF>
__device__ void vgemv8_body(const void* __restrict__ A, const void* __restrict__ W,
                            const void* __restrict__ bias, float* __restrict__ C,
                            int M) {
  const int t  = threadIdx.x;
  const int r0 = blockIdx.x * 8;
  if (r0 >= M) return;

  __shared__ float rowA[8][EMBED];
  {
    int r  = t >> 5;
    int rr = min(r0 + r, M - 1);
    int c0 = (t & 31) * 8;
    if (BF) {
      const bf16* ap = (const bf16*)A + (size_t)rr * EMBED + c0;
      short8 a = *(const short8*)ap;
#pragma unroll
      for (int j = 0; j < 8; ++j) {
        short s = a[j];
        bf16 hb = *reinterpret_cast<bf16*>(&s);
        rowA[r][c0 + j] = __bfloat162float(hb);
      }
    } else {
      const float* ap = (const float*)A + (size_t)rr * EMBED + c0;
#pragma unroll
      for (int j = 0; j < 8; ++j) rowA[r][c0 + j] = ap[j];
    }
  }
  __syncthreads();

  const int n = t;
  const float b = ldf<BF>(bias, n);
  float acc[8];
#pragma unroll
  for (int r = 0; r < 8; ++r) acc[r] = b;
#pragma unroll 4
  for (int k = 0; k < EMBED; ++k) {
    float w = ldf<BF>(W, (size_t)k * EMBED + n);
#pragma unroll
    for (int r = 0; r < 8; ++r) acc[r] = fmaf(rowA[r][k], w, acc[r]);
  }
#pragma unroll
  for (int r = 0; r < 8; ++r)
    if (r0 + r < M) C[(size_t)(r0 + r) * EMBED + n] = acc[r];
}

__global__ __launch_bounds__(256)
void k_vgemv8(const void* A, const void* W, const void* bias, float* C,
              int M, const int* flag) {
  if (*flag) vgemv8_body<true >(A, W, bias, C, M);
  else       vgemv8_body<false>(A, W, bias, C, M);
}

template<bool BF, class VT>
__device__ void fused_body(const void* __restrict__ query,
                           const void* __restrict__ ref_points,
                           const float* __restrict__ off_pre,
                           const void* __restrict__ W_attn,
                           const void* __restrict__ b_attn,
                           const VT* __restrict__ v,
                           void* __restrict__ out, int N, int BN) {
  int q = blockIdx.x;
  if (q >= BN) return;
  int b = q / N;
  int t = threadIdx.x;

  __shared__ float  row[EMBED];
  __shared__ float  s_part[256];
  __shared__ float  s_aw[HEADS * LEVELS * POINTS];
  __shared__ float  s_rp[2];
  __shared__ int4   s_pi[HEADS * LEVELS * POINTS];
  __shared__ float4 s_pw[HEADS * LEVELS * POINTS];

  row[t] = ldf<BF>(query, (size_t)q * EMBED + t);
  if (t < 2) s_rp[t] = ldf<BF>(ref_points, (size_t)q * 2 + t);
  __syncthreads();

  {
    const int col = t & 127;
    const int e0  = (t >> 7) * 128;
    float acc = 0.f;
#pragma unroll 8
    for (int e = 0; e < 128; ++e)
      acc = fmaf(row[e0 + e], ldf<BF>(W_attn, (size_t)(e0 + e) * 128 + col), acc);
    s_part[t] = acc;
  }
  __syncthreads();
  if (t < 128)
    s_aw[t] = ldf<BF>(b_attn, t) + s_part[t] + s_part[t + 128];
  __syncthreads();

  if (t < 128) {
    int base = t & ~15;
    float mx = -1e30f;
#pragma unroll
    for (int i = 0; i < 16; ++i) mx = fmaxf(mx, s_aw[base + i]);
    float sum = 0.f;
#pragma unroll
    for (int i = 0; i < 16; ++i) sum += expf(s_aw[base + i] - mx);
    float wa = expf(s_aw[t] - mx) / sum;

    int   l  = (t >> 2) & 3;
    int   Wl = 128 >> l;
    float fW = (float)Wl;
    int   st = (int)((65536u - (65536u >> (2 * l))) / 3u);
    float ox = off_pre[(size_t)q * EMBED + 2 * t]     - 0.5f;
    float oy = off_pre[(size_t)q * EMBED + 2 * t + 1] - 0.5f;
    float x = fmaf(s_rp[0], fW, ox);
    float y = fmaf(s_rp[1], fW, oy);
    float x0f = floorf(x), y0f = floorf(y);
    float lx = x - x0f, ly = y - y0f;
    int x0 = (int)x0f, y0 = (int)y0f;
    int x1 = x0 + 1,   y1 = y0 + 1;
    float w00 = wa * (1.f - lx) * (1.f - ly);
    float w01 = wa * lx * (1.f - ly);
    float w10 = wa * (1.f - lx) * ly;
    float w11 = wa * lx * ly;
    bool vx0 = (unsigned)x0 < (unsigned)Wl;
    bool vx1 = (unsigned)x1 < (unsigned)Wl;
    bool vy0 = (unsigned)y0 < (unsigned)Wl;
    bool vy1 = (unsigned)y1 < (unsigned)Wl;
    int xc0 = min(max(x0, 0), Wl - 1), xc1 = min(max(x1, 0), Wl - 1);
    int yc0 = min(max(y0, 0), Wl - 1), yc1 = min(max(y1, 0), Wl - 1);
    int r0i = st + yc0 * Wl;
    int r1i = st + yc1 * Wl;
    int4 pi; float4 pw;
    pi.x = (r0i + xc0) << 8;  pw.x = (vx0 && vy0) ? w00 : 0.f;
    pi.y = (r0i + xc1) << 8;  pw.y = (vx1 && vy0) ? w01 : 0.f;
    pi.z = (r1i + xc0) << 8;  pw.z = (vx0 && vy1) ? w10 : 0.f;
    pi.w = (r1i + xc1) << 8;  pw.w = (vx1 && vy1) ? w11 : 0.f;
    s_pi[t] = pi;
    s_pw[t] = pw;
  }
  __syncthreads();

  const int h = t >> 5;
  const VT* vbt = v + (size_t)b * M_TOT * EMBED + t;
  float o = 0.f;
#pragma unroll
  for (int lp = 0; lp < 16; ++lp) {
    int c = (h << 4) + lp;
    int4   i4 = s_pi[c];
    float4 w4 = s_pw[c];
    o = fmaf(w4.x, vt2f(vbt[i4.x]), o);
    o = fmaf(w4.y, vt2f(vbt[i4.y]), o);
    o = fmaf(w4.z, vt2f(vbt[i4.z]), o);
    o = fmaf(w4.w, vt2f(vbt[i4.w]), o);
  }
  if (BF) ((bf16*)out)[(size_t)q * EMBED + t] = __float2bfloat16(o);
  else    ((float*)out)[(size_t)q * EMBED + t] = o;
}

template<class VT>
__global__ __launch_bounds__(256)
void k_fused(const void* query, const void* ref_points, const float* off_pre,
             const void* W_attn, const void* b_attn,
             const VT* v, void* out, int N, int BN, const int* flag) {
  if (*flag) fused_body<true,  VT>(query, ref_points, off_pre, W_attn, b_attn, v, out, N, BN);
  else       fused_body<false, VT>(query, ref_points, off_pre, W_attn, b_attn, v, out, N, BN);
}

// ---------------------------------------------------------------------------
// Fallback path (ws too small): R2/R6's bf16 fused path, fully self-contained.
// ---------------------------------------------------------------------------
template<bool BF, class VT>
__device__ void vproj_body(const void* __restrict__ value,
                           const void* __restrict__ W_v,
                           const void* __restrict__ b_v,
                           VT* __restrict__ v, int BM) {
  int m = blockIdx.x;
  if (m >= BM) return;
  int t = threadIdx.x;
  __shared__ float row[EMBED];
  row[t] = ldf<BF>(value, (size_t)m * EMBED + t);
  __syncthreads();
  float acc = ldf<BF>(b_v, t);
#pragma unroll 8
  for (int e = 0; e < EMBED; ++e)
    acc = fmaf(row[e], ldf<BF>(W_v, (size_t)e * EMBED + t), acc);
  if (sizeof(VT) == 2) ((bf16*)v)[(size_t)m * EMBED + t] = __float2bfloat16(acc);
  else                 ((float*)v)[(size_t)m * EMBED + t] = acc;
}

template<class VT>
__global__ __launch_bounds__(256)
void k_value_proj(const void* value, const void* W_v, const void* b_v,
                  VT* v, int BM, const int* flag) {
  if (*flag) vproj_body<true,  VT>(value, W_v, b_v, v, BM);
  else       vproj_body<false, VT>(value, W_v, b_v, v, BM);
}

template<bool BF, class VT>
__device__ void fusedfb_body(const void* __restrict__ query,
                             const void* __restrict__ ref_points,
                             const void* __restrict__ W_off,
                             const void* __restrict__ b_off,
                             const void* __restrict__ W_attn,
                             const void* __restrict__ b_attn,
                             const VT* __restrict__ v,
                             void* __restrict__ out, int N, int BN) {
  int q = blockIdx.x;
  if (q >= BN) return;
  int b = q / N;
  int t = threadIdx.x;

  __shared__ float row[EMBED];
  __shared__ float s_off[EMBED];
  __shared__ float s_aw[HEADS * LEVELS * POINTS];
  __shared__ float s_rp[2];

  row[t] = ldf<BF>(query, (size_t)q * EMBED + t);
  if (t < 2) s_rp[t] = ldf<BF>(ref_points, (size_t)q * 2 + t);
  __syncthreads();

  {
    float acc = ldf<BF>(b_off, t);
#pragma unroll 8
    for (int e = 0; e < EMBED; ++e)
      acc = fmaf(row[e], ldf<BF>(W_off, (size_t)e * EMBED + t), acc);
    s_off[t] = acc;
  }
  if (t < 128) {
    float acc = ldf<BF>(b_attn, t);
#pragma unroll 8
    for (int e = 0; e < EMBED; ++e)
      acc = fmaf(row[e], ldf<BF>(W_attn, (size_t)e * 128 + t), acc);
    s_aw[t] = acc;
  }
  __syncthreads();

  float aval = 0.f;
  if (t < 128) {
    int base = t & ~15;
    float mx = -1e30f;
#pragma unroll
    for (int i = 0; i < 16; ++i) mx = fmaxf(mx, s_aw[base + i]);
    float sum = 0.f;
#pragma unroll
    for (int i = 0; i < 16; ++i) sum += expf(s_aw[base + i] - mx);
    aval = expf(s_aw[t] - mx) / sum;
  }
  __syncthreads();
  if (t < 128) s_aw[t] = aval;
  __syncthreads();

  int h = t >> 5;
  const VT* vb = v + (size_t)b * M_TOT * EMBED;
  float o = 0.f;
#pragma unroll
  for (int l = 0; l < LEVELS; ++l) {
    const int Hl = c_H[l], Wl = c_H[l];
    const VT* vl = vb + (size_t)c_St[l] * EMBED;
    const float fW = (float)Wl, fH = (float)Hl;
#pragma unroll
    for (int p = 0; p < POINTS; ++p) {
      int oi = ((h * LEVELS + l) * POINTS + p) << 1;
      float x = (s_rp[0] + s_off[oi]     / fW) * fW - 0.5f;
      float y = (s_rp[1] + s_off[oi + 1] / fH) * fH - 0.5f;
      float x0f = floorf(x), y0f = floorf(y);
      float lx = x - x0f, ly = y - y0f;
      int x0 = (int)x0f, y0 = (int)y0f;
      float wa = s_aw[(h * LEVELS + l) * POINTS + p];
      float cw[4] = {(1.f - lx) * (1.f - ly), lx * (1.f - ly),
                     (1.f - lx) * ly,         lx * ly};
      const int dxs[4] = {0, 1, 0, 1};
      const int dys[4] = {0, 0, 1, 1};
#pragma unroll
      for (int cidx = 0; cidx < 4; ++cidx) {
        int xi = x0 + dxs[cidx];
        int yi = y0 + dys[cidx];
        bool valid = (xi >= 0) & (xi < Wl) & (yi >= 0) & (yi < Hl);
        int xc = min(max(xi, 0), Wl - 1);
        int yc = min(max(yi, 0), Hl - 1);
        float g = vt2f(vl[(size_t)(yc * Wl + xc) * EMBED + t]);
        o += (valid ? wa * cw[cidx] : 0.f) * g;
      }
    }
  }
  if (BF) ((bf16*)out)[(size_t)q * EMBED + t] = __float2bfloat16(o);
  else    ((float*)out)[(size_t)q * EMBED + t] = o;
}

template<class VT>
__global__ __launch_bounds__(256)
void k_fused_fb(const void* query, const void* ref_points,
                const void* W_off, const void* b_off,
                const void* W_attn, const void* b_attn,
                const VT* v, void* out, int N, int BN, const int* flag) {
  if (*flag) fusedfb_body<true,  VT>(query, ref_points, W_off, b_off, W_attn, b_attn, v, out, N, BN);
  else       fusedfb_body<false, VT>(query, ref_points, W_off, b_off, W_attn, b_attn, v, out, N, BN);
}

// ---------------------------------------------------------------------------
extern "C" void kernel_launch(void* const* d_in, const int* in_sizes, int n_in,
                              void* d_out, int out_size, void* d_ws, size_t ws_size,
                              hipStream_t stream) {
  const void* query      = d_in[0];
  const void* value      = d_in[2];
  const void* ref_points = d_in[3];
  const void* W_off  = d_in[6];
  const void* b_off  = d_in[7];
  const void* W_attn = d_in[8];
  const void* b_attn = d_in[9];
  const void* W_v    = d_in[10];
  const void* b_v    = d_in[11];

  const int BN = in_sizes[0] / EMBED;   // 20000
  const int BM = in_sizes[2] / EMBED;   // 43520
  const int N  = BN / BATCH;

  int*  flag    = (int*)d_ws;
  char* ws_base = (char*)d_ws + 256;

  k_detect<<<1, 256, 0, stream>>>((const unsigned short*)query, flag);

  const size_t sz_v    = (size_t)BM * EMBED * sizeof(float);  // layout slot (v used as bf16)
  const size_t sz_off  = (size_t)BN * EMBED * sizeof(float);
  const size_t sz_attn = (size_t)BN * 128 * sizeof(float);
  // weight-transform area (union of bf16 path 320KB and f32 hi/lo path 640KB)
  const size_t sz_T    = (size_t)(256 * 256 * 2 + 256 * 128) * 2 /*hi+lo*/ * 2;
  const size_t need_mfma = 256 + sz_v + sz_off + sz_attn + sz_T;
  const size_t need_full = 256 + sz_v + sz_off + sz_attn;
  const size_t need_mid  = 256 + sz_v + sz_off;

  if (ws_size >= need_mfma) {
    bf16*  ws_v    = (bf16*)ws_base;                    // v stored as bf16 (22.3MB)
    float* ws_off  = (float*)(ws_base + sz_v);
    float* ws_attn = (float*)(ws_base + sz_v + sz_off);
    unsigned short* wsT = (unsigned short*)(ws_base + sz_v + sz_off + sz_attn);
    // bf16 path layout
    unsigned short* wsT_v    = wsT;
    unsigned short* wsT_off  = wsT + 256 * 256;
    unsigned short* wsT_attn = wsT + 2 * 256 * 256;
    // f32 path layout (same area; only one path runs)
    bf16* Tvh = (bf16*)wsT;
    bf16* Tvl = Tvh + 256 * 256;
    bf16* Toh = Tvl + 256 * 256;
    bf16* Tol = Toh + 256 * 256;
    bf16* Tah = Tol + 256 * 256;
    bf16* Tal = Tah + 256 * 128;

    // bf16 path (flag==1): 64-row blocks, direct-global (R12 proven form)
    const int rbV64 = (BM + 63) / 64;
    const int rbQ64 = (BN + 63) / 64;
    k_transpose_bf16<<<16, 256, 0, stream>>>((const unsigned short*)W_v,    wsT_v,    256, 256, flag);
    k_transpose_bf16<<<16, 256, 0, stream>>>((const unsigned short*)W_off,  wsT_off,  256, 256, flag);
    k_transpose_bf16<<< 8, 256, 0, stream>>>((const unsigned short*)W_attn, wsT_attn, 256, 128, flag);
    k_mfma_proj<bf16 ><<<rbV64 * 2, 256, 0, stream>>>((const bf16*)value, (const bf16*)wsT_v,
                                                      b_v, ws_v, BM, 256, flag);
    k_mfma_proj<float><<<rbQ64 * 2, 256, 0, stream>>>((const bf16*)query, (const bf16*)wsT_off,
                                                      b_off, ws_off, BN, 256, flag);
    k_mfma_proj<float><<<rbQ64,     256, 0, stream>>>((const bf16*)query, (const bf16*)wsT_attn,
                                                      b_attn, ws_attn, BN, 128, flag);

    // f32 path (flag==0): LDS-staged split-bf16 MFMA, 32-row blocks, nt-streams
    const int gV32 = (BM + 31) / 32;   // 1360
    const int gQ32 = (BN + 31) / 32;   // 625
    k_wsplit_all<<<40, 256, 0, stream>>>((const float*)W_v, (const float*)W_off,
                                         (const float*)W_attn,
                                         Tvh, Tvl, Toh, Tol, Tah, Tal, flag);
    k_mfma_projf2<4, bf16 ><<<gV32, 256, 0, stream>>>((const float*)value, Tvh, Tvl,
                                                      (const float*)b_v, ws_v, BM, flag);
    k_mfma_projf2<4, float><<<gQ32, 256, 0, stream>>>((const float*)query, Toh, Tol,
                                                      (const float*)b_off, ws_off, BN, flag);
    k_mfma_projf2<2, float><<<gQ32, 128, 0, stream>>>((const float*)query, Tah, Tal,
                                                      (const float*)b_attn, ws_attn, BN, flag);

    k_fused2<bf16><<<BN, 256, 0, stream>>>(ref_points, ws_off, ws_attn, ws_v,
                                           d_out, N, BN, flag);
  } else if (ws_size >= need_full) {
    float* ws_v    = (float*)ws_base;
    float* ws_off  = (float*)(ws_base + sz_v);
    float* ws_attn = (float*)(ws_base + sz_v + sz_off);
    k_vgemv4x4<<<(BM + 15) / 16, 256, 0, stream>>>(value, W_v, b_v, ws_v, BM, flag);
    k_vgemv4x4<<<(BN + 15) / 16, 256, 0, stream>>>(query, W_off, b_off, ws_off, BN, flag);
    k_agemv4<<<(BN + 15) / 16, 256, 0, stream>>>(query, W_attn, b_attn, ws_attn, BN, flag);
    k_fused2<float><<<BN, 256, 0, stream>>>(ref_points, ws_off, ws_attn, ws_v,
                                            d_out, N, BN, flag);
  } else if (ws_size >= need_mid) {
    float* ws_v   = (float*)ws_base;
    float* ws_off = (float*)(ws_base + sz_v);
    k_vgemv8<<<(BM + 7) / 8, 256, 0, stream>>>(value, W_v, b_v, ws_v, BM, flag);
    k_vgemv8<<<(BN + 7) / 8, 256, 0, stream>>>(query, W_off, b_off, ws_off, BN, flag);
    k_fused<float><<<BN, 256, 0, stream>>>(query, ref_points, ws_off,
                                           W_attn, b_attn, ws_v, d_out, N, BN, flag);
  } else {
    bf16* ws_v = (bf16*)ws_base;
    k_value_proj<bf16><<<BM, 256, 0, stream>>>(value, W_v, b_v, ws_v, BM, flag);
    k_fused_fb<bf16><<<BN, 256, 0, stream>>>(query, ref_points, W_off, b_off,
                                             W_attn, b_attn, ws_v, d_out, N, BN, flag);
  }
}

// Round 12
// 287.469 us; speedup vs baseline: 1.2841x; 1.1044x over previous
//
#include <hip/hip_runtime.h>
#include <hip/hip_bf16.h>

// DeformableAttention3D — MI355X (gfx950)
// R19 = R18 with the launch chain collapsed 12 -> 4 (sum of dispatch times
// ~195us vs total 317us -> ~110us of launch/gap overhead + dead launches):
//   * k_prep: blocks self-detect dtype; blocks 0-39 = f32 w-split,
//     40-79 = bf16 transposes; block 0 publishes flag. (replaces 5 launches)
//   * k_proj_all: bf16-path 3 GEMMs in one grid (segment decode).
//   * k_projf2_all: f32-path 3 split-bf16 GEMMs in one grid.
//   * k_fused2: s_part -> [2][2][128] plane layout (kills 5.1M bank-conf).
// Kernel bodies otherwise verbatim R18.
#define EMBED    256
#define HEADS    8
#define LEVELS   4
#define POINTS   4
#define BATCH    2
#define M_TOT    21760   // 128*128 + 64*64 + 32*32 + 16*16
#define LDP      (EMBED + 4)

typedef __hip_bfloat16 bf16;
typedef __attribute__((ext_vector_type(8))) short short8;
typedef __attribute__((ext_vector_type(8))) short bf16x8s;
typedef __attribute__((ext_vector_type(4))) float f32x4;

__device__ __constant__ int c_H[LEVELS]  = {128, 64, 32, 16};
__device__ __constant__ int c_St[LEVELS] = {0, 16384, 20480, 21504};

template<bool BF>
__device__ __forceinline__ float ldf(const void* p, size_t i) {
  if (BF) return __bfloat162float(((const bf16*)p)[i]);
  else    return ((const float*)p)[i];
}
__device__ __forceinline__ float vt2f(float x) { return x; }
__device__ __forceinline__ float vt2f(bf16 x)  { return __bfloat162float(x); }

__device__ __forceinline__ void stout(float* p, float v) { *p = v; }
__device__ __forceinline__ void stout(bf16* p, float v)  { *p = __float2bfloat16(v); }

__device__ __forceinline__ void ld2c(const bf16* p, float& lo, float& hi) {
  unsigned u = *(const unsigned*)p;
  lo = __uint_as_float(u << 16);
  hi = __uint_as_float(u & 0xFFFF0000u);
}
__device__ __forceinline__ void ld2c(const float* p, float& lo, float& hi) {
  float2 f = *(const float2*)p;
  lo = f.x; hi = f.y;
}

template<bool BF>
__device__ __forceinline__ float4 ld4(const void* p, size_t i) {
  if (BF) {
    ushort4 u = *(const ushort4*)((const bf16*)p + i);
    float4 f;
    f.x = __bfloat162float(*reinterpret_cast<bf16*>(&u.x));
    f.y = __bfloat162float(*reinterpret_cast<bf16*>(&u.y));
    f.z = __bfloat162float(*reinterpret_cast<bf16*>(&u.z));
    f.w = __bfloat162float(*reinterpret_cast<bf16*>(&u.w));
    return f;
  } else {
    return *(const float4*)((const float*)p + i);
  }
}

__device__ __forceinline__ void fma4(float4& ac, float s, const float4& wv) {
  ac.x = fmaf(s, wv.x, ac.x);
  ac.y = fmaf(s, wv.y, ac.y);
  ac.z = fmaf(s, wv.z, ac.z);
  ac.w = fmaf(s, wv.w, ac.w);
}

__device__ __forceinline__ void split8(const f32x4 x, const f32x4 y,
                                       bf16x8s& h, bf16x8s& l) {
  float f[8] = {x[0], x[1], x[2], x[3], y[0], y[1], y[2], y[3]};
#pragma unroll
  for (int j = 0; j < 8; ++j) {
    bf16 hb = __float2bfloat16(f[j]);
    float r = f[j] - __bfloat162float(hb);
    bf16 lb = __float2bfloat16(r);
    h[j] = *reinterpret_cast<short*>(&hb);
    l[j] = *reinterpret_cast<short*>(&lb);
  }
}

// detect helper: returns 1 if buffers look bf16 (no inf/nan patterns)
__device__ __forceinline__ int block_detect(const unsigned short* q16, int t,
                                            int* cnt) {
  if (t == 0) *cnt = 0;
  __syncthreads();
  int c = 0;
  for (int i = t; i < 8192; i += 256) {
    unsigned short v = q16[i];
    if ((v & 0x7F80u) == 0x7F80u) ++c;
  }
  if (c) atomicAdd(cnt, c);
  __syncthreads();
  return (*cnt == 0) ? 1 : 0;
}

// ---------------------------------------------------------------------------
// R19 k_prep: 80 blocks. Each self-detects dtype.
//   blocks 0-39  (f32 path): W -> transposed hi/lo bf16 split.
//   blocks 40-79 (bf16 path): W -> transposed bf16.
//   block 0 publishes flag for downstream kernels.
// ---------------------------------------------------------------------------
__global__ __launch_bounds__(256)
void k_prep(const unsigned short* __restrict__ q16, int* __restrict__ flag,
            const void* __restrict__ Wv, const void* __restrict__ Woff,
            const void* __restrict__ Wattn,
            unsigned short* __restrict__ wsT_v,
            unsigned short* __restrict__ wsT_off,
            unsigned short* __restrict__ wsT_attn,
            bf16* __restrict__ Tvh, bf16* __restrict__ Tvl,
            bf16* __restrict__ Toh, bf16* __restrict__ Tol,
            bf16* __restrict__ Tah, bf16* __restrict__ Tal) {
  __shared__ int cnt;
  __shared__ float  ftile[64][65];
  __shared__ unsigned short stile[64][65];

  const int t = threadIdx.x;
  const int isbf = block_detect(q16, t, &cnt);
  if ((int)blockIdx.x == 0 && t == 0) flag[0] = isbf;

  const int row = t >> 2;
  const int cq  = (t & 3) << 4;
  const int K = 256;

  if ((int)blockIdx.x < 40) {
    if (isbf) return;                       // f32 split path
    int bid = (int)blockIdx.x;
    const float* W; bf16 *H, *L; int N;
    if (bid < 16)      { W = (const float*)Wv;    H = Tvh; L = Tvl; N = 256; }
    else if (bid < 32) { W = (const float*)Woff;  H = Toh; L = Tol; N = 256; bid -= 16; }
    else               { W = (const float*)Wattn; H = Tah; L = Tal; N = 128; bid -= 32; }
    const int ntn = N >> 6;
    const int tk = bid / ntn, tn = bid % ntn;
    const int k0 = tk << 6, n0 = tn << 6;
    const float* src = W + (size_t)(k0 + row) * N + n0 + cq;
#pragma unroll
    for (int j = 0; j < 16; ++j) ftile[row][cq + j] = src[j];
    __syncthreads();
    const size_t d0 = (size_t)(n0 + row) * K + k0 + cq;
#pragma unroll
    for (int j = 0; j < 16; ++j) {
      float v = ftile[cq + j][row];
      bf16 hb = __float2bfloat16(v);
      float r = v - __bfloat162float(hb);
      H[d0 + j] = hb;
      L[d0 + j] = __float2bfloat16(r);
    }
  } else {
    if (!isbf) return;                      // bf16 transpose path
    int bid = (int)blockIdx.x - 40;
    const unsigned short* W; unsigned short* WT; int N;
    if (bid < 16)      { W = (const unsigned short*)Wv;    WT = wsT_v;    N = 256; }
    else if (bid < 32) { W = (const unsigned short*)Woff;  WT = wsT_off;  N = 256; bid -= 16; }
    else               { W = (const unsigned short*)Wattn; WT = wsT_attn; N = 128; bid -= 32; }
    const int ntn = N >> 6;
    const int tk = bid / ntn, tn = bid % ntn;
    const int k0 = tk << 6, n0 = tn << 6;
    const unsigned short* src = W + (size_t)(k0 + row) * N + n0 + cq;
#pragma unroll
    for (int j = 0; j < 16; ++j) stile[row][cq + j] = src[j];
    __syncthreads();
    unsigned short* dst = WT + (size_t)(n0 + row) * K + k0 + cq;
#pragma unroll
    for (int j = 0; j < 16; ++j) dst[j] = stile[cq + j][row];
  }
}

// ---------------------------------------------------------------------------
// R19 k_proj_all: bf16-input MFMA projections, all 3 in one grid (flag==1).
// seg0: value->Cv(bf16) N=256; seg1: query->Coff(f32) N=256;
// seg2: query->Cattn(f32) N=128.
// ---------------------------------------------------------------------------
__global__ __launch_bounds__(256)
void k_proj_all(const bf16* __restrict__ value, const bf16* __restrict__ query,
                const unsigned short* __restrict__ wsT_v,
                const unsigned short* __restrict__ wsT_off,
                const unsigned short* __restrict__ wsT_attn,
                const void* __restrict__ b_v, const void* __restrict__ b_off,
                const void* __restrict__ b_attn,
                bf16* __restrict__ Cv, float* __restrict__ Coff,
                float* __restrict__ Cattn,
                int BM, int BN, int g0, int g1,
                const int* __restrict__ flag) {
  if (*flag != 1) return;
  int bid = (int)blockIdx.x;
  int seg, sb;
  if (bid < g0)            { seg = 0; sb = bid; }
  else if (bid < g0 + g1)  { seg = 1; sb = bid - g0; }
  else                     { seg = 2; sb = bid - g0 - g1; }

  const bf16* A; const bf16* WT; const void* bias; int M, N;
  if (seg == 0)      { A = value; WT = (const bf16*)wsT_v;    bias = b_v;    M = BM; N = 256; }
  else if (seg == 1) { A = query; WT = (const bf16*)wsT_off;  bias = b_off;  M = BN; N = 256; }
  else               { A = query; WT = (const bf16*)wsT_attn; bias = b_attn; M = BN; N = 128; }

  const int colBlocks = N >> 7;
  const int rb = sb / colBlocks;
  const int cb = sb % colBlocks;
  const int t   = threadIdx.x;
  const int wid = t >> 6;
  const int l   = t & 63;
  const int lrow = l & 15;
  const int lk8  = (l >> 4) << 3;
  const int r0 = rb * 64 + (wid & 1) * 32;
  const int c0 = cb * 128 + (wid >> 1) * 64;

  f32x4 acc[2][4];
#pragma unroll
  for (int rf = 0; rf < 2; ++rf)
#pragma unroll
    for (int cf = 0; cf < 4; ++cf) acc[rf][cf] = (f32x4){0.f, 0.f, 0.f, 0.f};

  const bf16* Ap0 = A + (size_t)min(r0 + lrow,      M - 1) * EMBED + lk8;
  const bf16* Ap1 = A + (size_t)min(r0 + 16 + lrow, M - 1) * EMBED + lk8;
  const bf16* Bp  = WT + (size_t)(c0 + lrow) * EMBED + lk8;

#pragma unroll
  for (int k = 0; k < EMBED; k += 32) {
    bf16x8s a0 = *(const bf16x8s*)(Ap0 + k);
    bf16x8s a1 = *(const bf16x8s*)(Ap1 + k);
    bf16x8s b0 = *(const bf16x8s*)(Bp + 0 * 16 * EMBED + k);
    bf16x8s b1 = *(const bf16x8s*)(Bp + 1 * 16 * EMBED + k);
    bf16x8s b2 = *(const bf16x8s*)(Bp + 2 * 16 * EMBED + k);
    bf16x8s b3 = *(const bf16x8s*)(Bp + 3 * 16 * EMBED + k);
    acc[0][0] = __builtin_amdgcn_mfma_f32_16x16x32_bf16(a0, b0, acc[0][0], 0, 0, 0);
    acc[0][1] = __builtin_amdgcn_mfma_f32_16x16x32_bf16(a0, b1, acc[0][1], 0, 0, 0);
    acc[0][2] = __builtin_amdgcn_mfma_f32_16x16x32_bf16(a0, b2, acc[0][2], 0, 0, 0);
    acc[0][3] = __builtin_amdgcn_mfma_f32_16x16x32_bf16(a0, b3, acc[0][3], 0, 0, 0);
    acc[1][0] = __builtin_amdgcn_mfma_f32_16x16x32_bf16(a1, b0, acc[1][0], 0, 0, 0);
    acc[1][1] = __builtin_amdgcn_mfma_f32_16x16x32_bf16(a1, b1, acc[1][1], 0, 0, 0);
    acc[1][2] = __builtin_amdgcn_mfma_f32_16x16x32_bf16(a1, b2, acc[1][2], 0, 0, 0);
    acc[1][3] = __builtin_amdgcn_mfma_f32_16x16x32_bf16(a1, b3, acc[1][3], 0, 0, 0);
  }

  const int rbase = (l >> 4) << 2;
#pragma unroll
  for (int cf = 0; cf < 4; ++cf) {
    const int col = c0 + cf * 16 + lrow;
    const float bv = ldf<true>(bias, col);
#pragma unroll
    for (int rf = 0; rf < 2; ++rf) {
#pragma unroll
      for (int r = 0; r < 4; ++r) {
        const int row = r0 + rf * 16 + rbase + r;
        if (row < M) {
          float o = acc[rf][cf][r] + bv;
          size_t idx = (size_t)row * N + col;
          if (seg == 0)      Cv[idx]   = __float2bfloat16(o);
          else if (seg == 1) Coff[idx] = o;
          else               Cattn[idx] = o;
        }
      }
    }
  }
}

// ---------------------------------------------------------------------------
// R19 k_projf2_all: f32-input split-bf16 MFMA, LDS-staged A, all 3 in one
// grid (flag==0). seg0: value->Cv bf16; seg1: query->Coff f32 nt;
// seg2: query->Cattn f32 nt (N=128; waves 2-3 stage-only).
// ---------------------------------------------------------------------------
__global__ __launch_bounds__(256)
void k_projf2_all(const float* __restrict__ value, const float* __restrict__ query,
                  const bf16* __restrict__ Tvh, const bf16* __restrict__ Tvl,
                  const bf16* __restrict__ Toh, const bf16* __restrict__ Tol,
                  const bf16* __restrict__ Tah, const bf16* __restrict__ Tal,
                  const float* __restrict__ b_v, const float* __restrict__ b_off,
                  const float* __restrict__ b_attn,
                  bf16* __restrict__ Cv, float* __restrict__ Coff,
                  float* __restrict__ Cattn,
                  int BM, int BN, int gV, int gQ,
                  const int* __restrict__ flag) {
  if (*flag != 0) return;
  int bid = (int)blockIdx.x;
  int seg, rblk;
  if (bid < gV)           { seg = 0; rblk = bid; }
  else if (bid < gV + gQ) { seg = 1; rblk = bid - gV; }
  else                    { seg = 2; rblk = bid - gV - gQ; }

  const float* A; const bf16 *Bh0, *Bl0; const float* bias; int M, N;
  if (seg == 0)      { A = value; Bh0 = Tvh; Bl0 = Tvl; bias = b_v;    M = BM; N = 256; }
  else if (seg == 1) { A = query; Bh0 = Toh; Bl0 = Tol; bias = b_off;  M = BN; N = 256; }
  else               { A = query; Bh0 = Tah; Bl0 = Tal; bias = b_attn; M = BN; N = 128; }

  const int t   = threadIdx.x;
  const int wid = t >> 6;
  const int l   = t & 63;
  const int lrow = l & 15;
  const int lk8  = (l >> 4) << 3;
  const int r0 = rblk * 32;
  const int c0 = wid * 64;
  const bool active = (seg != 2) || (wid < 2);

  __shared__ float As[32][260];

  // stage 32 rows x 256 f32, nontemporal (all 4 waves; 8 rows each)
#pragma unroll
  for (int base = 0; base < 8; base += 8) {
    f32x4 tmp[8];
#pragma unroll
    for (int i = 0; i < 8; ++i) {
      int r   = wid + (base + i) * 4;
      int row = min(r0 + r, M - 1);
      tmp[i] = __builtin_nontemporal_load(
                 (const f32x4*)(A + (size_t)row * EMBED + (l << 2)));
    }
#pragma unroll
    for (int i = 0; i < 8; ++i) {
      int r = wid + (base + i) * 4;
      *(f32x4*)&As[r][l << 2] = tmp[i];
    }
  }
  __syncthreads();

  if (!active) return;

  f32x4 acc[2][4];
#pragma unroll
  for (int rf = 0; rf < 2; ++rf)
#pragma unroll
    for (int cf = 0; cf < 4; ++cf) acc[rf][cf] = (f32x4){0.f, 0.f, 0.f, 0.f};

  const bf16* Bh = Bh0 + (size_t)(c0 + lrow) * EMBED + lk8;
  const bf16* Bl = Bl0 + (size_t)(c0 + lrow) * EMBED + lk8;

#pragma unroll
  for (int ks = 0; ks < 8; ++ks) {
    const int k = ks * 32;
    bf16x8s a0h, a0l, a1h, a1l;
    split8(*(const f32x4*)&As[lrow     ][k + lk8],
           *(const f32x4*)&As[lrow     ][k + lk8 + 4], a0h, a0l);
    split8(*(const f32x4*)&As[lrow + 16][k + lk8],
           *(const f32x4*)&As[lrow + 16][k + lk8 + 4], a1h, a1l);
    bf16x8s bh0 = *(const bf16x8s*)(Bh + 0 * 16 * EMBED + k);
    bf16x8s bh1 = *(const bf16x8s*)(Bh + 1 * 16 * EMBED + k);
    bf16x8s bh2 = *(const bf16x8s*)(Bh + 2 * 16 * EMBED + k);
    bf16x8s bh3 = *(const bf16x8s*)(Bh + 3 * 16 * EMBED + k);
    bf16x8s bl0 = *(const bf16x8s*)(Bl + 0 * 16 * EMBED + k);
    bf16x8s bl1 = *(const bf16x8s*)(Bl + 1 * 16 * EMBED + k);
    bf16x8s bl2 = *(const bf16x8s*)(Bl + 2 * 16 * EMBED + k);
    bf16x8s bl3 = *(const bf16x8s*)(Bl + 3 * 16 * EMBED + k);
    acc[0][0] = __builtin_amdgcn_mfma_f32_16x16x32_bf16(a0h, bh0, acc[0][0], 0, 0, 0);
    acc[0][1] = __builtin_amdgcn_mfma_f32_16x16x32_bf16(a0h, bh1, acc[0][1], 0, 0, 0);
    acc[0][2] = __builtin_amdgcn_mfma_f32_16x16x32_bf16(a0h, bh2, acc[0][2], 0, 0, 0);
    acc[0][3] = __builtin_amdgcn_mfma_f32_16x16x32_bf16(a0h, bh3, acc[0][3], 0, 0, 0);
    acc[1][0] = __builtin_amdgcn_mfma_f32_16x16x32_bf16(a1h, bh0, acc[1][0], 0, 0, 0);
    acc[1][1] = __builtin_amdgcn_mfma_f32_16x16x32_bf16(a1h, bh1, acc[1][1], 0, 0, 0);
    acc[1][2] = __builtin_amdgcn_mfma_f32_16x16x32_bf16(a1h, bh2, acc[1][2], 0, 0, 0);
    acc[1][3] = __builtin_amdgcn_mfma_f32_16x16x32_bf16(a1h, bh3, acc[1][3], 0, 0, 0);
    acc[0][0] = __builtin_amdgcn_mfma_f32_16x16x32_bf16(a0h, bl0, acc[0][0], 0, 0, 0);
    acc[0][1] = __builtin_amdgcn_mfma_f32_16x16x32_bf16(a0h, bl1, acc[0][1], 0, 0, 0);
    acc[0][2] = __builtin_amdgcn_mfma_f32_16x16x32_bf16(a0h, bl2, acc[0][2], 0, 0, 0);
    acc[0][3] = __builtin_amdgcn_mfma_f32_16x16x32_bf16(a0h, bl3, acc[0][3], 0, 0, 0);
    acc[1][0] = __builtin_amdgcn_mfma_f32_16x16x32_bf16(a1h, bl0, acc[1][0], 0, 0, 0);
    acc[1][1] = __builtin_amdgcn_mfma_f32_16x16x32_bf16(a1h, bl1, acc[1][1], 0, 0, 0);
    acc[1][2] = __builtin_amdgcn_mfma_f32_16x16x32_bf16(a1h, bl2, acc[1][2], 0, 0, 0);
    acc[1][3] = __builtin_amdgcn_mfma_f32_16x16x32_bf16(a1h, bl3, acc[1][3], 0, 0, 0);
    acc[0][0] = __builtin_amdgcn_mfma_f32_16x16x32_bf16(a0l, bh0, acc[0][0], 0, 0, 0);
    acc[0][1] = __builtin_amdgcn_mfma_f32_16x16x32_bf16(a0l, bh1, acc[0][1], 0, 0, 0);
    acc[0][2] = __builtin_amdgcn_mfma_f32_16x16x32_bf16(a0l, bh2, acc[0][2], 0, 0, 0);
    acc[0][3] = __builtin_amdgcn_mfma_f32_16x16x32_bf16(a0l, bh3, acc[0][3], 0, 0, 0);
    acc[1][0] = __builtin_amdgcn_mfma_f32_16x16x32_bf16(a1l, bh0, acc[1][0], 0, 0, 0);
    acc[1][1] = __builtin_amdgcn_mfma_f32_16x16x32_bf16(a1l, bh1, acc[1][1], 0, 0, 0);
    acc[1][2] = __builtin_amdgcn_mfma_f32_16x16x32_bf16(a1l, bh2, acc[1][2], 0, 0, 0);
    acc[1][3] = __builtin_amdgcn_mfma_f32_16x16x32_bf16(a1l, bh3, acc[1][3], 0, 0, 0);
  }

  const int rbase = (l >> 4) << 2;
#pragma unroll
  for (int cf = 0; cf < 4; ++cf) {
    const int col = c0 + cf * 16 + lrow;
    const float bv = bias[col];
#pragma unroll
    for (int rf = 0; rf < 2; ++rf) {
#pragma unroll
      for (int r = 0; r < 4; ++r) {
        const int row = r0 + rf * 16 + rbase + r;
        if (row < M) {
          float o = acc[rf][cf][r] + bv;
          size_t idx = (size_t)row * N + col;
          if (seg == 0)      Cv[idx] = __float2bfloat16(o);
          else if (seg == 1) __builtin_nontemporal_store(o, &Coff[idx]);
          else               __builtin_nontemporal_store(o, &Cattn[idx]);
        }
      }
    }
  }
}

// ---------------------------------------------------------------------------
// shared staging: 16 rows of A into padded LDS tile (fallback tiers)
// ---------------------------------------------------------------------------
template<bool BF>
__device__ __forceinline__ void stage16(const void* __restrict__ A,
                                        float (*rowA)[LDP],
                                        int r0, int M, int t) {
  int r  = t >> 4;
  int rr = min(r0 + r, M - 1);
  int c0 = (t & 15) * 16;
  if (BF) {
    const bf16* ap = (const bf16*)A + (size_t)rr * EMBED + c0;
    short8 a0 = *(const short8*)ap;
    short8 a1 = *(const short8*)(ap + 8);
#pragma unroll
    for (int j = 0; j < 8; ++j) {
      short s0 = a0[j], s1 = a1[j];
      rowA[r][c0 + j]     = __bfloat162float(*reinterpret_cast<bf16*>(&s0));
      rowA[r][c0 + 8 + j] = __bfloat162float(*reinterpret_cast<bf16*>(&s1));
    }
  } else {
    const float* ap = (const float*)A + (size_t)rr * EMBED + c0;
#pragma unroll
    for (int j = 0; j < 4; ++j) {
      float4 f = *(const float4*)(ap + j * 4);
      rowA[r][c0 + j * 4 + 0] = f.x;
      rowA[r][c0 + j * 4 + 1] = f.y;
      rowA[r][c0 + j * 4 + 2] = f.z;
      rowA[r][c0 + j * 4 + 3] = f.w;
    }
  }
}

// ---------------------------------------------------------------------------
// fallback tier kernels (unchanged)
// ---------------------------------------------------------------------------
template<bool BF>
__device__ void vgemv4x4_body(const void* __restrict__ A, const void* __restrict__ W,
                              const void* __restrict__ bias, float* __restrict__ C,
                              int M) {
  const int t  = threadIdx.x;
  const int r0 = blockIdx.x * 16;
  if (r0 >= M) return;

  __shared__ float rowA[16][LDP];
  stage16<BF>(A, rowA, r0, M, t);
  __syncthreads();

  const int g  = t >> 6;
  const int c0 = (t & 63) * 4;

  float4 bv;
  bv.x = ldf<BF>(bias, c0 + 0);
  bv.y = ldf<BF>(bias, c0 + 1);
  bv.z = ldf<BF>(bias, c0 + 2);
  bv.w = ldf<BF>(bias, c0 + 3);

  float4 acc[4];
#pragma unroll
  for (int r = 0; r < 4; ++r) acc[r] = bv;

#pragma unroll 2
  for (int k = 0; k < EMBED; k += 4) {
    float4 av[4];
#pragma unroll
    for (int r = 0; r < 4; ++r)
      av[r] = *(const float4*)&rowA[g * 4 + r][k];
    float4 w0 = ld4<BF>(W, (size_t)(k + 0) * EMBED + c0);
    float4 w1 = ld4<BF>(W, (size_t)(k + 1) * EMBED + c0);
    float4 w2 = ld4<BF>(W, (size_t)(k + 2) * EMBED + c0);
    float4 w3 = ld4<BF>(W, (size_t)(k + 3) * EMBED + c0);
#pragma unroll
    for (int r = 0; r < 4; ++r) {
      fma4(acc[r], av[r].x, w0);
      fma4(acc[r], av[r].y, w1);
      fma4(acc[r], av[r].z, w2);
      fma4(acc[r], av[r].w, w3);
    }
  }
#pragma unroll
  for (int r = 0; r < 4; ++r) {
    int row = r0 + g * 4 + r;
    if (row < M) *(float4*)&C[(size_t)row * EMBED + c0] = acc[r];
  }
}

__global__ __launch_bounds__(256)
void k_vgemv4x4(const void* A, const void* W, const void* bias, float* C,
                int M, const int* flag) {
  if (*flag) vgemv4x4_body<true >(A, W, bias, C, M);
  else       vgemv4x4_body<false>(A, W, bias, C, M);
}

template<bool BF>
__device__ void agemv4_body(const void* __restrict__ A, const void* __restrict__ W,
                            const void* __restrict__ bias, float* __restrict__ C,
                            int M) {
  const int t  = threadIdx.x;
  const int r0 = blockIdx.x * 16;
  if (r0 >= M) return;

  __shared__ float rowA[16][LDP];
  stage16<BF>(A, rowA, r0, M, t);
  __syncthreads();

  const int g  = t >> 5;
  const int c0 = (t & 31) * 4;

  float4 bv;
  bv.x = ldf<BF>(bias, c0 + 0);
  bv.y = ldf<BF>(bias, c0 + 1);
  bv.z = ldf<BF>(bias, c0 + 2);
  bv.w = ldf<BF>(bias, c0 + 3);

  float4 acc[2];
  acc[0] = bv; acc[1] = bv;

#pragma unroll 2
  for (int k = 0; k < EMBED; k += 4) {
    float4 a0 = *(const float4*)&rowA[g * 2 + 0][k];
    float4 a1 = *(const float4*)&rowA[g * 2 + 1][k];
    float4 w0 = ld4<BF>(W, (size_t)(k + 0) * 128 + c0);
    float4 w1 = ld4<BF>(W, (size_t)(k + 1) * 128 + c0);
    float4 w2 = ld4<BF>(W, (size_t)(k + 2) * 128 + c0);
    float4 w3 = ld4<BF>(W, (size_t)(k + 3) * 128 + c0);
    fma4(acc[0], a0.x, w0); fma4(acc[0], a0.y, w1);
    fma4(acc[0], a0.z, w2); fma4(acc[0], a0.w, w3);
    fma4(acc[1], a1.x, w0); fma4(acc[1], a1.y, w1);
    fma4(acc[1], a1.z, w2); fma4(acc[1], a1.w, w3);
  }
#pragma unroll
  for (int r = 0; r < 2; ++r) {
    int row = r0 + g * 2 + r;
    if (row < M) *(float4*)&C[(size_t)row * 128 + c0] = acc[r];
  }
}

__global__ __launch_bounds__(256)
void k_agemv4(const void* A, const void* W, const void* bias, float* C,
              int M, const int* flag) {
  if (*flag) agemv4_body<true >(A, W, bias, C, M);
  else       agemv4_body<false>(A, W, bias, C, M);
}

// ---------------------------------------------------------------------------
// R19 k_fused2: softmax+pack + 2-ch/lane gather; s_part plane layout
// (conflict-free writes, 2-way reads).
// ---------------------------------------------------------------------------
template<bool BF, class VT>
__device__ void fused2_body(const void* __restrict__ ref_points,
                            const float* __restrict__ off_pre,
                            const float* __restrict__ scores,
                            const VT* __restrict__ v,
                            void* __restrict__ out, int N, int BN) {
  int q = blockIdx.x;
  if (q >= BN) return;
  int b = q / N;
  int t = threadIdx.x;

  __shared__ float  s_aw[128];
  __shared__ float  s_rp[2];
  __shared__ int4   s_pi[128];
  __shared__ float4 s_pw[128];
  __shared__ float  s_part[2][2][128];   // [half][hi/lo][pair]

  if (t < 2)   s_rp[t] = ldf<BF>(ref_points, (size_t)q * 2 + t);
  if (t < 128) s_aw[t] = __builtin_nontemporal_load(&scores[(size_t)q * 128 + t]);
  __syncthreads();

  if (t < 128) {
    int base = t & ~15;
    float mx = -1e30f;
#pragma unroll
    for (int i = 0; i < 16; ++i) mx = fmaxf(mx, s_aw[base + i]);
    float sum = 0.f;
#pragma unroll
    for (int i = 0; i < 16; ++i) sum += expf(s_aw[base + i] - mx);
    float wa = expf(s_aw[t] - mx) / sum;

    int   l  = (t >> 2) & 3;
    int   Wl = 128 >> l;
    float fW = (float)Wl;
    int   st = (int)((65536u - (65536u >> (2 * l))) / 3u);
    float ox = __builtin_nontemporal_load(&off_pre[(size_t)q * EMBED + 2 * t])     - 0.5f;
    float oy = __builtin_nontemporal_load(&off_pre[(size_t)q * EMBED + 2 * t + 1]) - 0.5f;
    float x = fmaf(s_rp[0], fW, ox);
    float y = fmaf(s_rp[1], fW, oy);
    float x0f = floorf(x), y0f = floorf(y);
    float lx = x - x0f, ly = y - y0f;
    int x0 = (int)x0f, y0 = (int)y0f;
    int x1 = x0 + 1,   y1 = y0 + 1;
    float w00 = wa * (1.f - lx) * (1.f - ly);
    float w01 = wa * lx * (1.f - ly);
    float w10 = wa * (1.f - lx) * ly;
    float w11 = wa * lx * ly;
    bool vx0 = (unsigned)x0 < (unsigned)Wl;
    bool vx1 = (unsigned)x1 < (unsigned)Wl;
    bool vy0 = (unsigned)y0 < (unsigned)Wl;
    bool vy1 = (unsigned)y1 < (unsigned)Wl;
    int xc0 = min(max(x0, 0), Wl - 1), xc1 = min(max(x1, 0), Wl - 1);
    int yc0 = min(max(y0, 0), Wl - 1), yc1 = min(max(y1, 0), Wl - 1);
    int r0i = st + yc0 * Wl;
    int r1i = st + yc1 * Wl;
    int4 pi; float4 pw;
    pi.x = (r0i + xc0) << 8;  pw.x = (vx0 && vy0) ? w00 : 0.f;
    pi.y = (r0i + xc1) << 8;  pw.y = (vx1 && vy0) ? w01 : 0.f;
    pi.z = (r1i + xc0) << 8;  pw.z = (vx0 && vy1) ? w10 : 0.f;
    pi.w = (r1i + xc1) << 8;  pw.w = (vx1 && vy1) ? w11 : 0.f;
    s_pi[t] = pi;
    s_pw[t] = pw;
  }
  __syncthreads();

  const int c  = t & 127;
  const int s  = t >> 7;
  const int h  = c >> 4;
  const int ch = c << 1;
  const VT* vb = v + (size_t)b * (M_TOT * EMBED) + ch;
  const int cbase = (h << 4) + (s << 3);

  float oL0 = 0.f, oH0 = 0.f, oL1 = 0.f, oH1 = 0.f;
#pragma unroll
  for (int g = 0; g < 2; ++g) {
    const int c0 = cbase + (g << 2);
    int4   iA = s_pi[c0 + 0], iB = s_pi[c0 + 1], iC = s_pi[c0 + 2], iD = s_pi[c0 + 3];
    float4 wA = s_pw[c0 + 0], wB = s_pw[c0 + 1], wC = s_pw[c0 + 2], wD = s_pw[c0 + 3];
    float lA0,hA0,lA1,hA1,lA2,hA2,lA3,hA3;
    float lB0,hB0,lB1,hB1,lB2,hB2,lB3,hB3;
    float lC0,hC0,lC1,hC1,lC2,hC2,lC3,hC3;
    float lD0,hD0,lD1,hD1,lD2,hD2,lD3,hD3;
    ld2c(vb + iA.x, lA0, hA0); ld2c(vb + iA.y, lA1, hA1);
    ld2c(vb + iA.z, lA2, hA2); ld2c(vb + iA.w, lA3, hA3);
    ld2c(vb + iB.x, lB0, hB0); ld2c(vb + iB.y, lB1, hB1);
    ld2c(vb + iB.z, lB2, hB2); ld2c(vb + iB.w, lB3, hB3);
    ld2c(vb + iC.x, lC0, hC0); ld2c(vb + iC.y, lC1, hC1);
    ld2c(vb + iC.z, lC2, hC2); ld2c(vb + iC.w, lC3, hC3);
    ld2c(vb + iD.x, lD0, hD0); ld2c(vb + iD.y, lD1, hD1);
    ld2c(vb + iD.z, lD2, hD2); ld2c(vb + iD.w, lD3, hD3);
    oL0 = fmaf(wA.x, lA0, oL0); oH0 = fmaf(wA.x, hA0, oH0);
    oL1 = fmaf(wA.y, lA1, oL1); oH1 = fmaf(wA.y, hA1, oH1);
    oL0 = fmaf(wA.z, lA2, oL0); oH0 = fmaf(wA.z, hA2, oH0);
    oL1 = fmaf(wA.w, lA3, oL1); oH1 = fmaf(wA.w, hA3, oH1);
    oL0 = fmaf(wB.x, lB0, oL0); oH0 = fmaf(wB.x, hB0, oH0);
    oL1 = fmaf(wB.y, lB1, oL1); oH1 = fmaf(wB.y, hB1, oH1);
    oL0 = fmaf(wB.z, lB2, oL0); oH0 = fmaf(wB.z, hB2, oH0);
    oL1 = fmaf(wB.w, lB3, oL1); oH1 = fmaf(wB.w, hB3, oH1);
    oL0 = fmaf(wC.x, lC0, oL0); oH0 = fmaf(wC.x, hC0, oH0);
    oL1 = fmaf(wC.y, lC1, oL1); oH1 = fmaf(wC.y, hC1, oH1);
    oL0 = fmaf(wC.z, lC2, oL0); oH0 = fmaf(wC.z, hC2, oH0);
    oL1 = fmaf(wC.w, lC3, oL1); oH1 = fmaf(wC.w, hC3, oH1);
    oL0 = fmaf(wD.x, lD0, oL0); oH0 = fmaf(wD.x, hD0, oH0);
    oL1 = fmaf(wD.y, lD1, oL1); oH1 = fmaf(wD.y, hD1, oH1);
    oL0 = fmaf(wD.z, lD2, oL0); oH0 = fmaf(wD.z, hD2, oH0);
    oL1 = fmaf(wD.w, lD3, oL1); oH1 = fmaf(wD.w, hD3, oH1);
  }
  s_part[s][0][c] = oL0 + oL1;
  s_part[s][1][c] = oH0 + oH1;
  __syncthreads();

  float o = s_part[0][t & 1][t >> 1] + s_part[1][t & 1][t >> 1];
  if (BF) {
    bf16 ob = __float2bfloat16(o);
    __builtin_nontemporal_store(*reinterpret_cast<unsigned short*>(&ob),
                                (unsigned short*)out + (size_t)q * EMBED + t);
  } else {
    __builtin_nontemporal_store(o, (float*)out + (size_t)q * EMBED + t);
  }
}

template<class VT>
__global__ __launch_bounds__(256)
void k_fused2(const void* ref_points, const float* off_pre, const float* scores,
              const VT* v, void* out, int N, int BN, const int* flag) {
  if (*flag) fused2_body<true,  VT>(ref_points, off_pre, scores, v, out, N, BN);
  else       fused2_body<false, VT>(ref_points, off_pre, scores, v, out, N, BN);
}

// ---------------------------------------------------------------------------
// mid/fallback tiers (unchanged; self-contained)
// ---------------------------------------------------------------------------
__global__ __launch_bounds__(256)
void k_detect(const unsigned short* __restrict__ q16, int* __restrict__ flag) {
  __shared__ int cnt;
  int isbf = block_detect(q16, threadIdx.x, &cnt);
  if (threadIdx.x == 0) flag[0] = isbf;
}

template<bool BF>
__device__ void vgemv8_body(const void* __restrict__ A, const void* __restrict__ W,
                            const void* __restrict__ bias, float* __restrict__ C,
                            int M) {
  const int t  = threadIdx.x;
  const int r0 = blockIdx.x * 8;
  if (r0 >= M) return;

  __shared__ float rowA[8][EMBED];
  {
    int r  = t >> 5;
    int rr = min(r0 + r, M - 1);
    int c0 = (t & 31) * 8;
    if (BF) {
      const bf16* ap = (const bf16*)A + (size_t)rr * EMBED + c0;
      short8 a = *(const short8*)ap;
#pragma unroll
      for (int j = 0; j < 8; ++j) {
        short s = a[j];
        bf16 hb = *reinterpret_cast<bf16*>(&s);
        rowA[r][c0 + j] = __bfloat162float(hb);
      }
    } else {
      const float* ap = (const float*)A + (size_t)rr * EMBED + c0;
#pragma unroll
      for (int j = 0; j < 8; ++j) rowA[r][c0 + j] = ap[j];
    }
  }
  __syncthreads();

  const int n = t;
  const float b = ldf<BF>(bias, n);
  float acc[8];
#pragma unroll
  for (int r = 0; r < 8; ++r) acc[r] = b;
#pragma unroll 4
  for (int k = 0; k < EMBED; ++k) {
    float w = ldf<BF>(W, (size_t)k * EMBED + n);
#pragma unroll
    for (int r = 0; r < 8; ++r) acc[r] = fmaf(rowA[r][k], w, acc[r]);
  }
#pragma unroll
  for (int r = 0; r < 8; ++r)
    if (r0 + r < M) C[(size_t)(r0 + r) * EMBED + n] = acc[r];
}

__global__ __launch_bounds__(256)
void k_vgemv8(const void* A, const void* W, const void* bias, float* C,
              int M, const int* flag) {
  if (*flag) vgemv8_body<true >(A, W, bias, C, M);
  else       vgemv8_body<false>(A, W, bias, C, M);
}

template<bool BF, class VT>
__device__ void fusedfb_body(const void* __restrict__ query,
                             const void* __restrict__ ref_points,
                             const void* __restrict__ W_off,
                             const void* __restrict__ b_off,
                             const void* __restrict__ W_attn,
                             const void* __restrict__ b_attn,
                             const VT* __restrict__ v,
                             void* __restrict__ out, int N, int BN) {
  int q = blockIdx.x;
  if (q >= BN) return;
  int b = q / N;
  int t = threadIdx.x;

  __shared__ float row[EMBED];
  __shared__ float s_off[EMBED];
  __shared__ float s_aw[HEADS * LEVELS * POINTS];
  __shared__ float s_rp[2];

  row[t] = ldf<BF>(query, (size_t)q * EMBED + t);
  if (t < 2) s_rp[t] = ldf<BF>(ref_points, (size_t)q * 2 + t);
  __syncthreads();

  {
    float acc = ldf<BF>(b_off, t);
#pragma unroll 8
    for (int e = 0; e < EMBED; ++e)
      acc = fmaf(row[e], ldf<BF>(W_off, (size_t)e * EMBED + t), acc);
    s_off[t] = acc;
  }
  if (t < 128) {
    float acc = ldf<BF>(b_attn, t);
#pragma unroll 8
    for (int e = 0; e < EMBED; ++e)
      acc = fmaf(row[e], ldf<BF>(W_attn, (size_t)e * 128 + t), acc);
    s_aw[t] = acc;
  }
  __syncthreads();

  float aval = 0.f;
  if (t < 128) {
    int base = t & ~15;
    float mx = -1e30f;
#pragma unroll
    for (int i = 0; i < 16; ++i) mx = fmaxf(mx, s_aw[base + i]);
    float sum = 0.f;
#pragma unroll
    for (int i = 0; i < 16; ++i) sum += expf(s_aw[base + i] - mx);
    aval = expf(s_aw[t] - mx) / sum;
  }
  __syncthreads();
  if (t < 128) s_aw[t] = aval;
  __syncthreads();

  int h = t >> 5;
  const VT* vb = v + (size_t)b * M_TOT * EMBED;
  float o = 0.f;
#pragma unroll
  for (int l = 0; l < LEVELS; ++l) {
    const int Hl = c_H[l], Wl = c_H[l];
    const VT* vl = vb + (size_t)c_St[l] * EMBED;
    const float fW = (float)Wl, fH = (float)Hl;
#pragma unroll
    for (int p = 0; p < POINTS; ++p) {
      int oi = ((h * LEVELS + l) * POINTS + p) << 1;
      float x = (s_rp[0] + s_off[oi]     / fW) * fW - 0.5f;
      float y = (s_rp[1] + s_off[oi + 1] / fH) * fH - 0.5f;
      float x0f = floorf(x), y0f = floorf(y);
      float lx = x - x0f, ly = y - y0f;
      int x0 = (int)x0f, y0 = (int)y0f;
      float wa = s_aw[(h * LEVELS + l) * POINTS + p];
      float cw[4] = {(1.f - lx) * (1.f - ly), lx * (1.f - ly),
                     (1.f - lx) * ly,         lx * ly};
      const int dxs[4] = {0, 1, 0, 1};
      const int dys[4] = {0, 0, 1, 1};
#pragma unroll
      for (int cidx = 0; cidx < 4; ++cidx) {
        int xi = x0 + dxs[cidx];
        int yi = y0 + dys[cidx];
        bool valid = (xi >= 0) & (xi < Wl) & (yi >= 0) & (yi < Hl);
        int xc = min(max(xi, 0), Wl - 1);
        int yc = min(max(yi, 0), Hl - 1);
        float g = vt2f(vl[(size_t)(yc * Wl + xc) * EMBED + t]);
        o += (valid ? wa * cw[cidx] : 0.f) * g;
      }
    }
  }
  if (BF) ((bf16*)out)[(size_t)q * EMBED + t] = __float2bfloat16(o);
  else    ((float*)out)[(size_t)q * EMBED + t] = o;
}

template<class VT>
__global__ __launch_bounds__(256)
void k_fused_fb(const void* query, const void* ref_points,
                const void* W_off, const void* b_off,
                const void* W_attn, const void* b_attn,
                const VT* v, void* out, int N, int BN, const int* flag) {
  if (*flag) fusedfb_body<true,  VT>(query, ref_points, W_off, b_off, W_attn, b_attn, v, out, N, BN);
  else       fusedfb_body<false, VT>(query, ref_points, W_off, b_off, W_attn, b_attn, v, out, N, BN);
}

template<bool BF, class VT>
__device__ void vproj_body(const void* __restrict__ value,
                           const void* __restrict__ W_v,
                           const void* __restrict__ b_v,
                           VT* __restrict__ v, int BM) {
  int m = blockIdx.x;
  if (m >= BM) return;
  int t = threadIdx.x;
  __shared__ float row[EMBED];
  row[t] = ldf<BF>(value, (size_t)m * EMBED + t);
  __syncthreads();
  float acc = ldf<BF>(b_v, t);
#pragma unroll 8
  for (int e = 0; e < EMBED; ++e)
    acc = fmaf(row[e], ldf<BF>(W_v, (size_t)e * EMBED + t), acc);
  if (sizeof(VT) == 2) ((bf16*)v)[(size_t)m * EMBED + t] = __float2bfloat16(acc);
  else                 ((float*)v)[(size_t)m * EMBED + t] = acc;
}

template<class VT>
__global__ __launch_bounds__(256)
void k_value_proj(const void* value, const void* W_v, const void* b_v,
                  VT* v, int BM, const int* flag) {
  if (*flag) vproj_body<true,  VT>(value, W_v, b_v, v, BM);
  else       vproj_body<false, VT>(value, W_v, b_v, v, BM);
}

// ---------------------------------------------------------------------------
extern "C" void kernel_launch(void* const* d_in, const int* in_sizes, int n_in,
                              void* d_out, int out_size, void* d_ws, size_t ws_size,
                              hipStream_t stream) {
  const void* query      = d_in[0];
  const void* value      = d_in[2];
  const void* ref_points = d_in[3];
  const void* W_off  = d_in[6];
  const void* b_off  = d_in[7];
  const void* W_attn = d_in[8];
  const void* b_attn = d_in[9];
  const void* W_v    = d_in[10];
  const void* b_v    = d_in[11];

  const int BN = in_sizes[0] / EMBED;   // 20000
  const int BM = in_sizes[2] / EMBED;   // 43520
  const int N  = BN / BATCH;

  int*  flag    = (int*)d_ws;
  char* ws_base = (char*)d_ws + 256;

  const size_t sz_v    = (size_t)BM * EMBED * sizeof(float);
  const size_t sz_off  = (size_t)BN * EMBED * sizeof(float);
  const size_t sz_attn = (size_t)BN * 128 * sizeof(float);
  const size_t sz_T    = (size_t)(256 * 256 * 2 + 256 * 128) * 2 * 2;
  const size_t need_mfma = 256 + sz_v + sz_off + sz_attn + sz_T;
  const size_t need_full = 256 + sz_v + sz_off + sz_attn;
  const size_t need_mid  = 256 + sz_v + sz_off;

  if (ws_size >= need_mfma) {
    bf16*  ws_v    = (bf16*)ws_base;
    float* ws_off  = (float*)(ws_base + sz_v);
    float* ws_attn = (float*)(ws_base + sz_v + sz_off);
    unsigned short* wsT = (unsigned short*)(ws_base + sz_v + sz_off + sz_attn);
    unsigned short* wsT_v    = wsT;
    unsigned short* wsT_off  = wsT + 256 * 256;
    unsigned short* wsT_attn = wsT + 2 * 256 * 256;
    bf16* Tvh = (bf16*)wsT;
    bf16* Tvl = Tvh + 256 * 256;
    bf16* Toh = Tvl + 256 * 256;
    bf16* Tol = Toh + 256 * 256;
    bf16* Tah = Tol + 256 * 256;
    bf16* Tal = Tah + 256 * 128;

    const int rbV64 = (BM + 63) / 64;
    const int rbQ64 = (BN + 63) / 64;
    const int g0 = rbV64 * 2, g1 = rbQ64 * 2, g2 = rbQ64;
    const int gV32 = (BM + 31) / 32;
    const int gQ32 = (BN + 31) / 32;

    // 1) prep: self-detect + weight transform for both dtype paths
    k_prep<<<80, 256, 0, stream>>>((const unsigned short*)query, flag,
                                   W_v, W_off, W_attn,
                                   wsT_v, wsT_off, wsT_attn,
                                   Tvh, Tvl, Toh, Tol, Tah, Tal);
    // 2) bf16-input path (dead if f32)
    k_proj_all<<<g0 + g1 + g2, 256, 0, stream>>>(
        (const bf16*)value, (const bf16*)query,
        wsT_v, wsT_off, wsT_attn, b_v, b_off, b_attn,
        ws_v, ws_off, ws_attn, BM, BN, g0, g1, flag);
    // 3) f32-input path (dead if bf16)
    k_projf2_all<<<gV32 + 2 * gQ32, 256, 0, stream>>>(
        (const float*)value, (const float*)query,
        Tvh, Tvl, Toh, Tol, Tah, Tal,
        (const float*)b_v, (const float*)b_off, (const float*)b_attn,
        ws_v, ws_off, ws_attn, BM, BN, gV32, gQ32, flag);
    // 4) sampling
    k_fused2<bf16><<<BN, 256, 0, stream>>>(ref_points, ws_off, ws_attn, ws_v,
                                           d_out, N, BN, flag);
  } else if (ws_size >= need_full) {
    float* ws_v    = (float*)ws_base;
    float* ws_off  = (float*)(ws_base + sz_v);
    float* ws_attn = (float*)(ws_base + sz_v + sz_off);
    k_detect<<<1, 256, 0, stream>>>((const unsigned short*)query, flag);
    k_vgemv4x4<<<(BM + 15) / 16, 256, 0, stream>>>(value, W_v, b_v, ws_v, BM, flag);
    k_vgemv4x4<<<(BN + 15) / 16, 256, 0, stream>>>(query, W_off, b_off, ws_off, BN, flag);
    k_agemv4<<<(BN + 15) / 16, 256, 0, stream>>>(query, W_attn, b_attn, ws_attn, BN, flag);
    k_fused2<float><<<BN, 256, 0, stream>>>(ref_points, ws_off, ws_attn, ws_v,
                                            d_out, N, BN, flag);
  } else {
    bf16* ws_v = (bf16*)ws_base;
    k_detect<<<1, 256, 0, stream>>>((const unsigned short*)query, flag);
    k_value_proj<bf16><<<BM, 256, 0, stream>>>(value, W_v, b_v, ws_v, BM, flag);
    k_fused_fb<bf16><<<BN, 256, 0, stream>>>(query, ref_points, W_off, b_off,
                                             W_attn, b_attn, ws_v, d_out, N, BN, flag);
  }
}